// Round 6
// baseline (558.454 us; speedup 1.0000x reference)
//
#include <hip/hip_runtime.h>
#include <stdint.h>

typedef unsigned short ushort_t;

__device__ __forceinline__ float bf2f(unsigned short u) {
  union { unsigned int i; float f; } c; c.i = ((unsigned int)u) << 16; return c.f;
}
__device__ __forceinline__ unsigned short f2bf(float f) {
  union { float f; unsigned int i; } c; c.f = f;
  unsigned int r = c.i + 0x7FFFu + ((c.i >> 16) & 1u);
  return (unsigned short)(r >> 16);
}
// NaN-propagating relu (tripwire: NaN stays visible)
__device__ __forceinline__ float relu_nanprop(float v) { return (v < 0.f) ? 0.f : v; }

// async global->LDS 16B copy: LDS dest = wave-uniform base + lane*16 (HW-implicit)
__device__ __forceinline__ void async_copy16(const void* g, void* l) {
  __builtin_amdgcn_global_load_lds(
      (const __attribute__((address_space(1))) unsigned int*)(uintptr_t)g,
      (__attribute__((address_space(3))) unsigned int*)(uintptr_t)l,
      16, 0, 0);
}

typedef __attribute__((ext_vector_type(8))) short s16x8;
typedef __attribute__((ext_vector_type(4))) float f32x4;

__device__ __forceinline__ int edge_at(const void* edges, int wide, int idx) {
  if (wide) return (int)((const long long*)edges)[idx];
  return ((const int*)edges)[idx];
}

// ---------------- setup: zero scratch + dtype detects (1 launch) ----------------
__global__ void setup_kernel(int* __restrict__ zreg2, int N,
                             const int* __restrict__ e32, int n32, int* __restrict__ eflag,
                             const unsigned int* __restrict__ x, int nw, int* __restrict__ fF) {
  int b = blockIdx.x, tid = threadIdx.x;
  if (b < 256) {
    int total = 2 * N + 1024;
    for (int i = b * 256 + tid; i < total; i += 256 * 256) zreg2[i] = 0;
  } else if (b == 256) {
    __shared__ int any;
    if (tid == 0) any = 0;
    __syncthreads();
    for (int i = tid; i < 4096; i += 256) {
      int idx = 2 * i + 1;
      if (idx < n32 && e32[idx] != 0) any = 1;
    }
    __syncthreads();
    if (tid == 0) eflag[0] = (any == 0) ? 1 : 0;  // 1 => int64
  } else {
    __shared__ int cnt;
    if (tid == 0) cnt = 0;
    __syncthreads();
    int local = 0;
    for (int i = tid; i < 4096 && i < nw; i += 256) {
      unsigned int low = x[i] & 0xFFFFu;
      unsigned int e = (low >> 7) & 0xFFu;
      if (low != 0u && (e < 96u || e > 144u)) local++;
    }
    atomicAdd(&cnt, local);
    __syncthreads();
    if (tid == 0) fF[0] = (cnt > 1024) ? 1 : 0;  // 1 => float32 inputs
  }
}

// ---------------- cvt_all: x0 cvt + params + weight prep + hist (1 launch) ----------
// R17: layer weights prepared for the qt-factorization:
//  Wq*b / Wk*b: straight bf16 copies (inputs to on-device M = Wk @ Wq^T GEMM)
//  wcatB* rows [D..]: Wr^T   (gemm4a B-matrix tail; rows [0..D) filled by M-GEMM)
//  wcatV*: Wv^T              (post-attn accumulate GEMM)
__global__ void cvt_all_kernel(const void* __restrict__ x0, ushort_t* __restrict__ x0b, int nx,
                               const void* p0, const void* p1, const void* p2,
                               const void* p3, const void* p4, const void* p5,
                               ushort_t* o0, ushort_t* o1, ushort_t* o2,
                               ushort_t* o3, ushort_t* o4, ushort_t* o5,
                               const void* W10, const void* W11, const void* W12, const void* W13,
                               ushort_t* __restrict__ Wq1b, ushort_t* __restrict__ Wk1b,
                               ushort_t* __restrict__ wcatB1, ushort_t* __restrict__ wcatV1,
                               const void* W20, const void* W21, const void* W22, const void* W23,
                               ushort_t* __restrict__ Wq2b, ushort_t* __restrict__ Wk2b,
                               ushort_t* __restrict__ wcatB2, ushort_t* __restrict__ wcatV2,
                               const void* __restrict__ edges, int* __restrict__ deg,
                               int E, int Nn,
                               const int* __restrict__ eflag, const int* __restrict__ fF) {
  int b = blockIdx.x, tid = threadIdx.x;
  int f = fF[0];
  if (b < 4096) {
    for (int i = b * 256 + tid; i < nx; i += 4096 * 256)
      x0b[i] = f ? f2bf(((const float*)x0)[i]) : ((const ushort_t*)x0)[i];
  } else if (b == 4096) {
    const void* ins[6] = {p0, p1, p2, p3, p4, p5};
    ushort_t* outs[6] = {o0, o1, o2, o3, o4, o5};
    const int segs[7] = {0, 256, 512, 768, 896, 1024, 1152};
    for (int i = tid; i < 1152; i += 256) {
      int s = 0;
      while (i >= segs[s + 1]) s++;
      int li = i - segs[s];
      outs[s][li] = f ? f2bf(((const float*)ins[s])[li]) : ((const ushort_t*)ins[s])[li];
    }
  } else if (b < 4609) {
    // layer-1: Wq1[128][256], Wk1[128][256] straight; Wr1[128][256]->wcatB1 rows 128..383;
    // Wv1[128][256]->wcatV1[256][128]. total 131072 elems.
    for (int i = (b - 4097) * 256 + tid; i < 131072; i += 512 * 256) {
      if (i < 32768) {
        Wq1b[i] = f ? f2bf(((const float*)W10)[i]) : ((const ushort_t*)W10)[i];
      } else if (i < 65536) {
        int r = i - 32768;
        Wk1b[r] = f ? f2bf(((const float*)W11)[r]) : ((const ushort_t*)W11)[r];
      } else if (i < 98304) {
        int rem = i - 65536, k = rem >> 8, c = rem & 255;  // Wr1[k][c]
        ushort_t v = f ? f2bf(((const float*)W13)[rem]) : ((const ushort_t*)W13)[rem];
        wcatB1[(size_t)(128 + c) * 128 + k] = v;
      } else {
        int rem = i - 98304, k = rem >> 8, c = rem & 255;  // Wv1[k][c]
        ushort_t v = f ? f2bf(((const float*)W12)[rem]) : ((const ushort_t*)W12)[rem];
        wcatV1[(size_t)c * 128 + k] = v;
      }
    }
  } else if (b < 5121) {
    // layer-2: Wq2[256][256], Wk2[256][256] straight; Wr2[256][128]->wcatB2 rows 256..383;
    // Wv2[256][128]->wcatV2[128][256]. total 196608 elems.
    for (int i = (b - 4609) * 256 + tid; i < 196608; i += 512 * 256) {
      if (i < 65536) {
        Wq2b[i] = f ? f2bf(((const float*)W20)[i]) : ((const ushort_t*)W20)[i];
      } else if (i < 131072) {
        int r = i - 65536;
        Wk2b[r] = f ? f2bf(((const float*)W21)[r]) : ((const ushort_t*)W21)[r];
      } else if (i < 163840) {
        int rem = i - 131072, k = rem >> 7, c = rem & 127;  // Wr2[k][c]
        ushort_t v = f ? f2bf(((const float*)W23)[rem]) : ((const ushort_t*)W23)[rem];
        wcatB2[(size_t)(256 + c) * 256 + k] = v;
      } else {
        int rem = i - 163840, k = rem >> 7, c = rem & 127;  // Wv2[k][c]
        ushort_t v = f ? f2bf(((const float*)W22)[rem]) : ((const ushort_t*)W22)[rem];
        wcatV2[(size_t)c * 256 + k] = v;
      }
    }
  } else {  // hist: 1024 blocks
    int wide = eflag[0];
    for (int e = (b - 5121) * 256 + tid; e < E; e += 1024 * 256) {
      int d = edge_at(edges, wide, E + e);
      if (d < 0) d = 0; if (d >= Nn) d = Nn - 1;
      atomicAdd(&deg[d], 1);
    }
  }
}

// 3-phase parallel scan (chunk = 256): supports N <= 65536
__global__ void chunk_sum_kernel(const int* __restrict__ deg, int* __restrict__ csum, int n) {
  int b = blockIdx.x, t = threadIdx.x, i = b * 256 + t;
  int v = (i < n) ? deg[i] : 0;
  __shared__ int ws[4];
#pragma unroll
  for (int o = 32; o > 0; o >>= 1) v += __shfl_down(v, o);
  if ((t & 63) == 0) ws[t >> 6] = v;
  __syncthreads();
  if (t == 0) csum[b] = ws[0] + ws[1] + ws[2] + ws[3];
}

__global__ void scan_small_kernel(const int* __restrict__ csum, int* __restrict__ cpre,
                                  int nc, int* __restrict__ offs, int N) {
  __shared__ int tmp[256];
  int t = threadIdx.x;
  int v = (t < nc) ? csum[t] : 0;
  tmp[t] = v;
  __syncthreads();
  for (int off = 1; off < 256; off <<= 1) {
    int x = (t >= off) ? tmp[t - off] : 0;
    __syncthreads();
    tmp[t] += x;
    __syncthreads();
  }
  if (t < nc) cpre[t] = tmp[t] - v;
  if (t == 255) offs[N] = tmp[255];
}

__global__ void scan_final_kernel(const int* __restrict__ deg, const int* __restrict__ cpre,
                                  int* __restrict__ offs, int n) {
  int b = blockIdx.x, t = threadIdx.x, i = b * 256 + t;
  __shared__ int tmp[256];
  int v = (i < n) ? deg[i] : 0;
  tmp[t] = v;
  __syncthreads();
  for (int off = 1; off < 256; off <<= 1) {
    int x = (t >= off) ? tmp[t - off] : 0;
    __syncthreads();
    tmp[t] += x;
    __syncthreads();
  }
  if (i < n) offs[i] = cpre[b] + tmp[t] - v;
}

__global__ void scatter_kernel(const void* __restrict__ edges, const int* __restrict__ flag,
                               const int* __restrict__ offs, int* __restrict__ fill,
                               int* __restrict__ srcS, int E, int Nn) {
  int wide = flag[0];
  for (int e = blockIdx.x * blockDim.x + threadIdx.x; e < E; e += gridDim.x * blockDim.x) {
    int s = edge_at(edges, wide, e);
    int d = edge_at(edges, wide, E + e);
    if (d < 0) d = 0; if (d >= Nn) d = Nn - 1;
    if (s < 0) s = 0; if (s >= Nn) s = Nn - 1;
    int p = offs[d] + atomicAdd(&fill[d], 1);
    if (p < 0) p = 0; if (p >= E) p = E - 1;
    srcS[p] = s;
  }
}

// ---------------- fused multi-section GEMM: out = A @ Bcat (+bias) (+accum) --------
// R11 config (best measured): 128x128 tile, acc 4x4, global_load_lds staging.
// R17: added accum flag (epilogue read-modify-write) for the deferred-Wv GEMM.
__global__ __launch_bounds__(256)
void gemm4_kernel(const ushort_t* __restrict__ A, const ushort_t* __restrict__ BT,
                  ushort_t* __restrict__ o0, ushort_t* __restrict__ o1,
                  ushort_t* __restrict__ o2, ushort_t* __restrict__ o3,
                  const ushort_t* __restrict__ bias3,
                  int M, int K, int NC, int b0, int b1, int b2, int accum) {
  __shared__ __align__(16) ushort_t As[128 * 32];
  __shared__ __align__(16) ushort_t Bs[128 * 32];
  int tid = threadIdx.x;
  int lane = tid & 63, wave = tid >> 6;
  int tm = blockIdx.x * 128, tn = blockIdx.y * 128;
  int wm = (wave >> 1) * 64, wn = (wave & 1) * 64;
  int q = lane >> 4, l = lane & 15;
  f32x4 acc[4][4];
#pragma unroll
  for (int a = 0; a < 4; a++)
#pragma unroll
    for (int b = 0; b < 4; b++) acc[a][b] = (f32x4){0.f, 0.f, 0.f, 0.f};

  int lrow = lane >> 2, c8 = (lane & 3) * 8;
  for (int k0 = 0; k0 < K; k0 += 32) {
#pragma unroll
    for (int t = 0; t < 2; t++) {
      int chunk = t * 4 + wave;           // 0..7, 16 rows each
      int row = chunk * 16 + lrow;
      int ra = tm + row; if (ra > M - 1) ra = M - 1;
      async_copy16(&A[(size_t)ra * K + k0 + c8], &As[chunk * 512]);
      async_copy16(&BT[(size_t)(tn + row) * K + k0 + c8], &Bs[chunk * 512]);
    }
    __syncthreads();
    s16x8 af[4], bfr[4];
#pragma unroll
    for (int mf = 0; mf < 4; mf++) af[mf] = *(const s16x8*)&As[(wm + mf * 16 + l) * 32 + q * 8];
#pragma unroll
    for (int nf = 0; nf < 4; nf++) bfr[nf] = *(const s16x8*)&Bs[(wn + nf * 16 + l) * 32 + q * 8];
#pragma unroll
    for (int mf = 0; mf < 4; mf++)
#pragma unroll
      for (int nf = 0; nf < 4; nf++)
        acc[mf][nf] = __builtin_amdgcn_mfma_f32_16x16x32_bf16(af[mf], bfr[nf], acc[mf][nf], 0, 0, 0);
    __syncthreads();
  }
  // Hoisted section select (tile is 128-aligned; sections are 128-multiples).
  ushort_t* op; int sbase, w; bool addb = false;
  if (tn < b0)      { op = o0; sbase = 0;  w = b0; }
  else if (tn < b1) { op = o1; sbase = b0; w = b1 - b0; }
  else if (tn < b2) { op = o2; sbase = b1; w = b2 - b1; }
  else              { op = o3; sbase = b2; w = NC - b2; addb = true; }
  int lc0 = tn + wn - sbase + l;
  float bv[4];
#pragma unroll
  for (int nf = 0; nf < 4; nf++) bv[nf] = addb ? bf2f(bias3[lc0 + nf * 16]) : 0.f;
  // C/D layout: col = lane&15, row = (lane>>4)*4 + reg   [m89-verified]
#pragma unroll
  for (int mf = 0; mf < 4; mf++) {
#pragma unroll
    for (int j = 0; j < 4; j++) {
      int r = tm + wm + mf * 16 + q * 4 + j;
      if (r < M) {
#pragma unroll
        for (int nf = 0; nf < 4; nf++) {
          size_t idx = (size_t)r * w + lc0 + nf * 16;
          float prev = accum ? bf2f(op[idx]) : 0.f;
          op[idx] = f2bf(acc[mf][nf][j] + bv[nf] + prev);
        }
      }
    }
  }
}

// ---------------- fused attention + aggregation, one WAVE per dst node ----------------
// R17: qt-factorization. logit = qt[d]·x[s]; agg = sum(w * x[s]) (Wv applied after).
// [R18 post-mortem: 2-deep pipeline +4% only — srcS->x dependent chain limited the
//  effective request depth.]
// R19: BATCHED index loads. 16 srcS indices in ONE coalesced load (lanes 0-15),
// __shfl-broadcast to the 4 edge-groups, then ALL 4 iterations' x-loads issue
// back-to-back (4x16B/lane in flight) before any math. 8-batch stage for mid-degree
// nodes. srcS access off the critical path entirely.
__global__ __launch_bounds__(256)
void attn_kernel(const ushort_t* __restrict__ qt, const ushort_t* __restrict__ x,
                 const int* __restrict__ offs, const int* __restrict__ srcS,
                 ushort_t* __restrict__ aggb, int D, int Nn) {
  int lane = threadIdx.x & 63, wave = threadIdx.x >> 6;
  int n = blockIdx.x * 4 + wave;
  if (n >= Nn) return;
  int g = lane >> 4, sub = lane & 15;

  int e0 = offs[n], e1 = offs[n + 1];
  float wsum = 0.f;

  if (D == 128) {  // 8 dims per lane
    s16x8 qv = __builtin_nontemporal_load((const s16x8*)(qt + (size_t)n * 128 + sub * 8));
    float qf[8];
#pragma unroll
    for (int i = 0; i < 8; i++) qf[i] = bf2f((unsigned short)qv[i]);
    float acc[8];
#pragma unroll
    for (int i = 0; i < 8; i++) acc[i] = 0.f;

    auto proc = [&](s16x8 xv) {
      float p = 0.f;
#pragma unroll
      for (int i = 0; i < 8; i++) p += qf[i] * bf2f((unsigned short)xv[i]);
      p += __shfl_xor(p, 1); p += __shfl_xor(p, 2);
      p += __shfl_xor(p, 4); p += __shfl_xor(p, 8);
      float w = __expf(p * 0.0625f);
      wsum += w;
#pragma unroll
      for (int i = 0; i < 8; i++) acc[i] += w * bf2f((unsigned short)xv[i]);
    };

    int j = e0;
    for (; j + 16 <= e1; j += 16) {   // 16-edge batches: 4 loads in flight
      int myidx = 0;
      if (lane < 16) {
        myidx = __builtin_nontemporal_load(srcS + j + lane);
        if (myidx < 0 || myidx >= Nn) myidx = 0;
      }
      int s0 = __shfl(myidx, g);
      int s1 = __shfl(myidx, 4 + g);
      int s2 = __shfl(myidx, 8 + g);
      int s3 = __shfl(myidx, 12 + g);
      s16x8 x0v = *(const s16x8*)(x + (size_t)s0 * 128 + sub * 8);
      s16x8 x1v = *(const s16x8*)(x + (size_t)s1 * 128 + sub * 8);
      s16x8 x2v = *(const s16x8*)(x + (size_t)s2 * 128 + sub * 8);
      s16x8 x3v = *(const s16x8*)(x + (size_t)s3 * 128 + sub * 8);
      proc(x0v); proc(x1v); proc(x2v); proc(x3v);
    }
    if (j + 8 <= e1) {                // one 8-edge batch: 2 loads in flight
      int myidx = 0;
      if (lane < 8) {
        myidx = __builtin_nontemporal_load(srcS + j + lane);
        if (myidx < 0 || myidx >= Nn) myidx = 0;
      }
      int s0 = __shfl(myidx, g);
      int s1 = __shfl(myidx, 4 + g);
      s16x8 x0v = *(const s16x8*)(x + (size_t)s0 * 128 + sub * 8);
      s16x8 x1v = *(const s16x8*)(x + (size_t)s1 * 128 + sub * 8);
      proc(x0v); proc(x1v);
      j += 8;
    }
    if (j + 4 <= e1) {
      int s = __builtin_nontemporal_load(srcS + j + g);
      if (s < 0 || s >= Nn) s = 0;
      s16x8 xv = *(const s16x8*)(x + (size_t)s * 128 + sub * 8);
      proc(xv);
      j += 4;
    }
    int rem = e1 - j;
    if (rem > 0) {
      bool valid = g < rem;
      int s = __builtin_nontemporal_load(srcS + (valid ? (j + g) : j));
      if (s < 0 || s >= Nn) s = 0;
      s16x8 xv = *(const s16x8*)(x + (size_t)s * 128 + sub * 8);
      float p = 0.f;
#pragma unroll
      for (int i = 0; i < 8; i++) p += qf[i] * bf2f((unsigned short)xv[i]);
      p += __shfl_xor(p, 1); p += __shfl_xor(p, 2);
      p += __shfl_xor(p, 4); p += __shfl_xor(p, 8);
      float w = 0.f;
      if (valid) w = __expf(p * 0.0625f);
      wsum += w;
#pragma unroll
      for (int i = 0; i < 8; i++) acc[i] += w * bf2f((unsigned short)xv[i]);
    }
    wsum += __shfl_xor(wsum, 16); wsum += __shfl_xor(wsum, 32);
#pragma unroll
    for (int i = 0; i < 8; i++) {
      acc[i] += __shfl_xor(acc[i], 16);
      acc[i] += __shfl_xor(acc[i], 32);
    }
    float inv = 1.f / fmaxf(wsum, 1e-16f);
    if (g == 0) {
      s16x8 r0;
#pragma unroll
      for (int i = 0; i < 8; i++) r0[i] = (short)f2bf(acc[i] * inv);
      *(s16x8*)(aggb + (size_t)n * 128 + sub * 8) = r0;
    }
  } else {  // D == 256: 16 dims per lane
    s16x8 q0 = __builtin_nontemporal_load((const s16x8*)(qt + (size_t)n * 256 + sub * 16));
    s16x8 q1 = __builtin_nontemporal_load((const s16x8*)(qt + (size_t)n * 256 + sub * 16 + 8));
    float qf[16];
#pragma unroll
    for (int i = 0; i < 8; i++) {
      qf[i]     = bf2f((unsigned short)q0[i]);
      qf[8 + i] = bf2f((unsigned short)q1[i]);
    }
    float acc[16];
#pragma unroll
    for (int i = 0; i < 16; i++) acc[i] = 0.f;

    auto proc2 = [&](s16x8 xa, s16x8 xb) {
      float pa = 0.f, pb = 0.f;
#pragma unroll
      for (int i = 0; i < 8; i++) {
        pa += qf[i] * bf2f((unsigned short)xa[i]);
        pb += qf[8 + i] * bf2f((unsigned short)xb[i]);
      }
      float p = pa + pb;
      p += __shfl_xor(p, 1); p += __shfl_xor(p, 2);
      p += __shfl_xor(p, 4); p += __shfl_xor(p, 8);
      float w = __expf(p * 0.0625f);
      wsum += w;
#pragma unroll
      for (int i = 0; i < 8; i++) {
        acc[i]     += w * bf2f((unsigned short)xa[i]);
        acc[8 + i] += w * bf2f((unsigned short)xb[i]);
      }
    };

    int j = e0;
    for (; j + 16 <= e1; j += 16) {   // 16-edge batches: 8x16B loads in flight
      int myidx = 0;
      if (lane < 16) {
        myidx = __builtin_nontemporal_load(srcS + j + lane);
        if (myidx < 0 || myidx >= Nn) myidx = 0;
      }
      int s0 = __shfl(myidx, g);
      int s1 = __shfl(myidx, 4 + g);
      int s2 = __shfl(myidx, 8 + g);
      int s3 = __shfl(myidx, 12 + g);
      const ushort_t* p0 = x + (size_t)s0 * 256 + sub * 16;
      const ushort_t* p1 = x + (size_t)s1 * 256 + sub * 16;
      const ushort_t* p2 = x + (size_t)s2 * 256 + sub * 16;
      const ushort_t* p3 = x + (size_t)s3 * 256 + sub * 16;
      s16x8 a0 = *(const s16x8*)p0, b0 = *(const s16x8*)(p0 + 8);
      s16x8 a1 = *(const s16x8*)p1, b1 = *(const s16x8*)(p1 + 8);
      s16x8 a2 = *(const s16x8*)p2, b2 = *(const s16x8*)(p2 + 8);
      s16x8 a3 = *(const s16x8*)p3, b3 = *(const s16x8*)(p3 + 8);
      proc2(a0, b0); proc2(a1, b1); proc2(a2, b2); proc2(a3, b3);
    }
    if (j + 8 <= e1) {
      int myidx = 0;
      if (lane < 8) {
        myidx = __builtin_nontemporal_load(srcS + j + lane);
        if (myidx < 0 || myidx >= Nn) myidx = 0;
      }
      int s0 = __shfl(myidx, g);
      int s1 = __shfl(myidx, 4 + g);
      const ushort_t* p0 = x + (size_t)s0 * 256 + sub * 16;
      const ushort_t* p1 = x + (size_t)s1 * 256 + sub * 16;
      s16x8 a0 = *(const s16x8*)p0, b0 = *(const s16x8*)(p0 + 8);
      s16x8 a1 = *(const s16x8*)p1, b1 = *(const s16x8*)(p1 + 8);
      proc2(a0, b0); proc2(a1, b1);
      j += 8;
    }
    if (j + 4 <= e1) {
      int s = __builtin_nontemporal_load(srcS + j + g);
      if (s < 0 || s >= Nn) s = 0;
      const ushort_t* xp = x + (size_t)s * 256 + sub * 16;
      s16x8 a0 = *(const s16x8*)xp, b0 = *(const s16x8*)(xp + 8);
      proc2(a0, b0);
      j += 4;
    }
    int rem = e1 - j;
    if (rem > 0) {
      bool valid = g < rem;
      int s = __builtin_nontemporal_load(srcS + (valid ? (j + g) : j));
      if (s < 0 || s >= Nn) s = 0;
      const ushort_t* xp = x + (size_t)s * 256 + sub * 16;
      s16x8 x0v = *(const s16x8*)xp, x1v = *(const s16x8*)(xp + 8);
      float pa = 0.f, pb = 0.f;
#pragma unroll
      for (int i = 0; i < 8; i++) {
        pa += qf[i] * bf2f((unsigned short)x0v[i]);
        pb += qf[8 + i] * bf2f((unsigned short)x1v[i]);
      }
      float p = pa + pb;
      p += __shfl_xor(p, 1); p += __shfl_xor(p, 2);
      p += __shfl_xor(p, 4); p += __shfl_xor(p, 8);
      float w = 0.f;
      if (valid) w = __expf(p * 0.0625f);
      wsum += w;
#pragma unroll
      for (int i = 0; i < 8; i++) {
        acc[i]     += w * bf2f((unsigned short)x0v[i]);
        acc[8 + i] += w * bf2f((unsigned short)x1v[i]);
      }
    }
    wsum += __shfl_xor(wsum, 16); wsum += __shfl_xor(wsum, 32);
#pragma unroll
    for (int i = 0; i < 16; i++) {
      acc[i] += __shfl_xor(acc[i], 16);
      acc[i] += __shfl_xor(acc[i], 32);
    }
    float inv = 1.f / fmaxf(wsum, 1e-16f);
    if (g == 0) {
      s16x8 r0, r1;
#pragma unroll
      for (int i = 0; i < 8; i++) {
        r0[i] = (short)f2bf(acc[i] * inv);
        r1[i] = (short)f2bf(acc[8 + i] * inv);
      }
      size_t idx = (size_t)n * 256 + sub * 16;
      *(s16x8*)(aggb + idx) = r0;
      *(s16x8*)(aggb + idx + 8) = r1;
    }
  }
}

// ---------------- BatchNorm ----------------
__global__ void bn_stats_kernel(const ushort_t* __restrict__ h, float* __restrict__ sum,
                                float* __restrict__ sumsq, int N, int F) {
  int col = threadIdx.x;
  float s = 0.f, s2 = 0.f;
  for (int r = blockIdx.x; r < N; r += gridDim.x) {
    float x = bf2f(h[(size_t)r * F + col]);
    s += x; s2 += x * x;
  }
  atomicAdd(&sum[col], s);
  atomicAdd(&sumsq[col], s2);
}

// normalize+relu; each block recomputes scale/shift from sums (removes bn_final launch)
__global__ void norm_relu_kernel(const ushort_t* __restrict__ h,
                                 const float* __restrict__ sum, const float* __restrict__ sumsq,
                                 const ushort_t* __restrict__ g, const ushort_t* __restrict__ be,
                                 ushort_t* __restrict__ x1, int N, size_t total, int cmask) {
  __shared__ float sc[256], sh[256];
  int t = threadIdx.x;
  if (t <= cmask) {
    float mu = sum[t] / (float)N;
    float var = sumsq[t] / (float)N - mu * mu;
    float s = bf2f(g[t]) * rsqrtf(var + 1e-5f);
    sc[t] = s;
    sh[t] = bf2f(be[t]) - mu * s;
  }
  __syncthreads();
  for (size_t i = blockIdx.x * (size_t)blockDim.x + t; i < total;
       i += (size_t)gridDim.x * blockDim.x) {
    int c = (int)(i & (size_t)cmask);
    float vv = bf2f(h[i]) * sc[c] + sh[c];
    x1[i] = f2bf(relu_nanprop(vv));
  }
}

// final: BN + residual + relu, dual-dtype out; recomputes scale/shift per block
__global__ void final_kernel(const ushort_t* __restrict__ h,
                             const float* __restrict__ sum, const float* __restrict__ sumsq,
                             const ushort_t* __restrict__ g, const ushort_t* __restrict__ be,
                             const ushort_t* __restrict__ x0b, void* __restrict__ out,
                             const int* __restrict__ flagF, int N, size_t total) {
  __shared__ float sc[128], sh[128];
  int t = threadIdx.x;
  if (t < 128) {
    float mu = sum[t] / (float)N;
    float var = sumsq[t] / (float)N - mu * mu;
    float s = bf2f(g[t]) * rsqrtf(var + 1e-5f);
    sc[t] = s;
    sh[t] = bf2f(be[t]) - mu * s;
  }
  __syncthreads();
  int f = flagF[0];
  for (size_t i = blockIdx.x * (size_t)blockDim.x + t; i < total;
       i += (size_t)gridDim.x * blockDim.x) {
    int c = (int)(i & 127);
    float vv = bf2f(h[i]) * sc[c] + sh[c] + bf2f(x0b[i]);
    vv = relu_nanprop(vv);
    if (f) ((float*)out)[i] = vv;
    else   ((ushort_t*)out)[i] = f2bf(vv);
  }
}

extern "C" void kernel_launch(void* const* d_in, const int* in_sizes, int n_in,
                              void* d_out, int out_size, void* d_ws, size_t ws_size,
                              hipStream_t stream) {
  const void* x0  = d_in[0];
  const void* edges = d_in[1];
  const void* Wq1 = d_in[2];
  const void* Wk1 = d_in[3];
  const void* Wv1 = d_in[4];
  const void* Wr1 = d_in[5];
  const void* b1  = d_in[6];
  const void* gw1 = d_in[7];
  const void* bw1 = d_in[8];
  const void* Wq2 = d_in[9];
  const void* Wk2 = d_in[10];
  const void* Wv2 = d_in[11];
  const void* Wr2 = d_in[12];
  const void* b2  = d_in[13];
  const void* gw2 = d_in[14];
  const void* bw2 = d_in[15];

  int N = in_sizes[0] / 128;
  int E = in_sizes[1] / 2;
  int NCHUNK = (N + 255) / 256;
  int MT = (N + 127) / 128;

  uintptr_t base = (uintptr_t)d_ws;
  auto carve = [&](size_t bytes) -> void* {
    uintptr_t p = base;
    base += (bytes + 255) & ~(size_t)255;
    return (void*)p;
  };
  ushort_t* x0b = (ushort_t*)carve((size_t)N * 128 * 2);
  ushort_t* qtb = (ushort_t*)carve((size_t)N * 256 * 2);   // qt1 (128) / qt2 (256)
  ushort_t* aggb = (ushort_t*)carve((size_t)N * 256 * 2);  // agg output (128/256)
  ushort_t* hb = (ushort_t*)carve((size_t)N * 256 * 2);
  ushort_t* x1 = (ushort_t*)carve((size_t)N * 256 * 2);
  ushort_t* Wq1b = (ushort_t*)carve((size_t)128 * 256 * 2);
  ushort_t* Wk1b = (ushort_t*)carve((size_t)128 * 256 * 2);
  ushort_t* wcatB1 = (ushort_t*)carve((size_t)384 * 128 * 2);  // [M1^T | Wr1^T]
  ushort_t* wcatV1 = (ushort_t*)carve((size_t)256 * 128 * 2);  // Wv1^T
  ushort_t* Wq2b = (ushort_t*)carve((size_t)256 * 256 * 2);
  ushort_t* Wk2b = (ushort_t*)carve((size_t)256 * 256 * 2);
  ushort_t* wcatB2 = (ushort_t*)carve((size_t)384 * 256 * 2);  // [M2^T | Wr2^T]
  ushort_t* wcatV2 = (ushort_t*)carve((size_t)128 * 256 * 2);  // Wv2^T
  ushort_t* b1b  = (ushort_t*)carve(256 * 2);
  ushort_t* g1b  = (ushort_t*)carve(256 * 2);
  ushort_t* be1b = (ushort_t*)carve(256 * 2);
  ushort_t* b2b  = (ushort_t*)carve(128 * 2);
  ushort_t* g2b  = (ushort_t*)carve(128 * 2);
  ushort_t* be2b = (ushort_t*)carve(128 * 2);
  int* offs = (int*)carve((size_t)(N + 1) * 4);
  int* srcS = (int*)carve((size_t)E * 4);
  int* csum = (int*)carve(256 * 4);
  int* cpre = (int*)carve(256 * 4);
  // zeroed region: deg(N) fill(N) sums(1024 floats)
  int nzero = 2 * N + 1024;
  int* zreg2 = (int*)carve((size_t)nzero * 4);
  int* deg   = zreg2;
  int* fill  = zreg2 + N;
  float* sum1 = (float*)(zreg2 + 2 * N);
  float* sq1  = sum1 + 256;
  float* sum2 = sum1 + 512;
  float* sq2  = sum1 + 640;
  int* eflag = (int*)carve(256);   // [0]=edge wide, [1]=float32 flag (setup writes)
  int* fF = eflag + 1;

  size_t needed = base - (uintptr_t)d_ws;
  if (needed > ws_size) return;

  // 1: zero + dtype detects
  setup_kernel<<<258, 256, 0, stream>>>(zreg2, N, (const int*)edges, 2 * E, eflag,
                                        (const unsigned int*)x0, N * 128, fF);
  // 2: x0 cvt + params + weight prep + hist
  cvt_all_kernel<<<6145, 256, 0, stream>>>(x0, x0b, N * 128,
                                           b1, gw1, bw1, b2, gw2, bw2,
                                           b1b, g1b, be1b, b2b, g2b, be2b,
                                           Wq1, Wk1, Wv1, Wr1, Wq1b, Wk1b, wcatB1, wcatV1,
                                           Wq2, Wk2, Wv2, Wr2, Wq2b, Wk2b, wcatB2, wcatV2,
                                           edges, deg, E, N, eflag, fF);
  // 3-6: scan + scatter
  chunk_sum_kernel<<<NCHUNK, 256, 0, stream>>>(deg, csum, N);
  scan_small_kernel<<<1, 256, 0, stream>>>(csum, cpre, NCHUNK, offs, N);
  scan_final_kernel<<<NCHUNK, 256, 0, stream>>>(deg, cpre, offs, N);
  scatter_kernel<<<1024, 256, 0, stream>>>(edges, eflag, offs, fill, srcS, E, N);

  // M1^T = Wk1 @ Wq1^T -> wcatB1 rows 0..127;  M2^T = Wk2 @ Wq2^T -> wcatB2 rows 0..255
  gemm4_kernel<<<dim3(1, 1), 256, 0, stream>>>(Wk1b, Wq1b, wcatB1, wcatB1, wcatB1, wcatB1,
                                               b1b, 128, 256, 128, 128, 128, 128, 0);
  gemm4_kernel<<<dim3(2, 2), 256, 0, stream>>>(Wk2b, Wq2b, wcatB2, wcatB2, wcatB2, wcatB2,
                                               b1b, 256, 256, 256, 256, 256, 256, 0);

  int gAttn = (N + 3) / 4;        // one wave per node
  // Layer 1: [qt1 | h=x@Wr1+b1] = x0b @ wcatB1
  gemm4_kernel<<<dim3(MT, 3), 256, 0, stream>>>(x0b, wcatB1, qtb, qtb, qtb, hb, b1b,
                                                N, 128, 384, 128, 128, 128, 0);
  attn_kernel<<<gAttn, 256, 0, stream>>>(qtb, x0b, offs, srcS, aggb, 128, N);
  // h += agg @ Wv1
  gemm4_kernel<<<dim3(MT, 2), 256, 0, stream>>>(aggb, wcatV1, hb, hb, hb, hb, b1b,
                                                N, 128, 256, 256, 256, 256, 1);
  bn_stats_kernel<<<512, 256, 0, stream>>>(hb, sum1, sq1, N, 256);
  norm_relu_kernel<<<4096, 256, 0, stream>>>(hb, sum1, sq1, g1b, be1b, x1, N,
                                             (size_t)N * 256, 255);
  // Layer 2: [qt2 | h=x1@Wr2+b2] = x1 @ wcatB2
  gemm4_kernel<<<dim3(MT, 3), 256, 0, stream>>>(x1, wcatB2, qtb, qtb, qtb, hb, b2b,
                                                N, 256, 384, 256, 256, 256, 0);
  attn_kernel<<<gAttn, 256, 0, stream>>>(qtb, x1, offs, srcS, aggb, 256, N);
  // h += agg @ Wv2
  gemm4_kernel<<<dim3(MT, 1), 256, 0, stream>>>(aggb, wcatV2, hb, hb, hb, hb, b1b,
                                                N, 256, 128, 128, 128, 128, 1);
  bn_stats_kernel<<<512, 128, 0, stream>>>(hb, sum2, sq2, N, 128);
  final_kernel<<<4096, 256, 0, stream>>>(hb, sum2, sq2, g2b, be2b, x0b, d_out, fF, N,
                                         (size_t)N * 128);
}

// Round 7
// 507.303 us; speedup vs baseline: 1.1008x; 1.1008x over previous
//
#include <hip/hip_runtime.h>
#include <stdint.h>

typedef unsigned short ushort_t;

__device__ __forceinline__ float bf2f(unsigned short u) {
  union { unsigned int i; float f; } c; c.i = ((unsigned int)u) << 16; return c.f;
}
__device__ __forceinline__ unsigned short f2bf(float f) {
  union { float f; unsigned int i; } c; c.f = f;
  unsigned int r = c.i + 0x7FFFu + ((c.i >> 16) & 1u);
  return (unsigned short)(r >> 16);
}
// NaN-propagating relu (tripwire: NaN stays visible)
__device__ __forceinline__ float relu_nanprop(float v) { return (v < 0.f) ? 0.f : v; }

// async global->LDS 16B copy: LDS dest = wave-uniform base + lane*16 (HW-implicit)
__device__ __forceinline__ void async_copy16(const void* g, void* l) {
  __builtin_amdgcn_global_load_lds(
      (const __attribute__((address_space(1))) unsigned int*)(uintptr_t)g,
      (__attribute__((address_space(3))) unsigned int*)(uintptr_t)l,
      16, 0, 0);
}

typedef __attribute__((ext_vector_type(8))) short s16x8;
typedef __attribute__((ext_vector_type(4))) float f32x4;

__device__ __forceinline__ int edge_at(const void* edges, int wide, int idx) {
  if (wide) return (int)((const long long*)edges)[idx];
  return ((const int*)edges)[idx];
}

// ---------------- setup: zero scratch + dtype detects (1 launch) ----------------
__global__ void setup_kernel(int* __restrict__ zreg2, int N,
                             const int* __restrict__ e32, int n32, int* __restrict__ eflag,
                             const unsigned int* __restrict__ x, int nw, int* __restrict__ fF) {
  int b = blockIdx.x, tid = threadIdx.x;
  if (b < 256) {
    int total = 2 * N + 1024;
    for (int i = b * 256 + tid; i < total; i += 256 * 256) zreg2[i] = 0;
  } else if (b == 256) {
    __shared__ int any;
    if (tid == 0) any = 0;
    __syncthreads();
    for (int i = tid; i < 4096; i += 256) {
      int idx = 2 * i + 1;
      if (idx < n32 && e32[idx] != 0) any = 1;
    }
    __syncthreads();
    if (tid == 0) eflag[0] = (any == 0) ? 1 : 0;  // 1 => int64
  } else {
    __shared__ int cnt;
    if (tid == 0) cnt = 0;
    __syncthreads();
    int local = 0;
    for (int i = tid; i < 4096 && i < nw; i += 256) {
      unsigned int low = x[i] & 0xFFFFu;
      unsigned int e = (low >> 7) & 0xFFu;
      if (low != 0u && (e < 96u || e > 144u)) local++;
    }
    atomicAdd(&cnt, local);
    __syncthreads();
    if (tid == 0) fF[0] = (cnt > 1024) ? 1 : 0;  // 1 => float32 inputs
  }
}

// ---------------- cvt_all: x0 cvt + params + weight prep + hist (1 launch) ----------
// R20 weight prep:
//  Wq*b / Wk*b: straight bf16 copies (inputs to on-device M = Wk @ Wq^T GEMM)
//  wcatH*: [Wr^T | Wv^T] concatenated along K — BT[c][k<D]=Wr[k][c], BT[c][D+k]=Wv[k][c]
//  (wcatQ* rows are filled by the M-GEMM on device)
__global__ void cvt_all_kernel(const void* __restrict__ x0, ushort_t* __restrict__ x0b, int nx,
                               const void* p0, const void* p1, const void* p2,
                               const void* p3, const void* p4, const void* p5,
                               ushort_t* o0, ushort_t* o1, ushort_t* o2,
                               ushort_t* o3, ushort_t* o4, ushort_t* o5,
                               const void* W10, const void* W11, const void* W12, const void* W13,
                               ushort_t* __restrict__ Wq1b, ushort_t* __restrict__ Wk1b,
                               ushort_t* __restrict__ wcatH1,
                               const void* W20, const void* W21, const void* W22, const void* W23,
                               ushort_t* __restrict__ Wq2b, ushort_t* __restrict__ Wk2b,
                               ushort_t* __restrict__ wcatH2,
                               const void* __restrict__ edges, int* __restrict__ deg,
                               int E, int Nn,
                               const int* __restrict__ eflag, const int* __restrict__ fF) {
  int b = blockIdx.x, tid = threadIdx.x;
  int f = fF[0];
  if (b < 4096) {
    for (int i = b * 256 + tid; i < nx; i += 4096 * 256)
      x0b[i] = f ? f2bf(((const float*)x0)[i]) : ((const ushort_t*)x0)[i];
  } else if (b == 4096) {
    const void* ins[6] = {p0, p1, p2, p3, p4, p5};
    ushort_t* outs[6] = {o0, o1, o2, o3, o4, o5};
    const int segs[7] = {0, 256, 512, 768, 896, 1024, 1152};
    for (int i = tid; i < 1152; i += 256) {
      int s = 0;
      while (i >= segs[s + 1]) s++;
      int li = i - segs[s];
      outs[s][li] = f ? f2bf(((const float*)ins[s])[li]) : ((const ushort_t*)ins[s])[li];
    }
  } else if (b < 4609) {
    // layer-1: Wq1[128][256], Wk1[128][256] straight;
    // Wr1[128][256] -> wcatH1[c][k]  (k<128);  Wv1[128][256] -> wcatH1[c][128+k].
    for (int i = (b - 4097) * 256 + tid; i < 131072; i += 512 * 256) {
      if (i < 32768) {
        Wq1b[i] = f ? f2bf(((const float*)W10)[i]) : ((const ushort_t*)W10)[i];
      } else if (i < 65536) {
        int r = i - 32768;
        Wk1b[r] = f ? f2bf(((const float*)W11)[r]) : ((const ushort_t*)W11)[r];
      } else if (i < 98304) {
        int rem = i - 65536, k = rem >> 8, c = rem & 255;  // Wr1[k][c]
        ushort_t v = f ? f2bf(((const float*)W13)[rem]) : ((const ushort_t*)W13)[rem];
        wcatH1[(size_t)c * 256 + k] = v;
      } else {
        int rem = i - 98304, k = rem >> 8, c = rem & 255;  // Wv1[k][c]
        ushort_t v = f ? f2bf(((const float*)W12)[rem]) : ((const ushort_t*)W12)[rem];
        wcatH1[(size_t)c * 256 + 128 + k] = v;
      }
    }
  } else if (b < 5121) {
    // layer-2: Wq2[256][256], Wk2[256][256] straight;
    // Wr2[256][128] -> wcatH2[c][k] (k<256);  Wv2[256][128] -> wcatH2[c][256+k].
    for (int i = (b - 4609) * 256 + tid; i < 196608; i += 512 * 256) {
      if (i < 65536) {
        Wq2b[i] = f ? f2bf(((const float*)W20)[i]) : ((const ushort_t*)W20)[i];
      } else if (i < 131072) {
        int r = i - 65536;
        Wk2b[r] = f ? f2bf(((const float*)W21)[r]) : ((const ushort_t*)W21)[r];
      } else if (i < 163840) {
        int rem = i - 131072, k = rem >> 7, c = rem & 127;  // Wr2[k][c]
        ushort_t v = f ? f2bf(((const float*)W23)[rem]) : ((const ushort_t*)W23)[rem];
        wcatH2[(size_t)c * 512 + k] = v;
      } else {
        int rem = i - 163840, k = rem >> 7, c = rem & 127;  // Wv2[k][c]
        ushort_t v = f ? f2bf(((const float*)W22)[rem]) : ((const ushort_t*)W22)[rem];
        wcatH2[(size_t)c * 512 + 256 + k] = v;
      }
    }
  } else {  // hist: 1024 blocks
    int wide = eflag[0];
    for (int e = (b - 5121) * 256 + tid; e < E; e += 1024 * 256) {
      int d = edge_at(edges, wide, E + e);
      if (d < 0) d = 0; if (d >= Nn) d = Nn - 1;
      atomicAdd(&deg[d], 1);
    }
  }
}

// 3-phase parallel scan (chunk = 256): supports N <= 65536
__global__ void chunk_sum_kernel(const int* __restrict__ deg, int* __restrict__ csum, int n) {
  int b = blockIdx.x, t = threadIdx.x, i = b * 256 + t;
  int v = (i < n) ? deg[i] : 0;
  __shared__ int ws[4];
#pragma unroll
  for (int o = 32; o > 0; o >>= 1) v += __shfl_down(v, o);
  if ((t & 63) == 0) ws[t >> 6] = v;
  __syncthreads();
  if (t == 0) csum[b] = ws[0] + ws[1] + ws[2] + ws[3];
}

__global__ void scan_small_kernel(const int* __restrict__ csum, int* __restrict__ cpre,
                                  int nc, int* __restrict__ offs, int N) {
  __shared__ int tmp[256];
  int t = threadIdx.x;
  int v = (t < nc) ? csum[t] : 0;
  tmp[t] = v;
  __syncthreads();
  for (int off = 1; off < 256; off <<= 1) {
    int x = (t >= off) ? tmp[t - off] : 0;
    __syncthreads();
    tmp[t] += x;
    __syncthreads();
  }
  if (t < nc) cpre[t] = tmp[t] - v;
  if (t == 255) offs[N] = tmp[255];
}

__global__ void scan_final_kernel(const int* __restrict__ deg, const int* __restrict__ cpre,
                                  int* __restrict__ offs, int n) {
  int b = blockIdx.x, t = threadIdx.x, i = b * 256 + t;
  __shared__ int tmp[256];
  int v = (i < n) ? deg[i] : 0;
  tmp[t] = v;
  __syncthreads();
  for (int off = 1; off < 256; off <<= 1) {
    int x = (t >= off) ? tmp[t - off] : 0;
    __syncthreads();
    tmp[t] += x;
    __syncthreads();
  }
  if (i < n) offs[i] = cpre[b] + tmp[t] - v;
}

__global__ void scatter_kernel(const void* __restrict__ edges, const int* __restrict__ flag,
                               const int* __restrict__ offs, int* __restrict__ fill,
                               int* __restrict__ srcS, int E, int Nn) {
  int wide = flag[0];
  for (int e = blockIdx.x * blockDim.x + threadIdx.x; e < E; e += gridDim.x * blockDim.x) {
    int s = edge_at(edges, wide, e);
    int d = edge_at(edges, wide, E + e);
    if (d < 0) d = 0; if (d >= Nn) d = Nn - 1;
    if (s < 0) s = 0; if (s >= Nn) s = Nn - 1;
    int p = offs[d] + atomicAdd(&fill[d], 1);
    if (p < 0) p = 0; if (p >= E) p = E - 1;
    srcS[p] = s;
  }
}

// ---------------- fused multi-section GEMM: out = [A|A2] @ Bcat (+bias) --------
// R11 config: 128x128 tile, acc 4x4, global_load_lds staging.
// R20: split-A staging — k < Ksplit reads A (stride Ksplit), k >= Ksplit reads A2
// (stride K-Ksplit). Lets h = [x|agg] @ [Wr;Wv] + b run as ONE GEMM: h written once,
// no read-modify-write accumulate pass. Pass Ksplit=K for unsplit GEMMs.
__global__ __launch_bounds__(256)
void gemm4_kernel(const ushort_t* __restrict__ A, const ushort_t* __restrict__ A2,
                  int Ksplit,
                  const ushort_t* __restrict__ BT,
                  ushort_t* __restrict__ o0, ushort_t* __restrict__ o1,
                  ushort_t* __restrict__ o2, ushort_t* __restrict__ o3,
                  const ushort_t* __restrict__ bias3,
                  int M, int K, int NC, int b0, int b1, int b2) {
  __shared__ __align__(16) ushort_t As[128 * 32];
  __shared__ __align__(16) ushort_t Bs[128 * 32];
  int tid = threadIdx.x;
  int lane = tid & 63, wave = tid >> 6;
  int tm = blockIdx.x * 128, tn = blockIdx.y * 128;
  int wm = (wave >> 1) * 64, wn = (wave & 1) * 64;
  int q = lane >> 4, l = lane & 15;
  f32x4 acc[4][4];
#pragma unroll
  for (int a = 0; a < 4; a++)
#pragma unroll
    for (int b = 0; b < 4; b++) acc[a][b] = (f32x4){0.f, 0.f, 0.f, 0.f};

  int lrow = lane >> 2, c8 = (lane & 3) * 8;
  for (int k0 = 0; k0 < K; k0 += 32) {
    const ushort_t* Ap; int kk, sA;
    if (k0 < Ksplit) { Ap = A;  kk = k0;          sA = Ksplit; }
    else             { Ap = A2; kk = k0 - Ksplit; sA = K - Ksplit; }
#pragma unroll
    for (int t = 0; t < 2; t++) {
      int chunk = t * 4 + wave;           // 0..7, 16 rows each
      int row = chunk * 16 + lrow;
      int ra = tm + row; if (ra > M - 1) ra = M - 1;
      async_copy16(&Ap[(size_t)ra * sA + kk + c8], &As[chunk * 512]);
      async_copy16(&BT[(size_t)(tn + row) * K + k0 + c8], &Bs[chunk * 512]);
    }
    __syncthreads();
    s16x8 af[4], bfr[4];
#pragma unroll
    for (int mf = 0; mf < 4; mf++) af[mf] = *(const s16x8*)&As[(wm + mf * 16 + l) * 32 + q * 8];
#pragma unroll
    for (int nf = 0; nf < 4; nf++) bfr[nf] = *(const s16x8*)&Bs[(wn + nf * 16 + l) * 32 + q * 8];
#pragma unroll
    for (int mf = 0; mf < 4; mf++)
#pragma unroll
      for (int nf = 0; nf < 4; nf++)
        acc[mf][nf] = __builtin_amdgcn_mfma_f32_16x16x32_bf16(af[mf], bfr[nf], acc[mf][nf], 0, 0, 0);
    __syncthreads();
  }
  // Hoisted section select (tile is 128-aligned; sections are 128-multiples).
  ushort_t* op; int sbase, w; bool addb = false;
  if (tn < b0)      { op = o0; sbase = 0;  w = b0; }
  else if (tn < b1) { op = o1; sbase = b0; w = b1 - b0; }
  else if (tn < b2) { op = o2; sbase = b1; w = b2 - b1; }
  else              { op = o3; sbase = b2; w = NC - b2; addb = true; }
  int lc0 = tn + wn - sbase + l;
  float bv[4];
#pragma unroll
  for (int nf = 0; nf < 4; nf++) bv[nf] = addb ? bf2f(bias3[lc0 + nf * 16]) : 0.f;
  // C/D layout: col = lane&15, row = (lane>>4)*4 + reg   [m89-verified]
#pragma unroll
  for (int mf = 0; mf < 4; mf++) {
#pragma unroll
    for (int j = 0; j < 4; j++) {
      int r = tm + wm + mf * 16 + q * 4 + j;
      if (r < M) {
#pragma unroll
        for (int nf = 0; nf < 4; nf++)
          op[(size_t)r * w + lc0 + nf * 16] = f2bf(acc[mf][nf][j] + bv[nf]);
      }
    }
  }
}

// ---------------- fused attention + aggregation, one WAVE per dst node ----------------
// R17: qt-factorization. logit = qt[d]·x[s]; agg = sum(w * x[s]) (Wv applied after).
// R18: 2-deep software pipeline — best measured config (72.6us, VGPR 44).
// [R19 post-mortem: batched-index loads hit VGPR 64 occupancy step; occ 44->35%,
//  dur +12%. Per-wave MLP trades ~1:1 vs occupancy here — REVERTED to R18.]
__global__ __launch_bounds__(256)
void attn_kernel(const ushort_t* __restrict__ qt, const ushort_t* __restrict__ x,
                 const int* __restrict__ offs, const int* __restrict__ srcS,
                 ushort_t* __restrict__ aggb, int D, int Nn) {
  int lane = threadIdx.x & 63, wave = threadIdx.x >> 6;
  int n = blockIdx.x * 4 + wave;
  if (n >= Nn) return;
  int g = lane >> 4, sub = lane & 15;

  int e0 = offs[n], e1 = offs[n + 1];
  float wsum = 0.f;

  if (D == 128) {  // 8 dims per lane
    s16x8 qv = __builtin_nontemporal_load((const s16x8*)(qt + (size_t)n * 128 + sub * 8));
    float qf[8];
#pragma unroll
    for (int i = 0; i < 8; i++) qf[i] = bf2f((unsigned short)qv[i]);
    float acc[8];
#pragma unroll
    for (int i = 0; i < 8; i++) acc[i] = 0.f;
    int j = e0;
    s16x8 xc;
    bool have = (j + 4 <= e1);
    if (have) {
      int s = __builtin_nontemporal_load(srcS + j + g);
      if (s < 0 || s >= Nn) s = 0;
      xc = *(const s16x8*)(x + (size_t)s * 128 + sub * 8);
    }
    for (; j + 8 <= e1; j += 4) {
      int s2 = __builtin_nontemporal_load(srcS + j + 4 + g);
      if (s2 < 0 || s2 >= Nn) s2 = 0;
      s16x8 xn = *(const s16x8*)(x + (size_t)s2 * 128 + sub * 8);
      float p = 0.f;
#pragma unroll
      for (int i = 0; i < 8; i++) p += qf[i] * bf2f((unsigned short)xc[i]);
      p += __shfl_xor(p, 1); p += __shfl_xor(p, 2);
      p += __shfl_xor(p, 4); p += __shfl_xor(p, 8);
      float w = __expf(p * 0.0625f);
      wsum += w;
#pragma unroll
      for (int i = 0; i < 8; i++) acc[i] += w * bf2f((unsigned short)xc[i]);
      xc = xn;
    }
    if (have) {
      float p = 0.f;
#pragma unroll
      for (int i = 0; i < 8; i++) p += qf[i] * bf2f((unsigned short)xc[i]);
      p += __shfl_xor(p, 1); p += __shfl_xor(p, 2);
      p += __shfl_xor(p, 4); p += __shfl_xor(p, 8);
      float w = __expf(p * 0.0625f);
      wsum += w;
#pragma unroll
      for (int i = 0; i < 8; i++) acc[i] += w * bf2f((unsigned short)xc[i]);
      j += 4;
    }
    int rem = e1 - j;
    if (rem > 0) {
      bool valid = g < rem;
      int s = __builtin_nontemporal_load(srcS + (valid ? (j + g) : j));
      if (s < 0 || s >= Nn) s = 0;
      s16x8 xv = *(const s16x8*)(x + (size_t)s * 128 + sub * 8);
      float p = 0.f;
#pragma unroll
      for (int i = 0; i < 8; i++) p += qf[i] * bf2f((unsigned short)xv[i]);
      p += __shfl_xor(p, 1); p += __shfl_xor(p, 2);
      p += __shfl_xor(p, 4); p += __shfl_xor(p, 8);
      float w = 0.f;
      if (valid) w = __expf(p * 0.0625f);
      wsum += w;
#pragma unroll
      for (int i = 0; i < 8; i++) acc[i] += w * bf2f((unsigned short)xv[i]);
    }
    wsum += __shfl_xor(wsum, 16); wsum += __shfl_xor(wsum, 32);
#pragma unroll
    for (int i = 0; i < 8; i++) {
      acc[i] += __shfl_xor(acc[i], 16);
      acc[i] += __shfl_xor(acc[i], 32);
    }
    float inv = 1.f / fmaxf(wsum, 1e-16f);
    if (g == 0) {
      s16x8 r0;
#pragma unroll
      for (int i = 0; i < 8; i++) r0[i] = (short)f2bf(acc[i] * inv);
      *(s16x8*)(aggb + (size_t)n * 128 + sub * 8) = r0;
    }
  } else {  // D == 256: 16 dims per lane
    s16x8 q0 = __builtin_nontemporal_load((const s16x8*)(qt + (size_t)n * 256 + sub * 16));
    s16x8 q1 = __builtin_nontemporal_load((const s16x8*)(qt + (size_t)n * 256 + sub * 16 + 8));
    float qf[16];
#pragma unroll
    for (int i = 0; i < 8; i++) {
      qf[i]     = bf2f((unsigned short)q0[i]);
      qf[8 + i] = bf2f((unsigned short)q1[i]);
    }
    float acc[16];
#pragma unroll
    for (int i = 0; i < 16; i++) acc[i] = 0.f;
    int j = e0;
    s16x8 x0c, x1c;
    bool have = (j + 4 <= e1);
    if (have) {
      int s = __builtin_nontemporal_load(srcS + j + g);
      if (s < 0 || s >= Nn) s = 0;
      const ushort_t* xp = x + (size_t)s * 256 + sub * 16;
      x0c = *(const s16x8*)xp; x1c = *(const s16x8*)(xp + 8);
    }
    for (; j + 8 <= e1; j += 4) {
      int s2 = __builtin_nontemporal_load(srcS + j + 4 + g);
      if (s2 < 0 || s2 >= Nn) s2 = 0;
      const ushort_t* xp2 = x + (size_t)s2 * 256 + sub * 16;
      s16x8 x0n = *(const s16x8*)xp2, x1n = *(const s16x8*)(xp2 + 8);
      float pa = 0.f, pb = 0.f;
#pragma unroll
      for (int i = 0; i < 8; i++) {
        pa += qf[i] * bf2f((unsigned short)x0c[i]);
        pb += qf[8 + i] * bf2f((unsigned short)x1c[i]);
      }
      float p = pa + pb;
      p += __shfl_xor(p, 1); p += __shfl_xor(p, 2);
      p += __shfl_xor(p, 4); p += __shfl_xor(p, 8);
      float w = __expf(p * 0.0625f);
      wsum += w;
#pragma unroll
      for (int i = 0; i < 8; i++) {
        acc[i]     += w * bf2f((unsigned short)x0c[i]);
        acc[8 + i] += w * bf2f((unsigned short)x1c[i]);
      }
      x0c = x0n; x1c = x1n;
    }
    if (have) {
      float pa = 0.f, pb = 0.f;
#pragma unroll
      for (int i = 0; i < 8; i++) {
        pa += qf[i] * bf2f((unsigned short)x0c[i]);
        pb += qf[8 + i] * bf2f((unsigned short)x1c[i]);
      }
      float p = pa + pb;
      p += __shfl_xor(p, 1); p += __shfl_xor(p, 2);
      p += __shfl_xor(p, 4); p += __shfl_xor(p, 8);
      float w = __expf(p * 0.0625f);
      wsum += w;
#pragma unroll
      for (int i = 0; i < 8; i++) {
        acc[i]     += w * bf2f((unsigned short)x0c[i]);
        acc[8 + i] += w * bf2f((unsigned short)x1c[i]);
      }
      j += 4;
    }
    int rem = e1 - j;
    if (rem > 0) {
      bool valid = g < rem;
      int s = __builtin_nontemporal_load(srcS + (valid ? (j + g) : j));
      if (s < 0 || s >= Nn) s = 0;
      const ushort_t* xp = x + (size_t)s * 256 + sub * 16;
      s16x8 x0v = *(const s16x8*)xp, x1v = *(const s16x8*)(xp + 8);
      float pa = 0.f, pb = 0.f;
#pragma unroll
      for (int i = 0; i < 8; i++) {
        pa += qf[i] * bf2f((unsigned short)x0v[i]);
        pb += qf[8 + i] * bf2f((unsigned short)x1v[i]);
      }
      float p = pa + pb;
      p += __shfl_xor(p, 1); p += __shfl_xor(p, 2);
      p += __shfl_xor(p, 4); p += __shfl_xor(p, 8);
      float w = 0.f;
      if (valid) w = __expf(p * 0.0625f);
      wsum += w;
#pragma unroll
      for (int i = 0; i < 8; i++) {
        acc[i]     += w * bf2f((unsigned short)x0v[i]);
        acc[8 + i] += w * bf2f((unsigned short)x1v[i]);
      }
    }
    wsum += __shfl_xor(wsum, 16); wsum += __shfl_xor(wsum, 32);
#pragma unroll
    for (int i = 0; i < 16; i++) {
      acc[i] += __shfl_xor(acc[i], 16);
      acc[i] += __shfl_xor(acc[i], 32);
    }
    float inv = 1.f / fmaxf(wsum, 1e-16f);
    if (g == 0) {
      s16x8 r0, r1;
#pragma unroll
      for (int i = 0; i < 8; i++) {
        r0[i] = (short)f2bf(acc[i] * inv);
        r1[i] = (short)f2bf(acc[8 + i] * inv);
      }
      size_t idx = (size_t)n * 256 + sub * 16;
      *(s16x8*)(aggb + idx) = r0;
      *(s16x8*)(aggb + idx + 8) = r1;
    }
  }
}

// ---------------- BatchNorm ----------------
__global__ void bn_stats_kernel(const ushort_t* __restrict__ h, float* __restrict__ sum,
                                float* __restrict__ sumsq, int N, int F) {
  int col = threadIdx.x;
  float s = 0.f, s2 = 0.f;
  for (int r = blockIdx.x; r < N; r += gridDim.x) {
    float x = bf2f(h[(size_t)r * F + col]);
    s += x; s2 += x * x;
  }
  atomicAdd(&sum[col], s);
  atomicAdd(&sumsq[col], s2);
}

// normalize+relu; each block recomputes scale/shift from sums (removes bn_final launch)
__global__ void norm_relu_kernel(const ushort_t* __restrict__ h,
                                 const float* __restrict__ sum, const float* __restrict__ sumsq,
                                 const ushort_t* __restrict__ g, const ushort_t* __restrict__ be,
                                 ushort_t* __restrict__ x1, int N, size_t total, int cmask) {
  __shared__ float sc[256], sh[256];
  int t = threadIdx.x;
  if (t <= cmask) {
    float mu = sum[t] / (float)N;
    float var = sumsq[t] / (float)N - mu * mu;
    float s = bf2f(g[t]) * rsqrtf(var + 1e-5f);
    sc[t] = s;
    sh[t] = bf2f(be[t]) - mu * s;
  }
  __syncthreads();
  for (size_t i = blockIdx.x * (size_t)blockDim.x + t; i < total;
       i += (size_t)gridDim.x * blockDim.x) {
    int c = (int)(i & (size_t)cmask);
    float vv = bf2f(h[i]) * sc[c] + sh[c];
    x1[i] = f2bf(relu_nanprop(vv));
  }
}

// final: BN + residual + relu, dual-dtype out; recomputes scale/shift per block
__global__ void final_kernel(const ushort_t* __restrict__ h,
                             const float* __restrict__ sum, const float* __restrict__ sumsq,
                             const ushort_t* __restrict__ g, const ushort_t* __restrict__ be,
                             const ushort_t* __restrict__ x0b, void* __restrict__ out,
                             const int* __restrict__ flagF, int N, size_t total) {
  __shared__ float sc[128], sh[128];
  int t = threadIdx.x;
  if (t < 128) {
    float mu = sum[t] / (float)N;
    float var = sumsq[t] / (float)N - mu * mu;
    float s = bf2f(g[t]) * rsqrtf(var + 1e-5f);
    sc[t] = s;
    sh[t] = bf2f(be[t]) - mu * s;
  }
  __syncthreads();
  int f = flagF[0];
  for (size_t i = blockIdx.x * (size_t)blockDim.x + t; i < total;
       i += (size_t)gridDim.x * blockDim.x) {
    int c = (int)(i & 127);
    float vv = bf2f(h[i]) * sc[c] + sh[c] + bf2f(x0b[i]);
    vv = relu_nanprop(vv);
    if (f) ((float*)out)[i] = vv;
    else   ((ushort_t*)out)[i] = f2bf(vv);
  }
}

extern "C" void kernel_launch(void* const* d_in, const int* in_sizes, int n_in,
                              void* d_out, int out_size, void* d_ws, size_t ws_size,
                              hipStream_t stream) {
  const void* x0  = d_in[0];
  const void* edges = d_in[1];
  const void* Wq1 = d_in[2];
  const void* Wk1 = d_in[3];
  const void* Wv1 = d_in[4];
  const void* Wr1 = d_in[5];
  const void* b1  = d_in[6];
  const void* gw1 = d_in[7];
  const void* bw1 = d_in[8];
  const void* Wq2 = d_in[9];
  const void* Wk2 = d_in[10];
  const void* Wv2 = d_in[11];
  const void* Wr2 = d_in[12];
  const void* b2  = d_in[13];
  const void* gw2 = d_in[14];
  const void* bw2 = d_in[15];

  int N = in_sizes[0] / 128;
  int E = in_sizes[1] / 2;
  int NCHUNK = (N + 255) / 256;
  int MT = (N + 127) / 128;

  uintptr_t base = (uintptr_t)d_ws;
  auto carve = [&](size_t bytes) -> void* {
    uintptr_t p = base;
    base += (bytes + 255) & ~(size_t)255;
    return (void*)p;
  };
  ushort_t* x0b = (ushort_t*)carve((size_t)N * 128 * 2);
  ushort_t* qtb = (ushort_t*)carve((size_t)N * 256 * 2);   // qt1 (128) / qt2 (256)
  ushort_t* aggb = (ushort_t*)carve((size_t)N * 256 * 2);  // agg output (128/256)
  ushort_t* hb = (ushort_t*)carve((size_t)N * 256 * 2);
  ushort_t* x1 = (ushort_t*)carve((size_t)N * 256 * 2);
  ushort_t* Wq1b = (ushort_t*)carve((size_t)128 * 256 * 2);
  ushort_t* Wk1b = (ushort_t*)carve((size_t)128 * 256 * 2);
  ushort_t* wcatQ1 = (ushort_t*)carve((size_t)128 * 128 * 2);  // M1^T
  ushort_t* wcatH1 = (ushort_t*)carve((size_t)256 * 256 * 2);  // [Wr1^T | Wv1^T]
  ushort_t* Wq2b = (ushort_t*)carve((size_t)256 * 256 * 2);
  ushort_t* Wk2b = (ushort_t*)carve((size_t)256 * 256 * 2);
  ushort_t* wcatQ2 = (ushort_t*)carve((size_t)256 * 256 * 2);  // M2^T
  ushort_t* wcatH2 = (ushort_t*)carve((size_t)128 * 512 * 2);  // [Wr2^T | Wv2^T]
  ushort_t* b1b  = (ushort_t*)carve(256 * 2);
  ushort_t* g1b  = (ushort_t*)carve(256 * 2);
  ushort_t* be1b = (ushort_t*)carve(256 * 2);
  ushort_t* b2b  = (ushort_t*)carve(128 * 2);
  ushort_t* g2b  = (ushort_t*)carve(128 * 2);
  ushort_t* be2b = (ushort_t*)carve(128 * 2);
  int* offs = (int*)carve((size_t)(N + 1) * 4);
  int* srcS = (int*)carve((size_t)E * 4);
  int* csum = (int*)carve(256 * 4);
  int* cpre = (int*)carve(256 * 4);
  // zeroed region: deg(N) fill(N) sums(1024 floats)
  int nzero = 2 * N + 1024;
  int* zreg2 = (int*)carve((size_t)nzero * 4);
  int* deg   = zreg2;
  int* fill  = zreg2 + N;
  float* sum1 = (float*)(zreg2 + 2 * N);
  float* sq1  = sum1 + 256;
  float* sum2 = sum1 + 512;
  float* sq2  = sum1 + 640;
  int* eflag = (int*)carve(256);   // [0]=edge wide, [1]=float32 flag (setup writes)
  int* fF = eflag + 1;

  size_t needed = base - (uintptr_t)d_ws;
  if (needed > ws_size) return;

  // 1: zero + dtype detects
  setup_kernel<<<258, 256, 0, stream>>>(zreg2, N, (const int*)edges, 2 * E, eflag,
                                        (const unsigned int*)x0, N * 128, fF);
  // 2: x0 cvt + params + weight prep + hist
  cvt_all_kernel<<<6145, 256, 0, stream>>>(x0, x0b, N * 128,
                                           b1, gw1, bw1, b2, gw2, bw2,
                                           b1b, g1b, be1b, b2b, g2b, be2b,
                                           Wq1, Wk1, Wv1, Wr1, Wq1b, Wk1b, wcatH1,
                                           Wq2, Wk2, Wv2, Wr2, Wq2b, Wk2b, wcatH2,
                                           edges, deg, E, N, eflag, fF);
  // 3-6: scan + scatter
  chunk_sum_kernel<<<NCHUNK, 256, 0, stream>>>(deg, csum, N);
  scan_small_kernel<<<1, 256, 0, stream>>>(csum, cpre, NCHUNK, offs, N);
  scan_final_kernel<<<NCHUNK, 256, 0, stream>>>(deg, cpre, offs, N);
  scatter_kernel<<<1024, 256, 0, stream>>>(edges, eflag, offs, fill, srcS, E, N);

  // M1^T = Wk1 @ Wq1^T -> wcatQ1;  M2^T = Wk2 @ Wq2^T -> wcatQ2
  gemm4_kernel<<<dim3(1, 1), 256, 0, stream>>>(Wk1b, Wk1b, 256, Wq1b,
                                               wcatQ1, wcatQ1, wcatQ1, wcatQ1,
                                               b1b, 128, 256, 128, 128, 128, 128);
  gemm4_kernel<<<dim3(2, 2), 256, 0, stream>>>(Wk2b, Wk2b, 256, Wq2b,
                                               wcatQ2, wcatQ2, wcatQ2, wcatQ2,
                                               b1b, 256, 256, 256, 256, 256, 256);

  int gAttn = (N + 3) / 4;        // one wave per node
  // Layer 1: qt1 = x0 @ M1^T;  attn;  h = [x0|agg] @ [Wr1;Wv1] + b1
  gemm4_kernel<<<dim3(MT, 1), 256, 0, stream>>>(x0b, x0b, 128, wcatQ1,
                                                qtb, qtb, qtb, qtb,
                                                b1b, N, 128, 128, 128, 128, 128);
  attn_kernel<<<gAttn, 256, 0, stream>>>(qtb, x0b, offs, srcS, aggb, 128, N);
  gemm4_kernel<<<dim3(MT, 2), 256, 0, stream>>>(x0b, aggb, 128, wcatH1,
                                                hb, hb, hb, hb,
                                                b1b, N, 256, 256, 0, 0, 0);
  bn_stats_kernel<<<512, 256, 0, stream>>>(hb, sum1, sq1, N, 256);
  norm_relu_kernel<<<4096, 256, 0, stream>>>(hb, sum1, sq1, g1b, be1b, x1, N,
                                             (size_t)N * 256, 255);
  // Layer 2: qt2 = x1 @ M2^T;  attn;  h = [x1|agg] @ [Wr2;Wv2] + b2
  gemm4_kernel<<<dim3(MT, 2), 256, 0, stream>>>(x1, x1, 256, wcatQ2,
                                                qtb, qtb, qtb, qtb,
                                                b2b, N, 256, 256, 256, 256, 256);
  attn_kernel<<<gAttn, 256, 0, stream>>>(qtb, x1, offs, srcS, aggb, 256, N);
  gemm4_kernel<<<dim3(MT, 1), 256, 0, stream>>>(x1, aggb, 256, wcatH2,
                                                hb, hb, hb, hb,
                                                b2b, N, 512, 128, 0, 0, 0);
  bn_stats_kernel<<<512, 128, 0, stream>>>(hb, sum2, sq2, N, 128);
  final_kernel<<<4096, 256, 0, stream>>>(hb, sum2, sq2, g2b, be2b, x0b, d_out, fF, N,
                                         (size_t)N * 128);
}

// Round 8
// 476.138 us; speedup vs baseline: 1.1729x; 1.0655x over previous
//
#include <hip/hip_runtime.h>
#include <stdint.h>

typedef unsigned short ushort_t;

__device__ __forceinline__ float bf2f(unsigned short u) {
  union { unsigned int i; float f; } c; c.i = ((unsigned int)u) << 16; return c.f;
}
__device__ __forceinline__ unsigned short f2bf(float f) {
  union { float f; unsigned int i; } c; c.f = f;
  unsigned int r = c.i + 0x7FFFu + ((c.i >> 16) & 1u);
  return (unsigned short)(r >> 16);
}
// NaN-propagating relu (tripwire: NaN stays visible)
__device__ __forceinline__ float relu_nanprop(float v) { return (v < 0.f) ? 0.f : v; }

// async global->LDS 16B copy: LDS dest = wave-uniform base + lane*16 (HW-implicit)
__device__ __forceinline__ void async_copy16(const void* g, void* l) {
  __builtin_amdgcn_global_load_lds(
      (const __attribute__((address_space(1))) unsigned int*)(uintptr_t)g,
      (__attribute__((address_space(3))) unsigned int*)(uintptr_t)l,
      16, 0, 0);
}

typedef __attribute__((ext_vector_type(8))) short s16x8;
typedef __attribute__((ext_vector_type(4))) float f32x4;

__device__ __forceinline__ int edge_at(const void* edges, int wide, int idx) {
  if (wide) return (int)((const long long*)edges)[idx];
  return ((const int*)edges)[idx];
}

// ---------------- setup: zero scratch + dtype detects (1 launch) ----------------
__global__ void setup_kernel(int* __restrict__ zreg2, int N,
                             const int* __restrict__ e32, int n32, int* __restrict__ eflag,
                             const unsigned int* __restrict__ x, int nw, int* __restrict__ fF) {
  int b = blockIdx.x, tid = threadIdx.x;
  if (b < 256) {
    int total = 2 * N + 1024;
    for (int i = b * 256 + tid; i < total; i += 256 * 256) zreg2[i] = 0;
  } else if (b == 256) {
    __shared__ int any;
    if (tid == 0) any = 0;
    __syncthreads();
    for (int i = tid; i < 4096; i += 256) {
      int idx = 2 * i + 1;
      if (idx < n32 && e32[idx] != 0) any = 1;
    }
    __syncthreads();
    if (tid == 0) eflag[0] = (any == 0) ? 1 : 0;  // 1 => int64
  } else {
    __shared__ int cnt;
    if (tid == 0) cnt = 0;
    __syncthreads();
    int local = 0;
    for (int i = tid; i < 4096 && i < nw; i += 256) {
      unsigned int low = x[i] & 0xFFFFu;
      unsigned int e = (low >> 7) & 0xFFu;
      if (low != 0u && (e < 96u || e > 144u)) local++;
    }
    atomicAdd(&cnt, local);
    __syncthreads();
    if (tid == 0) fF[0] = (cnt > 1024) ? 1 : 0;  // 1 => float32 inputs
  }
}

// ---------------- cvt_all: x0 cvt + params + weight prep + hist (1 launch) ----------
// R20 weight prep:
//  Wq*b / Wk*b: straight bf16 copies (inputs to on-device M = Wk @ Wq^T GEMM)
//  wcatH*: [Wr^T | Wv^T] concatenated along K — BT[c][k<D]=Wr[k][c], BT[c][D+k]=Wv[k][c]
//  (wcatQ* rows are filled by the M-GEMM on device)
__global__ void cvt_all_kernel(const void* __restrict__ x0, ushort_t* __restrict__ x0b, int nx,
                               const void* p0, const void* p1, const void* p2,
                               const void* p3, const void* p4, const void* p5,
                               ushort_t* o0, ushort_t* o1, ushort_t* o2,
                               ushort_t* o3, ushort_t* o4, ushort_t* o5,
                               const void* W10, const void* W11, const void* W12, const void* W13,
                               ushort_t* __restrict__ Wq1b, ushort_t* __restrict__ Wk1b,
                               ushort_t* __restrict__ wcatH1,
                               const void* W20, const void* W21, const void* W22, const void* W23,
                               ushort_t* __restrict__ Wq2b, ushort_t* __restrict__ Wk2b,
                               ushort_t* __restrict__ wcatH2,
                               const void* __restrict__ edges, int* __restrict__ deg,
                               int E, int Nn,
                               const int* __restrict__ eflag, const int* __restrict__ fF) {
  int b = blockIdx.x, tid = threadIdx.x;
  int f = fF[0];
  if (b < 4096) {
    for (int i = b * 256 + tid; i < nx; i += 4096 * 256)
      x0b[i] = f ? f2bf(((const float*)x0)[i]) : ((const ushort_t*)x0)[i];
  } else if (b == 4096) {
    const void* ins[6] = {p0, p1, p2, p3, p4, p5};
    ushort_t* outs[6] = {o0, o1, o2, o3, o4, o5};
    const int segs[7] = {0, 256, 512, 768, 896, 1024, 1152};
    for (int i = tid; i < 1152; i += 256) {
      int s = 0;
      while (i >= segs[s + 1]) s++;
      int li = i - segs[s];
      outs[s][li] = f ? f2bf(((const float*)ins[s])[li]) : ((const ushort_t*)ins[s])[li];
    }
  } else if (b < 4609) {
    // layer-1: Wq1[128][256], Wk1[128][256] straight;
    // Wr1[128][256] -> wcatH1[c][k]  (k<128);  Wv1[128][256] -> wcatH1[c][128+k].
    for (int i = (b - 4097) * 256 + tid; i < 131072; i += 512 * 256) {
      if (i < 32768) {
        Wq1b[i] = f ? f2bf(((const float*)W10)[i]) : ((const ushort_t*)W10)[i];
      } else if (i < 65536) {
        int r = i - 32768;
        Wk1b[r] = f ? f2bf(((const float*)W11)[r]) : ((const ushort_t*)W11)[r];
      } else if (i < 98304) {
        int rem = i - 65536, k = rem >> 8, c = rem & 255;  // Wr1[k][c]
        ushort_t v = f ? f2bf(((const float*)W13)[rem]) : ((const ushort_t*)W13)[rem];
        wcatH1[(size_t)c * 256 + k] = v;
      } else {
        int rem = i - 98304, k = rem >> 8, c = rem & 255;  // Wv1[k][c]
        ushort_t v = f ? f2bf(((const float*)W12)[rem]) : ((const ushort_t*)W12)[rem];
        wcatH1[(size_t)c * 256 + 128 + k] = v;
      }
    }
  } else if (b < 5121) {
    // layer-2: Wq2[256][256], Wk2[256][256] straight;
    // Wr2[256][128] -> wcatH2[c][k] (k<256);  Wv2[256][128] -> wcatH2[c][256+k].
    for (int i = (b - 4609) * 256 + tid; i < 196608; i += 512 * 256) {
      if (i < 65536) {
        Wq2b[i] = f ? f2bf(((const float*)W20)[i]) : ((const ushort_t*)W20)[i];
      } else if (i < 131072) {
        int r = i - 65536;
        Wk2b[r] = f ? f2bf(((const float*)W21)[r]) : ((const ushort_t*)W21)[r];
      } else if (i < 163840) {
        int rem = i - 131072, k = rem >> 7, c = rem & 127;  // Wr2[k][c]
        ushort_t v = f ? f2bf(((const float*)W23)[rem]) : ((const ushort_t*)W23)[rem];
        wcatH2[(size_t)c * 512 + k] = v;
      } else {
        int rem = i - 163840, k = rem >> 7, c = rem & 127;  // Wv2[k][c]
        ushort_t v = f ? f2bf(((const float*)W22)[rem]) : ((const ushort_t*)W22)[rem];
        wcatH2[(size_t)c * 512 + 256 + k] = v;
      }
    }
  } else {  // hist: 1024 blocks
    int wide = eflag[0];
    for (int e = (b - 5121) * 256 + tid; e < E; e += 1024 * 256) {
      int d = edge_at(edges, wide, E + e);
      if (d < 0) d = 0; if (d >= Nn) d = Nn - 1;
      atomicAdd(&deg[d], 1);
    }
  }
}

// 3-phase parallel scan (chunk = 256): supports N <= 65536
__global__ void chunk_sum_kernel(const int* __restrict__ deg, int* __restrict__ csum, int n) {
  int b = blockIdx.x, t = threadIdx.x, i = b * 256 + t;
  int v = (i < n) ? deg[i] : 0;
  __shared__ int ws[4];
#pragma unroll
  for (int o = 32; o > 0; o >>= 1) v += __shfl_down(v, o);
  if ((t & 63) == 0) ws[t >> 6] = v;
  __syncthreads();
  if (t == 0) csum[b] = ws[0] + ws[1] + ws[2] + ws[3];
}

__global__ void scan_small_kernel(const int* __restrict__ csum, int* __restrict__ cpre,
                                  int nc, int* __restrict__ offs, int N) {
  __shared__ int tmp[256];
  int t = threadIdx.x;
  int v = (t < nc) ? csum[t] : 0;
  tmp[t] = v;
  __syncthreads();
  for (int off = 1; off < 256; off <<= 1) {
    int x = (t >= off) ? tmp[t - off] : 0;
    __syncthreads();
    tmp[t] += x;
    __syncthreads();
  }
  if (t < nc) cpre[t] = tmp[t] - v;
  if (t == 255) offs[N] = tmp[255];
}

__global__ void scan_final_kernel(const int* __restrict__ deg, const int* __restrict__ cpre,
                                  int* __restrict__ offs, int n) {
  int b = blockIdx.x, t = threadIdx.x, i = b * 256 + t;
  __shared__ int tmp[256];
  int v = (i < n) ? deg[i] : 0;
  tmp[t] = v;
  __syncthreads();
  for (int off = 1; off < 256; off <<= 1) {
    int x = (t >= off) ? tmp[t - off] : 0;
    __syncthreads();
    tmp[t] += x;
    __syncthreads();
  }
  if (i < n) offs[i] = cpre[b] + tmp[t] - v;
}

__global__ void scatter_kernel(const void* __restrict__ edges, const int* __restrict__ flag,
                               const int* __restrict__ offs, int* __restrict__ fill,
                               int* __restrict__ srcS, int E, int Nn) {
  int wide = flag[0];
  for (int e = blockIdx.x * blockDim.x + threadIdx.x; e < E; e += gridDim.x * blockDim.x) {
    int s = edge_at(edges, wide, e);
    int d = edge_at(edges, wide, E + e);
    if (d < 0) d = 0; if (d >= Nn) d = Nn - 1;
    if (s < 0) s = 0; if (s >= Nn) s = Nn - 1;
    int p = offs[d] + atomicAdd(&fill[d], 1);
    if (p < 0) p = 0; if (p >= E) p = E - 1;
    srcS[p] = s;
  }
}

// ---------------- fused multi-section GEMM: out = [A|A2] @ Bcat (+bias) --------
// R11 config: 128x128 tile, acc 4x4, global_load_lds staging.
// R20: split-A staging (Ksplit). R21: optional fused BN-stats — epilogue reduces
// per-column sum/sumsq from the f32 accumulators (shfl over q-lanes sharing a col)
// and atomicAdds once per lane<16. Removes the bn_stats re-read pass entirely.
__global__ __launch_bounds__(256)
void gemm4_kernel(const ushort_t* __restrict__ A, const ushort_t* __restrict__ A2,
                  int Ksplit,
                  const ushort_t* __restrict__ BT,
                  ushort_t* __restrict__ o0, ushort_t* __restrict__ o1,
                  ushort_t* __restrict__ o2, ushort_t* __restrict__ o3,
                  const ushort_t* __restrict__ bias3,
                  int M, int K, int NC, int b0, int b1, int b2,
                  float* __restrict__ bnsum, float* __restrict__ bnsq) {
  __shared__ __align__(16) ushort_t As[128 * 32];
  __shared__ __align__(16) ushort_t Bs[128 * 32];
  int tid = threadIdx.x;
  int lane = tid & 63, wave = tid >> 6;
  int tm = blockIdx.x * 128, tn = blockIdx.y * 128;
  int wm = (wave >> 1) * 64, wn = (wave & 1) * 64;
  int q = lane >> 4, l = lane & 15;
  f32x4 acc[4][4];
#pragma unroll
  for (int a = 0; a < 4; a++)
#pragma unroll
    for (int b = 0; b < 4; b++) acc[a][b] = (f32x4){0.f, 0.f, 0.f, 0.f};

  int lrow = lane >> 2, c8 = (lane & 3) * 8;
  for (int k0 = 0; k0 < K; k0 += 32) {
    const ushort_t* Ap; int kk, sA;
    if (k0 < Ksplit) { Ap = A;  kk = k0;          sA = Ksplit; }
    else             { Ap = A2; kk = k0 - Ksplit; sA = K - Ksplit; }
#pragma unroll
    for (int t = 0; t < 2; t++) {
      int chunk = t * 4 + wave;           // 0..7, 16 rows each
      int row = chunk * 16 + lrow;
      int ra = tm + row; if (ra > M - 1) ra = M - 1;
      async_copy16(&Ap[(size_t)ra * sA + kk + c8], &As[chunk * 512]);
      async_copy16(&BT[(size_t)(tn + row) * K + k0 + c8], &Bs[chunk * 512]);
    }
    __syncthreads();
    s16x8 af[4], bfr[4];
#pragma unroll
    for (int mf = 0; mf < 4; mf++) af[mf] = *(const s16x8*)&As[(wm + mf * 16 + l) * 32 + q * 8];
#pragma unroll
    for (int nf = 0; nf < 4; nf++) bfr[nf] = *(const s16x8*)&Bs[(wn + nf * 16 + l) * 32 + q * 8];
#pragma unroll
    for (int mf = 0; mf < 4; mf++)
#pragma unroll
      for (int nf = 0; nf < 4; nf++)
        acc[mf][nf] = __builtin_amdgcn_mfma_f32_16x16x32_bf16(af[mf], bfr[nf], acc[mf][nf], 0, 0, 0);
    __syncthreads();
  }
  // Hoisted section select (tile is 128-aligned; sections are 128-multiples).
  ushort_t* op; int sbase, w; bool addb = false;
  if (tn < b0)      { op = o0; sbase = 0;  w = b0; }
  else if (tn < b1) { op = o1; sbase = b0; w = b1 - b0; }
  else if (tn < b2) { op = o2; sbase = b1; w = b2 - b1; }
  else              { op = o3; sbase = b2; w = NC - b2; addb = true; }
  int lc0 = tn + wn - sbase + l;
  float bv[4];
#pragma unroll
  for (int nf = 0; nf < 4; nf++) bv[nf] = addb ? bf2f(bias3[lc0 + nf * 16]) : 0.f;
  float csum[4] = {0.f, 0.f, 0.f, 0.f}, csq[4] = {0.f, 0.f, 0.f, 0.f};
  // C/D layout: col = lane&15, row = (lane>>4)*4 + reg   [m89-verified]
#pragma unroll
  for (int mf = 0; mf < 4; mf++) {
#pragma unroll
    for (int j = 0; j < 4; j++) {
      int r = tm + wm + mf * 16 + q * 4 + j;
      if (r < M) {
#pragma unroll
        for (int nf = 0; nf < 4; nf++) {
          float v = acc[mf][nf][j] + bv[nf];
          op[(size_t)r * w + lc0 + nf * 16] = f2bf(v);
          csum[nf] += v;
          csq[nf]  += v * v;
        }
      }
    }
  }
  if (bnsum) {
    // lanes l, l+16, l+32, l+48 share columns {lc0+nf*16}; reduce then atomicAdd once
#pragma unroll
    for (int nf = 0; nf < 4; nf++) {
      csum[nf] += __shfl_xor(csum[nf], 16); csum[nf] += __shfl_xor(csum[nf], 32);
      csq[nf]  += __shfl_xor(csq[nf], 16);  csq[nf]  += __shfl_xor(csq[nf], 32);
    }
    if (q == 0) {
#pragma unroll
      for (int nf = 0; nf < 4; nf++) {
        atomicAdd(&bnsum[lc0 + nf * 16], csum[nf]);
        atomicAdd(&bnsq[lc0 + nf * 16],  csq[nf]);
      }
    }
  }
}

// ---------------- fused attention + aggregation, one WAVE per dst node ----------------
// R17: qt-factorization. logit = qt[d]·x[s]; agg = sum(w * x[s]) (Wv applied after).
// R18: 2-deep software pipeline — best measured config (72.6us, VGPR 44).
// [R19 post-mortem: batched-index loads hit VGPR 64 occupancy step; occ 44->35%,
//  dur +12%. Per-wave MLP trades ~1:1 vs occupancy here — REVERTED to R18.]
// R21: nontemporal agg stores (don't evict the x gather set from L2).
__global__ __launch_bounds__(256)
void attn_kernel(const ushort_t* __restrict__ qt, const ushort_t* __restrict__ x,
                 const int* __restrict__ offs, const int* __restrict__ srcS,
                 ushort_t* __restrict__ aggb, int D, int Nn) {
  int lane = threadIdx.x & 63, wave = threadIdx.x >> 6;
  int n = blockIdx.x * 4 + wave;
  if (n >= Nn) return;
  int g = lane >> 4, sub = lane & 15;

  int e0 = offs[n], e1 = offs[n + 1];
  float wsum = 0.f;

  if (D == 128) {  // 8 dims per lane
    s16x8 qv = __builtin_nontemporal_load((const s16x8*)(qt + (size_t)n * 128 + sub * 8));
    float qf[8];
#pragma unroll
    for (int i = 0; i < 8; i++) qf[i] = bf2f((unsigned short)qv[i]);
    float acc[8];
#pragma unroll
    for (int i = 0; i < 8; i++) acc[i] = 0.f;
    int j = e0;
    s16x8 xc;
    bool have = (j + 4 <= e1);
    if (have) {
      int s = __builtin_nontemporal_load(srcS + j + g);
      if (s < 0 || s >= Nn) s = 0;
      xc = *(const s16x8*)(x + (size_t)s * 128 + sub * 8);
    }
    for (; j + 8 <= e1; j += 4) {
      int s2 = __builtin_nontemporal_load(srcS + j + 4 + g);
      if (s2 < 0 || s2 >= Nn) s2 = 0;
      s16x8 xn = *(const s16x8*)(x + (size_t)s2 * 128 + sub * 8);
      float p = 0.f;
#pragma unroll
      for (int i = 0; i < 8; i++) p += qf[i] * bf2f((unsigned short)xc[i]);
      p += __shfl_xor(p, 1); p += __shfl_xor(p, 2);
      p += __shfl_xor(p, 4); p += __shfl_xor(p, 8);
      float w = __expf(p * 0.0625f);
      wsum += w;
#pragma unroll
      for (int i = 0; i < 8; i++) acc[i] += w * bf2f((unsigned short)xc[i]);
      xc = xn;
    }
    if (have) {
      float p = 0.f;
#pragma unroll
      for (int i = 0; i < 8; i++) p += qf[i] * bf2f((unsigned short)xc[i]);
      p += __shfl_xor(p, 1); p += __shfl_xor(p, 2);
      p += __shfl_xor(p, 4); p += __shfl_xor(p, 8);
      float w = __expf(p * 0.0625f);
      wsum += w;
#pragma unroll
      for (int i = 0; i < 8; i++) acc[i] += w * bf2f((unsigned short)xc[i]);
      j += 4;
    }
    int rem = e1 - j;
    if (rem > 0) {
      bool valid = g < rem;
      int s = __builtin_nontemporal_load(srcS + (valid ? (j + g) : j));
      if (s < 0 || s >= Nn) s = 0;
      s16x8 xv = *(const s16x8*)(x + (size_t)s * 128 + sub * 8);
      float p = 0.f;
#pragma unroll
      for (int i = 0; i < 8; i++) p += qf[i] * bf2f((unsigned short)xv[i]);
      p += __shfl_xor(p, 1); p += __shfl_xor(p, 2);
      p += __shfl_xor(p, 4); p += __shfl_xor(p, 8);
      float w = 0.f;
      if (valid) w = __expf(p * 0.0625f);
      wsum += w;
#pragma unroll
      for (int i = 0; i < 8; i++) acc[i] += w * bf2f((unsigned short)xv[i]);
    }
    wsum += __shfl_xor(wsum, 16); wsum += __shfl_xor(wsum, 32);
#pragma unroll
    for (int i = 0; i < 8; i++) {
      acc[i] += __shfl_xor(acc[i], 16);
      acc[i] += __shfl_xor(acc[i], 32);
    }
    float inv = 1.f / fmaxf(wsum, 1e-16f);
    if (g == 0) {
      s16x8 r0;
#pragma unroll
      for (int i = 0; i < 8; i++) r0[i] = (short)f2bf(acc[i] * inv);
      __builtin_nontemporal_store(r0, (s16x8*)(aggb + (size_t)n * 128 + sub * 8));
    }
  } else {  // D == 256: 16 dims per lane
    s16x8 q0 = __builtin_nontemporal_load((const s16x8*)(qt + (size_t)n * 256 + sub * 16));
    s16x8 q1 = __builtin_nontemporal_load((const s16x8*)(qt + (size_t)n * 256 + sub * 16 + 8));
    float qf[16];
#pragma unroll
    for (int i = 0; i < 8; i++) {
      qf[i]     = bf2f((unsigned short)q0[i]);
      qf[8 + i] = bf2f((unsigned short)q1[i]);
    }
    float acc[16];
#pragma unroll
    for (int i = 0; i < 16; i++) acc[i] = 0.f;
    int j = e0;
    s16x8 x0c, x1c;
    bool have = (j + 4 <= e1);
    if (have) {
      int s = __builtin_nontemporal_load(srcS + j + g);
      if (s < 0 || s >= Nn) s = 0;
      const ushort_t* xp = x + (size_t)s * 256 + sub * 16;
      x0c = *(const s16x8*)xp; x1c = *(const s16x8*)(xp + 8);
    }
    for (; j + 8 <= e1; j += 4) {
      int s2 = __builtin_nontemporal_load(srcS + j + 4 + g);
      if (s2 < 0 || s2 >= Nn) s2 = 0;
      const ushort_t* xp2 = x + (size_t)s2 * 256 + sub * 16;
      s16x8 x0n = *(const s16x8*)xp2, x1n = *(const s16x8*)(xp2 + 8);
      float pa = 0.f, pb = 0.f;
#pragma unroll
      for (int i = 0; i < 8; i++) {
        pa += qf[i] * bf2f((unsigned short)x0c[i]);
        pb += qf[8 + i] * bf2f((unsigned short)x1c[i]);
      }
      float p = pa + pb;
      p += __shfl_xor(p, 1); p += __shfl_xor(p, 2);
      p += __shfl_xor(p, 4); p += __shfl_xor(p, 8);
      float w = __expf(p * 0.0625f);
      wsum += w;
#pragma unroll
      for (int i = 0; i < 8; i++) {
        acc[i]     += w * bf2f((unsigned short)x0c[i]);
        acc[8 + i] += w * bf2f((unsigned short)x1c[i]);
      }
      x0c = x0n; x1c = x1n;
    }
    if (have) {
      float pa = 0.f, pb = 0.f;
#pragma unroll
      for (int i = 0; i < 8; i++) {
        pa += qf[i] * bf2f((unsigned short)x0c[i]);
        pb += qf[8 + i] * bf2f((unsigned short)x1c[i]);
      }
      float p = pa + pb;
      p += __shfl_xor(p, 1); p += __shfl_xor(p, 2);
      p += __shfl_xor(p, 4); p += __shfl_xor(p, 8);
      float w = __expf(p * 0.0625f);
      wsum += w;
#pragma unroll
      for (int i = 0; i < 8; i++) {
        acc[i]     += w * bf2f((unsigned short)x0c[i]);
        acc[8 + i] += w * bf2f((unsigned short)x1c[i]);
      }
      j += 4;
    }
    int rem = e1 - j;
    if (rem > 0) {
      bool valid = g < rem;
      int s = __builtin_nontemporal_load(srcS + (valid ? (j + g) : j));
      if (s < 0 || s >= Nn) s = 0;
      const ushort_t* xp = x + (size_t)s * 256 + sub * 16;
      s16x8 x0v = *(const s16x8*)xp, x1v = *(const s16x8*)(xp + 8);
      float pa = 0.f, pb = 0.f;
#pragma unroll
      for (int i = 0; i < 8; i++) {
        pa += qf[i] * bf2f((unsigned short)x0v[i]);
        pb += qf[8 + i] * bf2f((unsigned short)x1v[i]);
      }
      float p = pa + pb;
      p += __shfl_xor(p, 1); p += __shfl_xor(p, 2);
      p += __shfl_xor(p, 4); p += __shfl_xor(p, 8);
      float w = 0.f;
      if (valid) w = __expf(p * 0.0625f);
      wsum += w;
#pragma unroll
      for (int i = 0; i < 8; i++) {
        acc[i]     += w * bf2f((unsigned short)x0v[i]);
        acc[8 + i] += w * bf2f((unsigned short)x1v[i]);
      }
    }
    wsum += __shfl_xor(wsum, 16); wsum += __shfl_xor(wsum, 32);
#pragma unroll
    for (int i = 0; i < 16; i++) {
      acc[i] += __shfl_xor(acc[i], 16);
      acc[i] += __shfl_xor(acc[i], 32);
    }
    float inv = 1.f / fmaxf(wsum, 1e-16f);
    if (g == 0) {
      s16x8 r0, r1;
#pragma unroll
      for (int i = 0; i < 8; i++) {
        r0[i] = (short)f2bf(acc[i] * inv);
        r1[i] = (short)f2bf(acc[8 + i] * inv);
      }
      size_t idx = (size_t)n * 256 + sub * 16;
      __builtin_nontemporal_store(r0, (s16x8*)(aggb + idx));
      __builtin_nontemporal_store(r1, (s16x8*)(aggb + idx + 8));
    }
  }
}

// normalize+relu; each block recomputes scale/shift from sums (removes bn_final launch)
__global__ void norm_relu_kernel(const ushort_t* __restrict__ h,
                                 const float* __restrict__ sum, const float* __restrict__ sumsq,
                                 const ushort_t* __restrict__ g, const ushort_t* __restrict__ be,
                                 ushort_t* __restrict__ x1, int N, size_t total, int cmask) {
  __shared__ float sc[256], sh[256];
  int t = threadIdx.x;
  if (t <= cmask) {
    float mu = sum[t] / (float)N;
    float var = sumsq[t] / (float)N - mu * mu;
    float s = bf2f(g[t]) * rsqrtf(var + 1e-5f);
    sc[t] = s;
    sh[t] = bf2f(be[t]) - mu * s;
  }
  __syncthreads();
  for (size_t i = blockIdx.x * (size_t)blockDim.x + t; i < total;
       i += (size_t)gridDim.x * blockDim.x) {
    int c = (int)(i & (size_t)cmask);
    float vv = bf2f(h[i]) * sc[c] + sh[c];
    x1[i] = f2bf(relu_nanprop(vv));
  }
}

// final: BN + residual + relu, dual-dtype out; recomputes scale/shift per block
__global__ void final_kernel(const ushort_t* __restrict__ h,
                             const float* __restrict__ sum, const float* __restrict__ sumsq,
                             const ushort_t* __restrict__ g, const ushort_t* __restrict__ be,
                             const ushort_t* __restrict__ x0b, void* __restrict__ out,
                             const int* __restrict__ flagF, int N, size_t total) {
  __shared__ float sc[128], sh[128];
  int t = threadIdx.x;
  if (t < 128) {
    float mu = sum[t] / (float)N;
    float var = sumsq[t] / (float)N - mu * mu;
    float s = bf2f(g[t]) * rsqrtf(var + 1e-5f);
    sc[t] = s;
    sh[t] = bf2f(be[t]) - mu * s;
  }
  __syncthreads();
  int f = flagF[0];
  for (size_t i = blockIdx.x * (size_t)blockDim.x + t; i < total;
       i += (size_t)gridDim.x * blockDim.x) {
    int c = (int)(i & 127);
    float vv = bf2f(h[i]) * sc[c] + sh[c] + bf2f(x0b[i]);
    vv = relu_nanprop(vv);
    if (f) ((float*)out)[i] = vv;
    else   ((ushort_t*)out)[i] = f2bf(vv);
  }
}

extern "C" void kernel_launch(void* const* d_in, const int* in_sizes, int n_in,
                              void* d_out, int out_size, void* d_ws, size_t ws_size,
                              hipStream_t stream) {
  const void* x0  = d_in[0];
  const void* edges = d_in[1];
  const void* Wq1 = d_in[2];
  const void* Wk1 = d_in[3];
  const void* Wv1 = d_in[4];
  const void* Wr1 = d_in[5];
  const void* b1  = d_in[6];
  const void* gw1 = d_in[7];
  const void* bw1 = d_in[8];
  const void* Wq2 = d_in[9];
  const void* Wk2 = d_in[10];
  const void* Wv2 = d_in[11];
  const void* Wr2 = d_in[12];
  const void* b2  = d_in[13];
  const void* gw2 = d_in[14];
  const void* bw2 = d_in[15];

  int N = in_sizes[0] / 128;
  int E = in_sizes[1] / 2;
  int NCHUNK = (N + 255) / 256;
  int MT = (N + 127) / 128;

  uintptr_t base = (uintptr_t)d_ws;
  auto carve = [&](size_t bytes) -> void* {
    uintptr_t p = base;
    base += (bytes + 255) & ~(size_t)255;
    return (void*)p;
  };
  ushort_t* x0b = (ushort_t*)carve((size_t)N * 128 * 2);
  ushort_t* qtb = (ushort_t*)carve((size_t)N * 256 * 2);   // qt1 (128) / qt2 (256)
  ushort_t* aggb = (ushort_t*)carve((size_t)N * 256 * 2);  // agg output (128/256)
  ushort_t* hb = (ushort_t*)carve((size_t)N * 256 * 2);
  ushort_t* x1 = (ushort_t*)carve((size_t)N * 256 * 2);
  ushort_t* Wq1b = (ushort_t*)carve((size_t)128 * 256 * 2);
  ushort_t* Wk1b = (ushort_t*)carve((size_t)128 * 256 * 2);
  ushort_t* wcatQ1 = (ushort_t*)carve((size_t)128 * 128 * 2);  // M1^T
  ushort_t* wcatH1 = (ushort_t*)carve((size_t)256 * 256 * 2);  // [Wr1^T | Wv1^T]
  ushort_t* Wq2b = (ushort_t*)carve((size_t)256 * 256 * 2);
  ushort_t* Wk2b = (ushort_t*)carve((size_t)256 * 256 * 2);
  ushort_t* wcatQ2 = (ushort_t*)carve((size_t)256 * 256 * 2);  // M2^T
  ushort_t* wcatH2 = (ushort_t*)carve((size_t)128 * 512 * 2);  // [Wr2^T | Wv2^T]
  ushort_t* b1b  = (ushort_t*)carve(256 * 2);
  ushort_t* g1b  = (ushort_t*)carve(256 * 2);
  ushort_t* be1b = (ushort_t*)carve(256 * 2);
  ushort_t* b2b  = (ushort_t*)carve(128 * 2);
  ushort_t* g2b  = (ushort_t*)carve(128 * 2);
  ushort_t* be2b = (ushort_t*)carve(128 * 2);
  int* offs = (int*)carve((size_t)(N + 1) * 4);
  int* srcS = (int*)carve((size_t)E * 4);
  int* csum = (int*)carve(256 * 4);
  int* cpre = (int*)carve(256 * 4);
  // zeroed region: deg(N) fill(N) sums(1024 floats)
  int nzero = 2 * N + 1024;
  int* zreg2 = (int*)carve((size_t)nzero * 4);
  int* deg   = zreg2;
  int* fill  = zreg2 + N;
  float* sum1 = (float*)(zreg2 + 2 * N);
  float* sq1  = sum1 + 256;
  float* sum2 = sum1 + 512;
  float* sq2  = sum1 + 640;
  int* eflag = (int*)carve(256);   // [0]=edge wide, [1]=float32 flag (setup writes)
  int* fF = eflag + 1;

  size_t needed = base - (uintptr_t)d_ws;
  if (needed > ws_size) return;

  // 1: zero + dtype detects
  setup_kernel<<<258, 256, 0, stream>>>(zreg2, N, (const int*)edges, 2 * E, eflag,
                                        (const unsigned int*)x0, N * 128, fF);
  // 2: x0 cvt + params + weight prep + hist
  cvt_all_kernel<<<6145, 256, 0, stream>>>(x0, x0b, N * 128,
                                           b1, gw1, bw1, b2, gw2, bw2,
                                           b1b, g1b, be1b, b2b, g2b, be2b,
                                           Wq1, Wk1, Wv1, Wr1, Wq1b, Wk1b, wcatH1,
                                           Wq2, Wk2, Wv2, Wr2, Wq2b, Wk2b, wcatH2,
                                           edges, deg, E, N, eflag, fF);
  // 3-6: scan + scatter
  chunk_sum_kernel<<<NCHUNK, 256, 0, stream>>>(deg, csum, N);
  scan_small_kernel<<<1, 256, 0, stream>>>(csum, cpre, NCHUNK, offs, N);
  scan_final_kernel<<<NCHUNK, 256, 0, stream>>>(deg, cpre, offs, N);
  scatter_kernel<<<1024, 256, 0, stream>>>(edges, eflag, offs, fill, srcS, E, N);

  // M1^T = Wk1 @ Wq1^T -> wcatQ1;  M2^T = Wk2 @ Wq2^T -> wcatQ2
  gemm4_kernel<<<dim3(1, 1), 256, 0, stream>>>(Wk1b, Wk1b, 256, Wq1b,
                                               wcatQ1, wcatQ1, wcatQ1, wcatQ1,
                                               b1b, 128, 256, 128, 128, 128, 128,
                                               nullptr, nullptr);
  gemm4_kernel<<<dim3(2, 2), 256, 0, stream>>>(Wk2b, Wk2b, 256, Wq2b,
                                               wcatQ2, wcatQ2, wcatQ2, wcatQ2,
                                               b1b, 256, 256, 256, 256, 256, 256,
                                               nullptr, nullptr);

  int gAttn = (N + 3) / 4;        // one wave per node
  // Layer 1: qt1 = x0 @ M1^T;  attn;  h = [x0|agg] @ [Wr1;Wv1] + b1 (+fused BN stats)
  gemm4_kernel<<<dim3(MT, 1), 256, 0, stream>>>(x0b, x0b, 128, wcatQ1,
                                                qtb, qtb, qtb, qtb,
                                                b1b, N, 128, 128, 128, 128, 128,
                                                nullptr, nullptr);
  attn_kernel<<<gAttn, 256, 0, stream>>>(qtb, x0b, offs, srcS, aggb, 128, N);
  gemm4_kernel<<<dim3(MT, 2), 256, 0, stream>>>(x0b, aggb, 128, wcatH1,
                                                hb, hb, hb, hb,
                                                b1b, N, 256, 256, 0, 0, 0,
                                                sum1, sq1);
  norm_relu_kernel<<<4096, 256, 0, stream>>>(hb, sum1, sq1, g1b, be1b, x1, N,
                                             (size_t)N * 256, 255);
  // Layer 2: qt2 = x1 @ M2^T;  attn;  h = [x1|agg] @ [Wr2;Wv2] + b2 (+fused BN stats)
  gemm4_kernel<<<dim3(MT, 2), 256, 0, stream>>>(x1, x1, 256, wcatQ2,
                                                qtb, qtb, qtb, qtb,
                                                b2b, N, 256, 256, 256, 256, 256,
                                                nullptr, nullptr);
  attn_kernel<<<gAttn, 256, 0, stream>>>(qtb, x1, offs, srcS, aggb, 256, N);
  gemm4_kernel<<<dim3(MT, 1), 256, 0, stream>>>(x1, aggb, 256, wcatH2,
                                                hb, hb, hb, hb,
                                                b2b, N, 512, 128, 0, 0, 0,
                                                sum2, sq2);
  final_kernel<<<4096, 256, 0, stream>>>(hb, sum2, sq2, g2b, be2b, x0b, d_out, fF, N,
                                         (size_t)N * 128);
}

// Round 9
// 471.571 us; speedup vs baseline: 1.1842x; 1.0097x over previous
//
#include <hip/hip_runtime.h>
#include <stdint.h>

typedef unsigned short ushort_t;

__device__ __forceinline__ float bf2f(unsigned short u) {
  union { unsigned int i; float f; } c; c.i = ((unsigned int)u) << 16; return c.f;
}
__device__ __forceinline__ unsigned short f2bf(float f) {
  union { float f; unsigned int i; } c; c.f = f;
  unsigned int r = c.i + 0x7FFFu + ((c.i >> 16) & 1u);
  return (unsigned short)(r >> 16);
}
// NaN-propagating relu (tripwire: NaN stays visible)
__device__ __forceinline__ float relu_nanprop(float v) { return (v < 0.f) ? 0.f : v; }

// async global->LDS 16B copy: LDS dest = wave-uniform base + lane*16 (HW-implicit)
__device__ __forceinline__ void async_copy16(const void* g, void* l) {
  __builtin_amdgcn_global_load_lds(
      (const __attribute__((address_space(1))) unsigned int*)(uintptr_t)g,
      (__attribute__((address_space(3))) unsigned int*)(uintptr_t)l,
      16, 0, 0);
}

typedef __attribute__((ext_vector_type(8))) short s16x8;
typedef __attribute__((ext_vector_type(4))) float f32x4;

__device__ __forceinline__ int edge_at(const void* edges, int wide, int idx) {
  if (wide) return (int)((const long long*)edges)[idx];
  return ((const int*)edges)[idx];
}

// ---------------- setup: zero scratch + dtype detects (1 launch) ----------------
__global__ void setup_kernel(int* __restrict__ zreg2, int N,
                             const int* __restrict__ e32, int n32, int* __restrict__ eflag,
                             const unsigned int* __restrict__ x, int nw, int* __restrict__ fF) {
  int b = blockIdx.x, tid = threadIdx.x;
  if (b < 256) {
    int total = 2 * N + 1024;
    for (int i = b * 256 + tid; i < total; i += 256 * 256) zreg2[i] = 0;
  } else if (b == 256) {
    __shared__ int any;
    if (tid == 0) any = 0;
    __syncthreads();
    for (int i = tid; i < 4096; i += 256) {
      int idx = 2 * i + 1;
      if (idx < n32 && e32[idx] != 0) any = 1;
    }
    __syncthreads();
    if (tid == 0) eflag[0] = (any == 0) ? 1 : 0;  // 1 => int64
  } else {
    __shared__ int cnt;
    if (tid == 0) cnt = 0;
    __syncthreads();
    int local = 0;
    for (int i = tid; i < 4096 && i < nw; i += 256) {
      unsigned int low = x[i] & 0xFFFFu;
      unsigned int e = (low >> 7) & 0xFFu;
      if (low != 0u && (e < 96u || e > 144u)) local++;
    }
    atomicAdd(&cnt, local);
    __syncthreads();
    if (tid == 0) fF[0] = (cnt > 1024) ? 1 : 0;  // 1 => float32 inputs
  }
}

// ---------------- cvt_all: x0 cvt + params + weight prep + hist (1 launch) ----------
// R20 weight prep: Wq*b/Wk*b straight; wcatH* = [Wr^T | Wv^T] K-concat.
// R22: x0 copy SKIPPED when input already bf16 (consumers select x0raw via fF);
// f32 path vectorized (float4 x2 -> short8).
__global__ void cvt_all_kernel(const void* __restrict__ x0, ushort_t* __restrict__ x0b, int nx,
                               const void* p0, const void* p1, const void* p2,
                               const void* p3, const void* p4, const void* p5,
                               ushort_t* o0, ushort_t* o1, ushort_t* o2,
                               ushort_t* o3, ushort_t* o4, ushort_t* o5,
                               const void* W10, const void* W11, const void* W12, const void* W13,
                               ushort_t* __restrict__ Wq1b, ushort_t* __restrict__ Wk1b,
                               ushort_t* __restrict__ wcatH1,
                               const void* W20, const void* W21, const void* W22, const void* W23,
                               ushort_t* __restrict__ Wq2b, ushort_t* __restrict__ Wk2b,
                               ushort_t* __restrict__ wcatH2,
                               const void* __restrict__ edges, int* __restrict__ deg,
                               int E, int Nn,
                               const int* __restrict__ eflag, const int* __restrict__ fF) {
  int b = blockIdx.x, tid = threadIdx.x;
  int f = fF[0];
  if (b < 4096) {
    if (f) {  // only convert when input is f32; bf16 inputs are used in place
      int nx8 = nx >> 3;
      for (int i = b * 256 + tid; i < nx8; i += 4096 * 256) {
        const float* src = (const float*)x0 + (size_t)i * 8;
        float4 a = *(const float4*)src;
        float4 c = *(const float4*)(src + 4);
        s16x8 r;
        r[0] = (short)f2bf(a.x); r[1] = (short)f2bf(a.y);
        r[2] = (short)f2bf(a.z); r[3] = (short)f2bf(a.w);
        r[4] = (short)f2bf(c.x); r[5] = (short)f2bf(c.y);
        r[6] = (short)f2bf(c.z); r[7] = (short)f2bf(c.w);
        *(s16x8*)(x0b + (size_t)i * 8) = r;
      }
    }
  } else if (b == 4096) {
    const void* ins[6] = {p0, p1, p2, p3, p4, p5};
    ushort_t* outs[6] = {o0, o1, o2, o3, o4, o5};
    const int segs[7] = {0, 256, 512, 768, 896, 1024, 1152};
    for (int i = tid; i < 1152; i += 256) {
      int s = 0;
      while (i >= segs[s + 1]) s++;
      int li = i - segs[s];
      outs[s][li] = f ? f2bf(((const float*)ins[s])[li]) : ((const ushort_t*)ins[s])[li];
    }
  } else if (b < 4609) {
    // layer-1: Wq1[128][256], Wk1[128][256] straight;
    // Wr1[128][256] -> wcatH1[c][k]  (k<128);  Wv1[128][256] -> wcatH1[c][128+k].
    for (int i = (b - 4097) * 256 + tid; i < 131072; i += 512 * 256) {
      if (i < 32768) {
        Wq1b[i] = f ? f2bf(((const float*)W10)[i]) : ((const ushort_t*)W10)[i];
      } else if (i < 65536) {
        int r = i - 32768;
        Wk1b[r] = f ? f2bf(((const float*)W11)[r]) : ((const ushort_t*)W11)[r];
      } else if (i < 98304) {
        int rem = i - 65536, k = rem >> 8, c = rem & 255;  // Wr1[k][c]
        ushort_t v = f ? f2bf(((const float*)W13)[rem]) : ((const ushort_t*)W13)[rem];
        wcatH1[(size_t)c * 256 + k] = v;
      } else {
        int rem = i - 98304, k = rem >> 8, c = rem & 255;  // Wv1[k][c]
        ushort_t v = f ? f2bf(((const float*)W12)[rem]) : ((const ushort_t*)W12)[rem];
        wcatH1[(size_t)c * 256 + 128 + k] = v;
      }
    }
  } else if (b < 5121) {
    // layer-2: Wq2[256][256], Wk2[256][256] straight;
    // Wr2[256][128] -> wcatH2[c][k] (k<256);  Wv2[256][128] -> wcatH2[c][256+k].
    for (int i = (b - 4609) * 256 + tid; i < 196608; i += 512 * 256) {
      if (i < 65536) {
        Wq2b[i] = f ? f2bf(((const float*)W20)[i]) : ((const ushort_t*)W20)[i];
      } else if (i < 131072) {
        int r = i - 65536;
        Wk2b[r] = f ? f2bf(((const float*)W21)[r]) : ((const ushort_t*)W21)[r];
      } else if (i < 163840) {
        int rem = i - 131072, k = rem >> 7, c = rem & 127;  // Wr2[k][c]
        ushort_t v = f ? f2bf(((const float*)W23)[rem]) : ((const ushort_t*)W23)[rem];
        wcatH2[(size_t)c * 512 + k] = v;
      } else {
        int rem = i - 163840, k = rem >> 7, c = rem & 127;  // Wv2[k][c]
        ushort_t v = f ? f2bf(((const float*)W22)[rem]) : ((const ushort_t*)W22)[rem];
        wcatH2[(size_t)c * 512 + 256 + k] = v;
      }
    }
  } else {  // hist: 1024 blocks
    int wide = eflag[0];
    for (int e = (b - 5121) * 256 + tid; e < E; e += 1024 * 256) {
      int d = edge_at(edges, wide, E + e);
      if (d < 0) d = 0; if (d >= Nn) d = Nn - 1;
      atomicAdd(&deg[d], 1);
    }
  }
}

// 3-phase parallel scan (chunk = 256): supports N <= 65536
__global__ void chunk_sum_kernel(const int* __restrict__ deg, int* __restrict__ csum, int n) {
  int b = blockIdx.x, t = threadIdx.x, i = b * 256 + t;
  int v = (i < n) ? deg[i] : 0;
  __shared__ int ws[4];
#pragma unroll
  for (int o = 32; o > 0; o >>= 1) v += __shfl_down(v, o);
  if ((t & 63) == 0) ws[t >> 6] = v;
  __syncthreads();
  if (t == 0) csum[b] = ws[0] + ws[1] + ws[2] + ws[3];
}

__global__ void scan_small_kernel(const int* __restrict__ csum, int* __restrict__ cpre,
                                  int nc, int* __restrict__ offs, int N) {
  __shared__ int tmp[256];
  int t = threadIdx.x;
  int v = (t < nc) ? csum[t] : 0;
  tmp[t] = v;
  __syncthreads();
  for (int off = 1; off < 256; off <<= 1) {
    int x = (t >= off) ? tmp[t - off] : 0;
    __syncthreads();
    tmp[t] += x;
    __syncthreads();
  }
  if (t < nc) cpre[t] = tmp[t] - v;
  if (t == 255) offs[N] = tmp[255];
}

__global__ void scan_final_kernel(const int* __restrict__ deg, const int* __restrict__ cpre,
                                  int* __restrict__ offs, int n) {
  int b = blockIdx.x, t = threadIdx.x, i = b * 256 + t;
  __shared__ int tmp[256];
  int v = (i < n) ? deg[i] : 0;
  tmp[t] = v;
  __syncthreads();
  for (int off = 1; off < 256; off <<= 1) {
    int x = (t >= off) ? tmp[t - off] : 0;
    __syncthreads();
    tmp[t] += x;
    __syncthreads();
  }
  if (i < n) offs[i] = cpre[b] + tmp[t] - v;
}

__global__ void scatter_kernel(const void* __restrict__ edges, const int* __restrict__ flag,
                               const int* __restrict__ offs, int* __restrict__ fill,
                               int* __restrict__ srcS, int E, int Nn) {
  int wide = flag[0];
  for (int e = blockIdx.x * blockDim.x + threadIdx.x; e < E; e += gridDim.x * blockDim.x) {
    int s = edge_at(edges, wide, e);
    int d = edge_at(edges, wide, E + e);
    if (d < 0) d = 0; if (d >= Nn) d = Nn - 1;
    if (s < 0) s = 0; if (s >= Nn) s = Nn - 1;
    int p = offs[d] + atomicAdd(&fill[d], 1);
    if (p < 0) p = 0; if (p >= E) p = E - 1;
    srcS[p] = s;
  }
}

// ---------------- fused multi-section GEMM: out = [A|A2] @ Bcat (+bias) --------
// R11 config: 128x128 tile, acc 4x4, global_load_lds staging.
// R20: split-A staging (Ksplit). R21: optional fused BN-stats epilogue.
// R22: axsel — when fF[0]==0 (bf16 input), replace A (bit0) / A2 (bit1) with x0raw
// (skips the x0->x0b conversion copy entirely).
__global__ __launch_bounds__(256)
void gemm4_kernel(const ushort_t* __restrict__ A, const ushort_t* __restrict__ A2,
                  int Ksplit,
                  const ushort_t* __restrict__ BT,
                  ushort_t* __restrict__ o0, ushort_t* __restrict__ o1,
                  ushort_t* __restrict__ o2, ushort_t* __restrict__ o3,
                  const ushort_t* __restrict__ bias3,
                  int M, int K, int NC, int b0, int b1, int b2,
                  float* __restrict__ bnsum, float* __restrict__ bnsq,
                  const int* __restrict__ fF, const void* __restrict__ x0raw, int axsel) {
  __shared__ __align__(16) ushort_t As[128 * 32];
  __shared__ __align__(16) ushort_t Bs[128 * 32];
  const ushort_t* Ae = A;
  const ushort_t* A2e = A2;
  if (axsel && fF[0] == 0) {
    if (axsel & 1) Ae = (const ushort_t*)x0raw;
    if (axsel & 2) A2e = (const ushort_t*)x0raw;
  }
  int tid = threadIdx.x;
  int lane = tid & 63, wave = tid >> 6;
  int tm = blockIdx.x * 128, tn = blockIdx.y * 128;
  int wm = (wave >> 1) * 64, wn = (wave & 1) * 64;
  int q = lane >> 4, l = lane & 15;
  f32x4 acc[4][4];
#pragma unroll
  for (int a = 0; a < 4; a++)
#pragma unroll
    for (int b = 0; b < 4; b++) acc[a][b] = (f32x4){0.f, 0.f, 0.f, 0.f};

  int lrow = lane >> 2, c8 = (lane & 3) * 8;
  for (int k0 = 0; k0 < K; k0 += 32) {
    const ushort_t* Ap; int kk, sA;
    if (k0 < Ksplit) { Ap = Ae;  kk = k0;          sA = Ksplit; }
    else             { Ap = A2e; kk = k0 - Ksplit; sA = K - Ksplit; }
#pragma unroll
    for (int t = 0; t < 2; t++) {
      int chunk = t * 4 + wave;           // 0..7, 16 rows each
      int row = chunk * 16 + lrow;
      int ra = tm + row; if (ra > M - 1) ra = M - 1;
      async_copy16(&Ap[(size_t)ra * sA + kk + c8], &As[chunk * 512]);
      async_copy16(&BT[(size_t)(tn + row) * K + k0 + c8], &Bs[chunk * 512]);
    }
    __syncthreads();
    s16x8 af[4], bfr[4];
#pragma unroll
    for (int mf = 0; mf < 4; mf++) af[mf] = *(const s16x8*)&As[(wm + mf * 16 + l) * 32 + q * 8];
#pragma unroll
    for (int nf = 0; nf < 4; nf++) bfr[nf] = *(const s16x8*)&Bs[(wn + nf * 16 + l) * 32 + q * 8];
#pragma unroll
    for (int mf = 0; mf < 4; mf++)
#pragma unroll
      for (int nf = 0; nf < 4; nf++)
        acc[mf][nf] = __builtin_amdgcn_mfma_f32_16x16x32_bf16(af[mf], bfr[nf], acc[mf][nf], 0, 0, 0);
    __syncthreads();
  }
  // Hoisted section select (tile is 128-aligned; sections are 128-multiples).
  ushort_t* op; int sbase, w; bool addb = false;
  if (tn < b0)      { op = o0; sbase = 0;  w = b0; }
  else if (tn < b1) { op = o1; sbase = b0; w = b1 - b0; }
  else if (tn < b2) { op = o2; sbase = b1; w = b2 - b1; }
  else              { op = o3; sbase = b2; w = NC - b2; addb = true; }
  int lc0 = tn + wn - sbase + l;
  float bv[4];
#pragma unroll
  for (int nf = 0; nf < 4; nf++) bv[nf] = addb ? bf2f(bias3[lc0 + nf * 16]) : 0.f;
  float csum[4] = {0.f, 0.f, 0.f, 0.f}, csq[4] = {0.f, 0.f, 0.f, 0.f};
  // C/D layout: col = lane&15, row = (lane>>4)*4 + reg   [m89-verified]
#pragma unroll
  for (int mf = 0; mf < 4; mf++) {
#pragma unroll
    for (int j = 0; j < 4; j++) {
      int r = tm + wm + mf * 16 + q * 4 + j;
      if (r < M) {
#pragma unroll
        for (int nf = 0; nf < 4; nf++) {
          float v = acc[mf][nf][j] + bv[nf];
          op[(size_t)r * w + lc0 + nf * 16] = f2bf(v);
          csum[nf] += v;
          csq[nf]  += v * v;
        }
      }
    }
  }
  if (bnsum) {
    // lanes l, l+16, l+32, l+48 share columns {lc0+nf*16}; reduce then atomicAdd once
#pragma unroll
    for (int nf = 0; nf < 4; nf++) {
      csum[nf] += __shfl_xor(csum[nf], 16); csum[nf] += __shfl_xor(csum[nf], 32);
      csq[nf]  += __shfl_xor(csq[nf], 16);  csq[nf]  += __shfl_xor(csq[nf], 32);
    }
    if (q == 0) {
#pragma unroll
      for (int nf = 0; nf < 4; nf++) {
        atomicAdd(&bnsum[lc0 + nf * 16], csum[nf]);
        atomicAdd(&bnsq[lc0 + nf * 16],  csq[nf]);
      }
    }
  }
}

// ---------------- fused attention + aggregation, one WAVE per dst node ----------------
// R17: qt-factorization. logit = qt[d]·x[s]; agg = sum(w * x[s]) (Wv applied after).
// R18: 2-deep software pipeline — best measured config (72.6us, VGPR 44).
// [R19 post-mortem: batched-index loads hit VGPR 64 occupancy step; occ 44->35%,
//  dur +12%. Per-wave MLP trades ~1:1 vs occupancy here — REVERTED to R18.]
// R21: nontemporal agg stores. R22: xsel — gather from x0raw when bf16 input.
__global__ __launch_bounds__(256)
void attn_kernel(const ushort_t* __restrict__ qt, const ushort_t* __restrict__ xin,
                 const int* __restrict__ offs, const int* __restrict__ srcS,
                 ushort_t* __restrict__ aggb, int D, int Nn,
                 const int* __restrict__ fF, const void* __restrict__ x0raw, int xsel) {
  int lane = threadIdx.x & 63, wave = threadIdx.x >> 6;
  int n = blockIdx.x * 4 + wave;
  if (n >= Nn) return;
  int g = lane >> 4, sub = lane & 15;
  const ushort_t* x = (xsel && fF[0] == 0) ? (const ushort_t*)x0raw : xin;

  int e0 = offs[n], e1 = offs[n + 1];
  float wsum = 0.f;

  if (D == 128) {  // 8 dims per lane
    s16x8 qv = __builtin_nontemporal_load((const s16x8*)(qt + (size_t)n * 128 + sub * 8));
    float qf[8];
#pragma unroll
    for (int i = 0; i < 8; i++) qf[i] = bf2f((unsigned short)qv[i]);
    float acc[8];
#pragma unroll
    for (int i = 0; i < 8; i++) acc[i] = 0.f;
    int j = e0;
    s16x8 xc;
    bool have = (j + 4 <= e1);
    if (have) {
      int s = __builtin_nontemporal_load(srcS + j + g);
      if (s < 0 || s >= Nn) s = 0;
      xc = *(const s16x8*)(x + (size_t)s * 128 + sub * 8);
    }
    for (; j + 8 <= e1; j += 4) {
      int s2 = __builtin_nontemporal_load(srcS + j + 4 + g);
      if (s2 < 0 || s2 >= Nn) s2 = 0;
      s16x8 xn = *(const s16x8*)(x + (size_t)s2 * 128 + sub * 8);
      float p = 0.f;
#pragma unroll
      for (int i = 0; i < 8; i++) p += qf[i] * bf2f((unsigned short)xc[i]);
      p += __shfl_xor(p, 1); p += __shfl_xor(p, 2);
      p += __shfl_xor(p, 4); p += __shfl_xor(p, 8);
      float w = __expf(p * 0.0625f);
      wsum += w;
#pragma unroll
      for (int i = 0; i < 8; i++) acc[i] += w * bf2f((unsigned short)xc[i]);
      xc = xn;
    }
    if (have) {
      float p = 0.f;
#pragma unroll
      for (int i = 0; i < 8; i++) p += qf[i] * bf2f((unsigned short)xc[i]);
      p += __shfl_xor(p, 1); p += __shfl_xor(p, 2);
      p += __shfl_xor(p, 4); p += __shfl_xor(p, 8);
      float w = __expf(p * 0.0625f);
      wsum += w;
#pragma unroll
      for (int i = 0; i < 8; i++) acc[i] += w * bf2f((unsigned short)xc[i]);
      j += 4;
    }
    int rem = e1 - j;
    if (rem > 0) {
      bool valid = g < rem;
      int s = __builtin_nontemporal_load(srcS + (valid ? (j + g) : j));
      if (s < 0 || s >= Nn) s = 0;
      s16x8 xv = *(const s16x8*)(x + (size_t)s * 128 + sub * 8);
      float p = 0.f;
#pragma unroll
      for (int i = 0; i < 8; i++) p += qf[i] * bf2f((unsigned short)xv[i]);
      p += __shfl_xor(p, 1); p += __shfl_xor(p, 2);
      p += __shfl_xor(p, 4); p += __shfl_xor(p, 8);
      float w = 0.f;
      if (valid) w = __expf(p * 0.0625f);
      wsum += w;
#pragma unroll
      for (int i = 0; i < 8; i++) acc[i] += w * bf2f((unsigned short)xv[i]);
    }
    wsum += __shfl_xor(wsum, 16); wsum += __shfl_xor(wsum, 32);
#pragma unroll
    for (int i = 0; i < 8; i++) {
      acc[i] += __shfl_xor(acc[i], 16);
      acc[i] += __shfl_xor(acc[i], 32);
    }
    float inv = 1.f / fmaxf(wsum, 1e-16f);
    if (g == 0) {
      s16x8 r0;
#pragma unroll
      for (int i = 0; i < 8; i++) r0[i] = (short)f2bf(acc[i] * inv);
      __builtin_nontemporal_store(r0, (s16x8*)(aggb + (size_t)n * 128 + sub * 8));
    }
  } else {  // D == 256: 16 dims per lane
    s16x8 q0 = __builtin_nontemporal_load((const s16x8*)(qt + (size_t)n * 256 + sub * 16));
    s16x8 q1 = __builtin_nontemporal_load((const s16x8*)(qt + (size_t)n * 256 + sub * 16 + 8));
    float qf[16];
#pragma unroll
    for (int i = 0; i < 8; i++) {
      qf[i]     = bf2f((unsigned short)q0[i]);
      qf[8 + i] = bf2f((unsigned short)q1[i]);
    }
    float acc[16];
#pragma unroll
    for (int i = 0; i < 16; i++) acc[i] = 0.f;
    int j = e0;
    s16x8 x0c, x1c;
    bool have = (j + 4 <= e1);
    if (have) {
      int s = __builtin_nontemporal_load(srcS + j + g);
      if (s < 0 || s >= Nn) s = 0;
      const ushort_t* xp = x + (size_t)s * 256 + sub * 16;
      x0c = *(const s16x8*)xp; x1c = *(const s16x8*)(xp + 8);
    }
    for (; j + 8 <= e1; j += 4) {
      int s2 = __builtin_nontemporal_load(srcS + j + 4 + g);
      if (s2 < 0 || s2 >= Nn) s2 = 0;
      const ushort_t* xp2 = x + (size_t)s2 * 256 + sub * 16;
      s16x8 x0n = *(const s16x8*)xp2, x1n = *(const s16x8*)(xp2 + 8);
      float pa = 0.f, pb = 0.f;
#pragma unroll
      for (int i = 0; i < 8; i++) {
        pa += qf[i] * bf2f((unsigned short)x0c[i]);
        pb += qf[8 + i] * bf2f((unsigned short)x1c[i]);
      }
      float p = pa + pb;
      p += __shfl_xor(p, 1); p += __shfl_xor(p, 2);
      p += __shfl_xor(p, 4); p += __shfl_xor(p, 8);
      float w = __expf(p * 0.0625f);
      wsum += w;
#pragma unroll
      for (int i = 0; i < 8; i++) {
        acc[i]     += w * bf2f((unsigned short)x0c[i]);
        acc[8 + i] += w * bf2f((unsigned short)x1c[i]);
      }
      x0c = x0n; x1c = x1n;
    }
    if (have) {
      float pa = 0.f, pb = 0.f;
#pragma unroll
      for (int i = 0; i < 8; i++) {
        pa += qf[i] * bf2f((unsigned short)x0c[i]);
        pb += qf[8 + i] * bf2f((unsigned short)x1c[i]);
      }
      float p = pa + pb;
      p += __shfl_xor(p, 1); p += __shfl_xor(p, 2);
      p += __shfl_xor(p, 4); p += __shfl_xor(p, 8);
      float w = __expf(p * 0.0625f);
      wsum += w;
#pragma unroll
      for (int i = 0; i < 8; i++) {
        acc[i]     += w * bf2f((unsigned short)x0c[i]);
        acc[8 + i] += w * bf2f((unsigned short)x1c[i]);
      }
      j += 4;
    }
    int rem = e1 - j;
    if (rem > 0) {
      bool valid = g < rem;
      int s = __builtin_nontemporal_load(srcS + (valid ? (j + g) : j));
      if (s < 0 || s >= Nn) s = 0;
      const ushort_t* xp = x + (size_t)s * 256 + sub * 16;
      s16x8 x0v = *(const s16x8*)xp, x1v = *(const s16x8*)(xp + 8);
      float pa = 0.f, pb = 0.f;
#pragma unroll
      for (int i = 0; i < 8; i++) {
        pa += qf[i] * bf2f((unsigned short)x0v[i]);
        pb += qf[8 + i] * bf2f((unsigned short)x1v[i]);
      }
      float p = pa + pb;
      p += __shfl_xor(p, 1); p += __shfl_xor(p, 2);
      p += __shfl_xor(p, 4); p += __shfl_xor(p, 8);
      float w = 0.f;
      if (valid) w = __expf(p * 0.0625f);
      wsum += w;
#pragma unroll
      for (int i = 0; i < 8; i++) {
        acc[i]     += w * bf2f((unsigned short)x0v[i]);
        acc[8 + i] += w * bf2f((unsigned short)x1v[i]);
      }
    }
    wsum += __shfl_xor(wsum, 16); wsum += __shfl_xor(wsum, 32);
#pragma unroll
    for (int i = 0; i < 16; i++) {
      acc[i] += __shfl_xor(acc[i], 16);
      acc[i] += __shfl_xor(acc[i], 32);
    }
    float inv = 1.f / fmaxf(wsum, 1e-16f);
    if (g == 0) {
      s16x8 r0, r1;
#pragma unroll
      for (int i = 0; i < 8; i++) {
        r0[i] = (short)f2bf(acc[i] * inv);
        r1[i] = (short)f2bf(acc[8 + i] * inv);
      }
      size_t idx = (size_t)n * 256 + sub * 16;
      __builtin_nontemporal_store(r0, (s16x8*)(aggb + idx));
      __builtin_nontemporal_store(r1, (s16x8*)(aggb + idx + 8));
    }
  }
}

// normalize+relu; R22: short8-vectorized (scalar bf16 loads are ~2x slower, G13).
// total8 = total elements / 8; channels per row are a multiple of 8.
__global__ void norm_relu_kernel(const ushort_t* __restrict__ h,
                                 const float* __restrict__ sum, const float* __restrict__ sumsq,
                                 const ushort_t* __restrict__ g, const ushort_t* __restrict__ be,
                                 ushort_t* __restrict__ x1, int N, size_t total8, int cmask) {
  __shared__ float sc[256], sh[256];
  int t = threadIdx.x;
  if (t <= cmask) {
    float mu = sum[t] / (float)N;
    float var = sumsq[t] / (float)N - mu * mu;
    float s = bf2f(g[t]) * rsqrtf(var + 1e-5f);
    sc[t] = s;
    sh[t] = bf2f(be[t]) - mu * s;
  }
  __syncthreads();
  for (size_t i = blockIdx.x * (size_t)blockDim.x + t; i < total8;
       i += (size_t)gridDim.x * blockDim.x) {
    size_t base = i * 8;
    s16x8 hv = *(const s16x8*)(h + base);
    int c0 = (int)(base & (size_t)cmask);
    s16x8 r;
#pragma unroll
    for (int j = 0; j < 8; j++) {
      float vv = bf2f((unsigned short)hv[j]) * sc[c0 + j] + sh[c0 + j];
      r[j] = (short)f2bf(relu_nanprop(vv));
    }
    *(s16x8*)(x1 + base) = r;
  }
}

// final: BN + residual + relu, dual-dtype out; R22: short8-vectorized + x0raw select.
__global__ void final_kernel(const ushort_t* __restrict__ h,
                             const float* __restrict__ sum, const float* __restrict__ sumsq,
                             const ushort_t* __restrict__ g, const ushort_t* __restrict__ be,
                             const ushort_t* __restrict__ x0b, const void* __restrict__ x0raw,
                             void* __restrict__ out,
                             const int* __restrict__ flagF, int N, size_t total8) {
  __shared__ float sc[128], sh[128];
  int t = threadIdx.x;
  if (t < 128) {
    float mu = sum[t] / (float)N;
    float var = sumsq[t] / (float)N - mu * mu;
    float s = bf2f(g[t]) * rsqrtf(var + 1e-5f);
    sc[t] = s;
    sh[t] = bf2f(be[t]) - mu * s;
  }
  __syncthreads();
  int f = flagF[0];
  const ushort_t* xp = f ? x0b : (const ushort_t*)x0raw;
  for (size_t i = blockIdx.x * (size_t)blockDim.x + t; i < total8;
       i += (size_t)gridDim.x * blockDim.x) {
    size_t base = i * 8;
    s16x8 hv = *(const s16x8*)(h + base);
    s16x8 xv = *(const s16x8*)(xp + base);
    int c0 = (int)(base & 127);
    float v[8];
#pragma unroll
    for (int j = 0; j < 8; j++) {
      float vv = bf2f((unsigned short)hv[j]) * sc[c0 + j] + sh[c0 + j]
               + bf2f((unsigned short)xv[j]);
      v[j] = relu_nanprop(vv);
    }
    if (f) {
      float4 o1 = {v[0], v[1], v[2], v[3]};
      float4 o2 = {v[4], v[5], v[6], v[7]};
      *(float4*)((float*)out + base) = o1;
      *(float4*)((float*)out + base + 4) = o2;
    } else {
      s16x8 r;
#pragma unroll
      for (int j = 0; j < 8; j++) r[j] = (short)f2bf(v[j]);
      *(s16x8*)((ushort_t*)out + base) = r;
    }
  }
}

extern "C" void kernel_launch(void* const* d_in, const int* in_sizes, int n_in,
                              void* d_out, int out_size, void* d_ws, size_t ws_size,
                              hipStream_t stream) {
  const void* x0  = d_in[0];
  const void* edges = d_in[1];
  const void* Wq1 = d_in[2];
  const void* Wk1 = d_in[3];
  const void* Wv1 = d_in[4];
  const void* Wr1 = d_in[5];
  const void* b1  = d_in[6];
  const void* gw1 = d_in[7];
  const void* bw1 = d_in[8];
  const void* Wq2 = d_in[9];
  const void* Wk2 = d_in[10];
  const void* Wv2 = d_in[11];
  const void* Wr2 = d_in[12];
  const void* b2  = d_in[13];
  const void* gw2 = d_in[14];
  const void* bw2 = d_in[15];

  int N = in_sizes[0] / 128;
  int E = in_sizes[1] / 2;
  int NCHUNK = (N + 255) / 256;
  int MT = (N + 127) / 128;

  uintptr_t base = (uintptr_t)d_ws;
  auto carve = [&](size_t bytes) -> void* {
    uintptr_t p = base;
    base += (bytes + 255) & ~(size_t)255;
    return (void*)p;
  };
  ushort_t* x0b = (ushort_t*)carve((size_t)N * 128 * 2);
  ushort_t* qtb = (ushort_t*)carve((size_t)N * 256 * 2);   // qt1 (128) / qt2 (256)
  ushort_t* aggb = (ushort_t*)carve((size_t)N * 256 * 2);  // agg output (128/256)
  ushort_t* hb = (ushort_t*)carve((size_t)N * 256 * 2);
  ushort_t* x1 = (ushort_t*)carve((size_t)N * 256 * 2);
  ushort_t* Wq1b = (ushort_t*)carve((size_t)128 * 256 * 2);
  ushort_t* Wk1b = (ushort_t*)carve((size_t)128 * 256 * 2);
  ushort_t* wcatQ1 = (ushort_t*)carve((size_t)128 * 128 * 2);  // M1^T
  ushort_t* wcatH1 = (ushort_t*)carve((size_t)256 * 256 * 2);  // [Wr1^T | Wv1^T]
  ushort_t* Wq2b = (ushort_t*)carve((size_t)256 * 256 * 2);
  ushort_t* Wk2b = (ushort_t*)carve((size_t)256 * 256 * 2);
  ushort_t* wcatQ2 = (ushort_t*)carve((size_t)256 * 256 * 2);  // M2^T
  ushort_t* wcatH2 = (ushort_t*)carve((size_t)128 * 512 * 2);  // [Wr2^T | Wv2^T]
  ushort_t* b1b  = (ushort_t*)carve(256 * 2);
  ushort_t* g1b  = (ushort_t*)carve(256 * 2);
  ushort_t* be1b = (ushort_t*)carve(256 * 2);
  ushort_t* b2b  = (ushort_t*)carve(128 * 2);
  ushort_t* g2b  = (ushort_t*)carve(128 * 2);
  ushort_t* be2b = (ushort_t*)carve(128 * 2);
  int* offs = (int*)carve((size_t)(N + 1) * 4);
  int* srcS = (int*)carve((size_t)E * 4);
  int* csum = (int*)carve(256 * 4);
  int* cpre = (int*)carve(256 * 4);
  // zeroed region: deg(N) fill(N) sums(1024 floats)
  int nzero = 2 * N + 1024;
  int* zreg2 = (int*)carve((size_t)nzero * 4);
  int* deg   = zreg2;
  int* fill  = zreg2 + N;
  float* sum1 = (float*)(zreg2 + 2 * N);
  float* sq1  = sum1 + 256;
  float* sum2 = sum1 + 512;
  float* sq2  = sum1 + 640;
  int* eflag = (int*)carve(256);   // [0]=edge wide, [1]=float32 flag (setup writes)
  int* fF = eflag + 1;

  size_t needed = base - (uintptr_t)d_ws;
  if (needed > ws_size) return;

  // 1: zero + dtype detects
  setup_kernel<<<258, 256, 0, stream>>>(zreg2, N, (const int*)edges, 2 * E, eflag,
                                        (const unsigned int*)x0, N * 128, fF);
  // 2: x0 cvt (f32 only) + params + weight prep + hist
  cvt_all_kernel<<<6145, 256, 0, stream>>>(x0, x0b, N * 128,
                                           b1, gw1, bw1, b2, gw2, bw2,
                                           b1b, g1b, be1b, b2b, g2b, be2b,
                                           Wq1, Wk1, Wv1, Wr1, Wq1b, Wk1b, wcatH1,
                                           Wq2, Wk2, Wv2, Wr2, Wq2b, Wk2b, wcatH2,
                                           edges, deg, E, N, eflag, fF);
  // 3-6: scan + scatter
  chunk_sum_kernel<<<NCHUNK, 256, 0, stream>>>(deg, csum, N);
  scan_small_kernel<<<1, 256, 0, stream>>>(csum, cpre, NCHUNK, offs, N);
  scan_final_kernel<<<NCHUNK, 256, 0, stream>>>(deg, cpre, offs, N);
  scatter_kernel<<<1024, 256, 0, stream>>>(edges, eflag, offs, fill, srcS, E, N);

  // M1^T = Wk1 @ Wq1^T -> wcatQ1;  M2^T = Wk2 @ Wq2^T -> wcatQ2
  gemm4_kernel<<<dim3(1, 1), 256, 0, stream>>>(Wk1b, Wk1b, 256, Wq1b,
                                               wcatQ1, wcatQ1, wcatQ1, wcatQ1,
                                               b1b, 128, 256, 128, 128, 128, 128,
                                               nullptr, nullptr, fF, x0, 0);
  gemm4_kernel<<<dim3(2, 2), 256, 0, stream>>>(Wk2b, Wk2b, 256, Wq2b,
                                               wcatQ2, wcatQ2, wcatQ2, wcatQ2,
                                               b1b, 256, 256, 256, 256, 256, 256,
                                               nullptr, nullptr, fF, x0, 0);

  int gAttn = (N + 3) / 4;        // one wave per node
  // Layer 1: qt1 = x0 @ M1^T;  attn;  h = [x0|agg] @ [Wr1;Wv1] + b1 (+fused BN stats)
  gemm4_kernel<<<dim3(MT, 1), 256, 0, stream>>>(x0b, x0b, 128, wcatQ1,
                                                qtb, qtb, qtb, qtb,
                                                b1b, N, 128, 128, 128, 128, 128,
                                                nullptr, nullptr, fF, x0, 3);
  attn_kernel<<<gAttn, 256, 0, stream>>>(qtb, x0b, offs, srcS, aggb, 128, N, fF, x0, 1);
  gemm4_kernel<<<dim3(MT, 2), 256, 0, stream>>>(x0b, aggb, 128, wcatH1,
                                                hb, hb, hb, hb,
                                                b1b, N, 256, 256, 0, 0, 0,
                                                sum1, sq1, fF, x0, 1);
  norm_relu_kernel<<<4096, 256, 0, stream>>>(hb, sum1, sq1, g1b, be1b, x1, N,
                                             (size_t)N * 32, 255);
  // Layer 2: qt2 = x1 @ M2^T;  attn;  h = [x1|agg] @ [Wr2;Wv2] + b2 (+fused BN stats)
  gemm4_kernel<<<dim3(MT, 2), 256, 0, stream>>>(x1, x1, 256, wcatQ2,
                                                qtb, qtb, qtb, qtb,
                                                b2b, N, 256, 256, 256, 256, 256,
                                                nullptr, nullptr, fF, x0, 0);
  attn_kernel<<<gAttn, 256, 0, stream>>>(qtb, x1, offs, srcS, aggb, 256, N, fF, x0, 0);
  gemm4_kernel<<<dim3(MT, 1), 256, 0, stream>>>(x1, aggb, 256, wcatH2,
                                                hb, hb, hb, hb,
                                                b2b, N, 512, 128, 0, 0, 0,
                                                sum2, sq2, fF, x0, 0);
  final_kernel<<<2048, 256, 0, stream>>>(hb, sum2, sq2, g2b, be2b, x0b, x0, d_out, fF, N,
                                         (size_t)N * 16);
}

// Round 10
// 455.771 us; speedup vs baseline: 1.2253x; 1.0347x over previous
//
#include <hip/hip_runtime.h>
#include <stdint.h>

typedef unsigned short ushort_t;

__device__ __forceinline__ float bf2f(unsigned short u) {
  union { unsigned int i; float f; } c; c.i = ((unsigned int)u) << 16; return c.f;
}
__device__ __forceinline__ unsigned short f2bf(float f) {
  union { float f; unsigned int i; } c; c.f = f;
  unsigned int r = c.i + 0x7FFFu + ((c.i >> 16) & 1u);
  return (unsigned short)(r >> 16);
}
// NaN-propagating relu (tripwire: NaN stays visible)
__device__ __forceinline__ float relu_nanprop(float v) { return (v < 0.f) ? 0.f : v; }

// async global->LDS 16B copy: LDS dest = wave-uniform base + lane*16 (HW-implicit)
__device__ __forceinline__ void async_copy16(const void* g, void* l) {
  __builtin_amdgcn_global_load_lds(
      (const __attribute__((address_space(1))) unsigned int*)(uintptr_t)g,
      (__attribute__((address_space(3))) unsigned int*)(uintptr_t)l,
      16, 0, 0);
}

typedef __attribute__((ext_vector_type(8))) short s16x8;
typedef __attribute__((ext_vector_type(4))) float f32x4;

__device__ __forceinline__ int edge_at(const void* edges, int wide, int idx) {
  if (wide) return (int)((const long long*)edges)[idx];
  return ((const int*)edges)[idx];
}

// ---------------- setup: zero scratch + dtype detects (1 launch) ----------------
__global__ void setup_kernel(int* __restrict__ zreg2, int N,
                             const int* __restrict__ e32, int n32, int* __restrict__ eflag,
                             const unsigned int* __restrict__ x, int nw, int* __restrict__ fF) {
  int b = blockIdx.x, tid = threadIdx.x;
  if (b < 256) {
    int total = 2 * N + 1024;
    for (int i = b * 256 + tid; i < total; i += 256 * 256) zreg2[i] = 0;
  } else if (b == 256) {
    __shared__ int any;
    if (tid == 0) any = 0;
    __syncthreads();
    for (int i = tid; i < 4096; i += 256) {
      int idx = 2 * i + 1;
      if (idx < n32 && e32[idx] != 0) any = 1;
    }
    __syncthreads();
    if (tid == 0) eflag[0] = (any == 0) ? 1 : 0;  // 1 => int64
  } else {
    __shared__ int cnt;
    if (tid == 0) cnt = 0;
    __syncthreads();
    int local = 0;
    for (int i = tid; i < 4096 && i < nw; i += 256) {
      unsigned int low = x[i] & 0xFFFFu;
      unsigned int e = (low >> 7) & 0xFFu;
      if (low != 0u && (e < 96u || e > 144u)) local++;
    }
    atomicAdd(&cnt, local);
    __syncthreads();
    if (tid == 0) fF[0] = (cnt > 1024) ? 1 : 0;  // 1 => float32 inputs
  }
}

// ---------------- cvt_all: x0 cvt + params + weight prep + hist (1 launch) ----------
// R20 weight prep: Wq*b/Wk*b straight; wcatH* = [Wr^T | Wv^T] K-concat.
// R22: x0 copy SKIPPED when input already bf16; f32 path vectorized.
__global__ void cvt_all_kernel(const void* __restrict__ x0, ushort_t* __restrict__ x0b, int nx,
                               const void* p0, const void* p1, const void* p2,
                               const void* p3, const void* p4, const void* p5,
                               ushort_t* o0, ushort_t* o1, ushort_t* o2,
                               ushort_t* o3, ushort_t* o4, ushort_t* o5,
                               const void* W10, const void* W11, const void* W12, const void* W13,
                               ushort_t* __restrict__ Wq1b, ushort_t* __restrict__ Wk1b,
                               ushort_t* __restrict__ wcatH1,
                               const void* W20, const void* W21, const void* W22, const void* W23,
                               ushort_t* __restrict__ Wq2b, ushort_t* __restrict__ Wk2b,
                               ushort_t* __restrict__ wcatH2,
                               const void* __restrict__ edges, int* __restrict__ deg,
                               int E, int Nn,
                               const int* __restrict__ eflag, const int* __restrict__ fF) {
  int b = blockIdx.x, tid = threadIdx.x;
  int f = fF[0];
  if (b < 4096) {
    if (f) {  // only convert when input is f32; bf16 inputs are used in place
      int nx8 = nx >> 3;
      for (int i = b * 256 + tid; i < nx8; i += 4096 * 256) {
        const float* src = (const float*)x0 + (size_t)i * 8;
        float4 a = *(const float4*)src;
        float4 c = *(const float4*)(src + 4);
        s16x8 r;
        r[0] = (short)f2bf(a.x); r[1] = (short)f2bf(a.y);
        r[2] = (short)f2bf(a.z); r[3] = (short)f2bf(a.w);
        r[4] = (short)f2bf(c.x); r[5] = (short)f2bf(c.y);
        r[6] = (short)f2bf(c.z); r[7] = (short)f2bf(c.w);
        *(s16x8*)(x0b + (size_t)i * 8) = r;
      }
    }
  } else if (b == 4096) {
    const void* ins[6] = {p0, p1, p2, p3, p4, p5};
    ushort_t* outs[6] = {o0, o1, o2, o3, o4, o5};
    const int segs[7] = {0, 256, 512, 768, 896, 1024, 1152};
    for (int i = tid; i < 1152; i += 256) {
      int s = 0;
      while (i >= segs[s + 1]) s++;
      int li = i - segs[s];
      outs[s][li] = f ? f2bf(((const float*)ins[s])[li]) : ((const ushort_t*)ins[s])[li];
    }
  } else if (b < 4609) {
    // layer-1: Wq1[128][256], Wk1[128][256] straight;
    // Wr1[128][256] -> wcatH1[c][k]  (k<128);  Wv1[128][256] -> wcatH1[c][128+k].
    for (int i = (b - 4097) * 256 + tid; i < 131072; i += 512 * 256) {
      if (i < 32768) {
        Wq1b[i] = f ? f2bf(((const float*)W10)[i]) : ((const ushort_t*)W10)[i];
      } else if (i < 65536) {
        int r = i - 32768;
        Wk1b[r] = f ? f2bf(((const float*)W11)[r]) : ((const ushort_t*)W11)[r];
      } else if (i < 98304) {
        int rem = i - 65536, k = rem >> 8, c = rem & 255;  // Wr1[k][c]
        ushort_t v = f ? f2bf(((const float*)W13)[rem]) : ((const ushort_t*)W13)[rem];
        wcatH1[(size_t)c * 256 + k] = v;
      } else {
        int rem = i - 98304, k = rem >> 8, c = rem & 255;  // Wv1[k][c]
        ushort_t v = f ? f2bf(((const float*)W12)[rem]) : ((const ushort_t*)W12)[rem];
        wcatH1[(size_t)c * 256 + 128 + k] = v;
      }
    }
  } else if (b < 5121) {
    // layer-2: Wq2[256][256], Wk2[256][256] straight;
    // Wr2[256][128] -> wcatH2[c][k] (k<256);  Wv2[256][128] -> wcatH2[c][256+k].
    for (int i = (b - 4609) * 256 + tid; i < 196608; i += 512 * 256) {
      if (i < 65536) {
        Wq2b[i] = f ? f2bf(((const float*)W20)[i]) : ((const ushort_t*)W20)[i];
      } else if (i < 131072) {
        int r = i - 65536;
        Wk2b[r] = f ? f2bf(((const float*)W21)[r]) : ((const ushort_t*)W21)[r];
      } else if (i < 163840) {
        int rem = i - 131072, k = rem >> 7, c = rem & 127;  // Wr2[k][c]
        ushort_t v = f ? f2bf(((const float*)W23)[rem]) : ((const ushort_t*)W23)[rem];
        wcatH2[(size_t)c * 512 + k] = v;
      } else {
        int rem = i - 163840, k = rem >> 7, c = rem & 127;  // Wv2[k][c]
        ushort_t v = f ? f2bf(((const float*)W22)[rem]) : ((const ushort_t*)W22)[rem];
        wcatH2[(size_t)c * 512 + 256 + k] = v;
      }
    }
  } else {  // hist: 1024 blocks
    int wide = eflag[0];
    for (int e = (b - 5121) * 256 + tid; e < E; e += 1024 * 256) {
      int d = edge_at(edges, wide, E + e);
      if (d < 0) d = 0; if (d >= Nn) d = Nn - 1;
      atomicAdd(&deg[d], 1);
    }
  }
}

// 3-phase parallel scan (chunk = 256): supports N <= 65536
__global__ void chunk_sum_kernel(const int* __restrict__ deg, int* __restrict__ csum, int n) {
  int b = blockIdx.x, t = threadIdx.x, i = b * 256 + t;
  int v = (i < n) ? deg[i] : 0;
  __shared__ int ws[4];
#pragma unroll
  for (int o = 32; o > 0; o >>= 1) v += __shfl_down(v, o);
  if ((t & 63) == 0) ws[t >> 6] = v;
  __syncthreads();
  if (t == 0) csum[b] = ws[0] + ws[1] + ws[2] + ws[3];
}

__global__ void scan_small_kernel(const int* __restrict__ csum, int* __restrict__ cpre,
                                  int nc, int* __restrict__ offs, int N) {
  __shared__ int tmp[256];
  int t = threadIdx.x;
  int v = (t < nc) ? csum[t] : 0;
  tmp[t] = v;
  __syncthreads();
  for (int off = 1; off < 256; off <<= 1) {
    int x = (t >= off) ? tmp[t - off] : 0;
    __syncthreads();
    tmp[t] += x;
    __syncthreads();
  }
  if (t < nc) cpre[t] = tmp[t] - v;
  if (t == 255) offs[N] = tmp[255];
}

__global__ void scan_final_kernel(const int* __restrict__ deg, const int* __restrict__ cpre,
                                  int* __restrict__ offs, int n) {
  int b = blockIdx.x, t = threadIdx.x, i = b * 256 + t;
  __shared__ int tmp[256];
  int v = (i < n) ? deg[i] : 0;
  tmp[t] = v;
  __syncthreads();
  for (int off = 1; off < 256; off <<= 1) {
    int x = (t >= off) ? tmp[t - off] : 0;
    __syncthreads();
    tmp[t] += x;
    __syncthreads();
  }
  if (i < n) offs[i] = cpre[b] + tmp[t] - v;
}

__global__ void scatter_kernel(const void* __restrict__ edges, const int* __restrict__ flag,
                               const int* __restrict__ offs, int* __restrict__ fill,
                               int* __restrict__ srcS, int E, int Nn) {
  int wide = flag[0];
  for (int e = blockIdx.x * blockDim.x + threadIdx.x; e < E; e += gridDim.x * blockDim.x) {
    int s = edge_at(edges, wide, e);
    int d = edge_at(edges, wide, E + e);
    if (d < 0) d = 0; if (d >= Nn) d = Nn - 1;
    if (s < 0) s = 0; if (s >= Nn) s = Nn - 1;
    int p = offs[d] + atomicAdd(&fill[d], 1);
    if (p < 0) p = 0; if (p >= E) p = E - 1;
    srcS[p] = s;
  }
}

// ---------------- R23: both M-GEMMs in ONE launch (5 tile-blocks) -------------
// block 0: M1^T = Wk1 @ Wq1^T (128x128, K=256) -> wcatQ1
// blocks 1-4: M2^T = Wk2 @ Wq2^T (256x256, K=256) -> wcatQ2
__global__ __launch_bounds__(256)
void mgemm_kernel(const ushort_t* __restrict__ Wk1b, const ushort_t* __restrict__ Wq1b,
                  ushort_t* __restrict__ wcatQ1,
                  const ushort_t* __restrict__ Wk2b, const ushort_t* __restrict__ Wq2b,
                  ushort_t* __restrict__ wcatQ2) {
  __shared__ __align__(16) ushort_t As[128 * 32];
  __shared__ __align__(16) ushort_t Bs[128 * 32];
  const ushort_t* A; const ushort_t* BT; ushort_t* O; int tm, tn, w;
  int b = blockIdx.x;
  if (b == 0) { A = Wk1b; BT = Wq1b; O = wcatQ1; tm = 0; tn = 0; w = 128; }
  else {
    A = Wk2b; BT = Wq2b; O = wcatQ2;
    tm = ((b - 1) >> 1) * 128; tn = ((b - 1) & 1) * 128; w = 256;
  }
  int tid = threadIdx.x;
  int lane = tid & 63, wave = tid >> 6;
  int wm = (wave >> 1) * 64, wn = (wave & 1) * 64;
  int q = lane >> 4, l = lane & 15;
  f32x4 acc[4][4];
#pragma unroll
  for (int a = 0; a < 4; a++)
#pragma unroll
    for (int c = 0; c < 4; c++) acc[a][c] = (f32x4){0.f, 0.f, 0.f, 0.f};
  int lrow = lane >> 2, c8 = (lane & 3) * 8;
  for (int k0 = 0; k0 < 256; k0 += 32) {
#pragma unroll
    for (int t = 0; t < 2; t++) {
      int chunk = t * 4 + wave;
      int row = chunk * 16 + lrow;
      async_copy16(&A[(size_t)(tm + row) * 256 + k0 + c8], &As[chunk * 512]);
      async_copy16(&BT[(size_t)(tn + row) * 256 + k0 + c8], &Bs[chunk * 512]);
    }
    __syncthreads();
    s16x8 af[4], bfr[4];
#pragma unroll
    for (int mf = 0; mf < 4; mf++) af[mf] = *(const s16x8*)&As[(wm + mf * 16 + l) * 32 + q * 8];
#pragma unroll
    for (int nf = 0; nf < 4; nf++) bfr[nf] = *(const s16x8*)&Bs[(wn + nf * 16 + l) * 32 + q * 8];
#pragma unroll
    for (int mf = 0; mf < 4; mf++)
#pragma unroll
      for (int nf = 0; nf < 4; nf++)
        acc[mf][nf] = __builtin_amdgcn_mfma_f32_16x16x32_bf16(af[mf], bfr[nf], acc[mf][nf], 0, 0, 0);
    __syncthreads();
  }
  int lc0 = tn + wn + l;
#pragma unroll
  for (int mf = 0; mf < 4; mf++)
#pragma unroll
    for (int j = 0; j < 4; j++) {
      int r = tm + wm + mf * 16 + q * 4 + j;
#pragma unroll
      for (int nf = 0; nf < 4; nf++)
        O[(size_t)r * w + lc0 + nf * 16] = f2bf(acc[mf][nf][j]);
    }
}

// ---------------- fused multi-section GEMM: out = [A|A2] @ Bcat (+bias) --------
// R11 config: 128x128 tile, acc 4x4, global_load_lds staging.
// R20: split-A staging (Ksplit). R21: optional fused BN-stats epilogue.
// R22: axsel — when fF[0]==0 (bf16 input), A (bit0)/A2 (bit1) replaced by x0raw.
__global__ __launch_bounds__(256)
void gemm4_kernel(const ushort_t* __restrict__ A, const ushort_t* __restrict__ A2,
                  int Ksplit,
                  const ushort_t* __restrict__ BT,
                  ushort_t* __restrict__ o0, ushort_t* __restrict__ o1,
                  ushort_t* __restrict__ o2, ushort_t* __restrict__ o3,
                  const ushort_t* __restrict__ bias3,
                  int M, int K, int NC, int b0, int b1, int b2,
                  float* __restrict__ bnsum, float* __restrict__ bnsq,
                  const int* __restrict__ fF, const void* __restrict__ x0raw, int axsel) {
  __shared__ __align__(16) ushort_t As[128 * 32];
  __shared__ __align__(16) ushort_t Bs[128 * 32];
  const ushort_t* Ae = A;
  const ushort_t* A2e = A2;
  if (axsel && fF[0] == 0) {
    if (axsel & 1) Ae = (const ushort_t*)x0raw;
    if (axsel & 2) A2e = (const ushort_t*)x0raw;
  }
  int tid = threadIdx.x;
  int lane = tid & 63, wave = tid >> 6;
  int tm = blockIdx.x * 128, tn = blockIdx.y * 128;
  int wm = (wave >> 1) * 64, wn = (wave & 1) * 64;
  int q = lane >> 4, l = lane & 15;
  f32x4 acc[4][4];
#pragma unroll
  for (int a = 0; a < 4; a++)
#pragma unroll
    for (int b = 0; b < 4; b++) acc[a][b] = (f32x4){0.f, 0.f, 0.f, 0.f};

  int lrow = lane >> 2, c8 = (lane & 3) * 8;
  for (int k0 = 0; k0 < K; k0 += 32) {
    const ushort_t* Ap; int kk, sA;
    if (k0 < Ksplit) { Ap = Ae;  kk = k0;          sA = Ksplit; }
    else             { Ap = A2e; kk = k0 - Ksplit; sA = K - Ksplit; }
#pragma unroll
    for (int t = 0; t < 2; t++) {
      int chunk = t * 4 + wave;           // 0..7, 16 rows each
      int row = chunk * 16 + lrow;
      int ra = tm + row; if (ra > M - 1) ra = M - 1;
      async_copy16(&Ap[(size_t)ra * sA + kk + c8], &As[chunk * 512]);
      async_copy16(&BT[(size_t)(tn + row) * K + k0 + c8], &Bs[chunk * 512]);
    }
    __syncthreads();
    s16x8 af[4], bfr[4];
#pragma unroll
    for (int mf = 0; mf < 4; mf++) af[mf] = *(const s16x8*)&As[(wm + mf * 16 + l) * 32 + q * 8];
#pragma unroll
    for (int nf = 0; nf < 4; nf++) bfr[nf] = *(const s16x8*)&Bs[(wn + nf * 16 + l) * 32 + q * 8];
#pragma unroll
    for (int mf = 0; mf < 4; mf++)
#pragma unroll
      for (int nf = 0; nf < 4; nf++)
        acc[mf][nf] = __builtin_amdgcn_mfma_f32_16x16x32_bf16(af[mf], bfr[nf], acc[mf][nf], 0, 0, 0);
    __syncthreads();
  }
  // Hoisted section select (tile is 128-aligned; sections are 128-multiples).
  ushort_t* op; int sbase, w; bool addb = false;
  if (tn < b0)      { op = o0; sbase = 0;  w = b0; }
  else if (tn < b1) { op = o1; sbase = b0; w = b1 - b0; }
  else if (tn < b2) { op = o2; sbase = b1; w = b2 - b1; }
  else              { op = o3; sbase = b2; w = NC - b2; addb = true; }
  int lc0 = tn + wn - sbase + l;
  float bv[4];
#pragma unroll
  for (int nf = 0; nf < 4; nf++) bv[nf] = addb ? bf2f(bias3[lc0 + nf * 16]) : 0.f;
  float csum[4] = {0.f, 0.f, 0.f, 0.f}, csq[4] = {0.f, 0.f, 0.f, 0.f};
  // C/D layout: col = lane&15, row = (lane>>4)*4 + reg   [m89-verified]
#pragma unroll
  for (int mf = 0; mf < 4; mf++) {
#pragma unroll
    for (int j = 0; j < 4; j++) {
      int r = tm + wm + mf * 16 + q * 4 + j;
      if (r < M) {
#pragma unroll
        for (int nf = 0; nf < 4; nf++) {
          float v = acc[mf][nf][j] + bv[nf];
          op[(size_t)r * w + lc0 + nf * 16] = f2bf(v);
          csum[nf] += v;
          csq[nf]  += v * v;
        }
      }
    }
  }
  if (bnsum) {
    // lanes l, l+16, l+32, l+48 share columns {lc0+nf*16}; reduce then atomicAdd once
#pragma unroll
    for (int nf = 0; nf < 4; nf++) {
      csum[nf] += __shfl_xor(csum[nf], 16); csum[nf] += __shfl_xor(csum[nf], 32);
      csq[nf]  += __shfl_xor(csq[nf], 16);  csq[nf]  += __shfl_xor(csq[nf], 32);
    }
    if (q == 0) {
#pragma unroll
      for (int nf = 0; nf < 4; nf++) {
        atomicAdd(&bnsum[lc0 + nf * 16], csum[nf]);
        atomicAdd(&bnsq[lc0 + nf * 16],  csq[nf]);
      }
    }
  }
}

// ---------------- fused attention + aggregation, one WAVE per dst node ----------------
// R17: qt-factorization. logit = qt[d]·x[s]; agg = sum(w * x[s]) (Wv applied after).
// R18: 2-deep software pipeline (best D=256 config: 72.6us, VGPR 44).
// [R19: batched-index loads hit VGPR-64 occupancy step — reverted.]
// R21: nontemporal agg stores. R22: xsel — gather from x0raw when bf16 input.
// R23: D=128 re-grouped to 8 lanes/edge x 8 edges/iter (16 dims/lane, 2x16B loads)
// — doubles in-flight bytes to match the D=256 register profile; no VGPR cliff.
__global__ __launch_bounds__(256)
void attn_kernel(const ushort_t* __restrict__ qt, const ushort_t* __restrict__ xin,
                 const int* __restrict__ offs, const int* __restrict__ srcS,
                 ushort_t* __restrict__ aggb, int D, int Nn,
                 const int* __restrict__ fF, const void* __restrict__ x0raw, int xsel) {
  int lane = threadIdx.x & 63, wave = threadIdx.x >> 6;
  int n = blockIdx.x * 4 + wave;
  if (n >= Nn) return;
  const ushort_t* x = (xsel && fF[0] == 0) ? (const ushort_t*)x0raw : xin;

  int e0 = offs[n], e1 = offs[n + 1];
  float wsum = 0.f;

  if (D == 128) {  // R23: 8 lanes/edge, 8 edges per wave-iter; 16 dims per lane
    int g = lane >> 3, sub = lane & 7;
    const ushort_t* qp = qt + (size_t)n * 128 + sub * 16;
    s16x8 q0 = __builtin_nontemporal_load((const s16x8*)qp);
    s16x8 q1 = __builtin_nontemporal_load((const s16x8*)(qp + 8));
    float qf[16];
#pragma unroll
    for (int i = 0; i < 8; i++) {
      qf[i]     = bf2f((unsigned short)q0[i]);
      qf[8 + i] = bf2f((unsigned short)q1[i]);
    }
    float acc[16];
#pragma unroll
    for (int i = 0; i < 16; i++) acc[i] = 0.f;
    int j = e0;
    s16x8 x0c, x1c;
    bool have = (j + 8 <= e1);
    if (have) {
      int s = __builtin_nontemporal_load(srcS + j + g);
      if (s < 0 || s >= Nn) s = 0;
      const ushort_t* xp = x + (size_t)s * 128 + sub * 16;
      x0c = *(const s16x8*)xp; x1c = *(const s16x8*)(xp + 8);
    }
    for (; j + 16 <= e1; j += 8) {
      int s2 = __builtin_nontemporal_load(srcS + j + 8 + g);
      if (s2 < 0 || s2 >= Nn) s2 = 0;
      const ushort_t* xp2 = x + (size_t)s2 * 128 + sub * 16;
      s16x8 x0n = *(const s16x8*)xp2, x1n = *(const s16x8*)(xp2 + 8);
      float pa = 0.f, pb = 0.f;
#pragma unroll
      for (int i = 0; i < 8; i++) {
        pa += qf[i] * bf2f((unsigned short)x0c[i]);
        pb += qf[8 + i] * bf2f((unsigned short)x1c[i]);
      }
      float p = pa + pb;
      p += __shfl_xor(p, 1); p += __shfl_xor(p, 2); p += __shfl_xor(p, 4);
      float w = __expf(p * 0.0625f);
      wsum += w;
#pragma unroll
      for (int i = 0; i < 8; i++) {
        acc[i]     += w * bf2f((unsigned short)x0c[i]);
        acc[8 + i] += w * bf2f((unsigned short)x1c[i]);
      }
      x0c = x0n; x1c = x1n;
    }
    if (have) {
      float pa = 0.f, pb = 0.f;
#pragma unroll
      for (int i = 0; i < 8; i++) {
        pa += qf[i] * bf2f((unsigned short)x0c[i]);
        pb += qf[8 + i] * bf2f((unsigned short)x1c[i]);
      }
      float p = pa + pb;
      p += __shfl_xor(p, 1); p += __shfl_xor(p, 2); p += __shfl_xor(p, 4);
      float w = __expf(p * 0.0625f);
      wsum += w;
#pragma unroll
      for (int i = 0; i < 8; i++) {
        acc[i]     += w * bf2f((unsigned short)x0c[i]);
        acc[8 + i] += w * bf2f((unsigned short)x1c[i]);
      }
      j += 8;
    }
    int rem = e1 - j;  // 0..7
    if (rem > 0) {
      bool valid = g < rem;
      int s = __builtin_nontemporal_load(srcS + (valid ? (j + g) : j));
      if (s < 0 || s >= Nn) s = 0;
      const ushort_t* xp = x + (size_t)s * 128 + sub * 16;
      s16x8 x0v = *(const s16x8*)xp, x1v = *(const s16x8*)(xp + 8);
      float pa = 0.f, pb = 0.f;
#pragma unroll
      for (int i = 0; i < 8; i++) {
        pa += qf[i] * bf2f((unsigned short)x0v[i]);
        pb += qf[8 + i] * bf2f((unsigned short)x1v[i]);
      }
      float p = pa + pb;
      p += __shfl_xor(p, 1); p += __shfl_xor(p, 2); p += __shfl_xor(p, 4);
      float w = 0.f;
      if (valid) w = __expf(p * 0.0625f);
      wsum += w;
#pragma unroll
      for (int i = 0; i < 8; i++) {
        acc[i]     += w * bf2f((unsigned short)x0v[i]);
        acc[8 + i] += w * bf2f((unsigned short)x1v[i]);
      }
    }
    // combine the 8 groups (once per node)
    wsum += __shfl_xor(wsum, 8); wsum += __shfl_xor(wsum, 16); wsum += __shfl_xor(wsum, 32);
#pragma unroll
    for (int i = 0; i < 16; i++) {
      acc[i] += __shfl_xor(acc[i], 8);
      acc[i] += __shfl_xor(acc[i], 16);
      acc[i] += __shfl_xor(acc[i], 32);
    }
    float inv = 1.f / fmaxf(wsum, 1e-16f);
    if (g == 0) {  // lanes 0..7 cover the 128 dims
      s16x8 r0, r1;
#pragma unroll
      for (int i = 0; i < 8; i++) {
        r0[i] = (short)f2bf(acc[i] * inv);
        r1[i] = (short)f2bf(acc[8 + i] * inv);
      }
      size_t idx = (size_t)n * 128 + sub * 16;
      __builtin_nontemporal_store(r0, (s16x8*)(aggb + idx));
      __builtin_nontemporal_store(r1, (s16x8*)(aggb + idx + 8));
    }
  } else {  // D == 256: 16 lanes/edge, 4 edges/iter (R18 config, unchanged)
    int g = lane >> 4, sub = lane & 15;
    s16x8 q0 = __builtin_nontemporal_load((const s16x8*)(qt + (size_t)n * 256 + sub * 16));
    s16x8 q1 = __builtin_nontemporal_load((const s16x8*)(qt + (size_t)n * 256 + sub * 16 + 8));
    float qf[16];
#pragma unroll
    for (int i = 0; i < 8; i++) {
      qf[i]     = bf2f((unsigned short)q0[i]);
      qf[8 + i] = bf2f((unsigned short)q1[i]);
    }
    float acc[16];
#pragma unroll
    for (int i = 0; i < 16; i++) acc[i] = 0.f;
    int j = e0;
    s16x8 x0c, x1c;
    bool have = (j + 4 <= e1);
    if (have) {
      int s = __builtin_nontemporal_load(srcS + j + g);
      if (s < 0 || s >= Nn) s = 0;
      const ushort_t* xp = x + (size_t)s * 256 + sub * 16;
      x0c = *(const s16x8*)xp; x1c = *(const s16x8*)(xp + 8);
    }
    for (; j + 8 <= e1; j += 4) {
      int s2 = __builtin_nontemporal_load(srcS + j + 4 + g);
      if (s2 < 0 || s2 >= Nn) s2 = 0;
      const ushort_t* xp2 = x + (size_t)s2 * 256 + sub * 16;
      s16x8 x0n = *(const s16x8*)xp2, x1n = *(const s16x8*)(xp2 + 8);
      float pa = 0.f, pb = 0.f;
#pragma unroll
      for (int i = 0; i < 8; i++) {
        pa += qf[i] * bf2f((unsigned short)x0c[i]);
        pb += qf[8 + i] * bf2f((unsigned short)x1c[i]);
      }
      float p = pa + pb;
      p += __shfl_xor(p, 1); p += __shfl_xor(p, 2);
      p += __shfl_xor(p, 4); p += __shfl_xor(p, 8);
      float w = __expf(p * 0.0625f);
      wsum += w;
#pragma unroll
      for (int i = 0; i < 8; i++) {
        acc[i]     += w * bf2f((unsigned short)x0c[i]);
        acc[8 + i] += w * bf2f((unsigned short)x1c[i]);
      }
      x0c = x0n; x1c = x1n;
    }
    if (have) {
      float pa = 0.f, pb = 0.f;
#pragma unroll
      for (int i = 0; i < 8; i++) {
        pa += qf[i] * bf2f((unsigned short)x0c[i]);
        pb += qf[8 + i] * bf2f((unsigned short)x1c[i]);
      }
      float p = pa + pb;
      p += __shfl_xor(p, 1); p += __shfl_xor(p, 2);
      p += __shfl_xor(p, 4); p += __shfl_xor(p, 8);
      float w = __expf(p * 0.0625f);
      wsum += w;
#pragma unroll
      for (int i = 0; i < 8; i++) {
        acc[i]     += w * bf2f((unsigned short)x0c[i]);
        acc[8 + i] += w * bf2f((unsigned short)x1c[i]);
      }
      j += 4;
    }
    int rem = e1 - j;
    if (rem > 0) {
      bool valid = g < rem;
      int s = __builtin_nontemporal_load(srcS + (valid ? (j + g) : j));
      if (s < 0 || s >= Nn) s = 0;
      const ushort_t* xp = x + (size_t)s * 256 + sub * 16;
      s16x8 x0v = *(const s16x8*)xp, x1v = *(const s16x8*)(xp + 8);
      float pa = 0.f, pb = 0.f;
#pragma unroll
      for (int i = 0; i < 8; i++) {
        pa += qf[i] * bf2f((unsigned short)x0v[i]);
        pb += qf[8 + i] * bf2f((unsigned short)x1v[i]);
      }
      float p = pa + pb;
      p += __shfl_xor(p, 1); p += __shfl_xor(p, 2);
      p += __shfl_xor(p, 4); p += __shfl_xor(p, 8);
      float w = 0.f;
      if (valid) w = __expf(p * 0.0625f);
      wsum += w;
#pragma unroll
      for (int i = 0; i < 8; i++) {
        acc[i]     += w * bf2f((unsigned short)x0v[i]);
        acc[8 + i] += w * bf2f((unsigned short)x1v[i]);
      }
    }
    wsum += __shfl_xor(wsum, 16); wsum += __shfl_xor(wsum, 32);
#pragma unroll
    for (int i = 0; i < 16; i++) {
      acc[i] += __shfl_xor(acc[i], 16);
      acc[i] += __shfl_xor(acc[i], 32);
    }
    float inv = 1.f / fmaxf(wsum, 1e-16f);
    if (g == 0) {
      s16x8 r0, r1;
#pragma unroll
      for (int i = 0; i < 8; i++) {
        r0[i] = (short)f2bf(acc[i] * inv);
        r1[i] = (short)f2bf(acc[8 + i] * inv);
      }
      size_t idx = (size_t)n * 256 + sub * 16;
      __builtin_nontemporal_store(r0, (s16x8*)(aggb + idx));
      __builtin_nontemporal_store(r1, (s16x8*)(aggb + idx + 8));
    }
  }
}

// normalize+relu; R22: short8-vectorized. total8 = total elements / 8.
__global__ void norm_relu_kernel(const ushort_t* __restrict__ h,
                                 const float* __restrict__ sum, const float* __restrict__ sumsq,
                                 const ushort_t* __restrict__ g, const ushort_t* __restrict__ be,
                                 ushort_t* __restrict__ x1, int N, size_t total8, int cmask) {
  __shared__ float sc[256], sh[256];
  int t = threadIdx.x;
  if (t <= cmask) {
    float mu = sum[t] / (float)N;
    float var = sumsq[t] / (float)N - mu * mu;
    float s = bf2f(g[t]) * rsqrtf(var + 1e-5f);
    sc[t] = s;
    sh[t] = bf2f(be[t]) - mu * s;
  }
  __syncthreads();
  for (size_t i = blockIdx.x * (size_t)blockDim.x + t; i < total8;
       i += (size_t)gridDim.x * blockDim.x) {
    size_t base = i * 8;
    s16x8 hv = *(const s16x8*)(h + base);
    int c0 = (int)(base & (size_t)cmask);
    s16x8 r;
#pragma unroll
    for (int j = 0; j < 8; j++) {
      float vv = bf2f((unsigned short)hv[j]) * sc[c0 + j] + sh[c0 + j];
      r[j] = (short)f2bf(relu_nanprop(vv));
    }
    *(s16x8*)(x1 + base) = r;
  }
}

// final: BN + residual + relu, dual-dtype out; R22: short8-vectorized + x0raw select.
__global__ void final_kernel(const ushort_t* __restrict__ h,
                             const float* __restrict__ sum, const float* __restrict__ sumsq,
                             const ushort_t* __restrict__ g, const ushort_t* __restrict__ be,
                             const ushort_t* __restrict__ x0b, const void* __restrict__ x0raw,
                             void* __restrict__ out,
                             const int* __restrict__ flagF, int N, size_t total8) {
  __shared__ float sc[128], sh[128];
  int t = threadIdx.x;
  if (t < 128) {
    float mu = sum[t] / (float)N;
    float var = sumsq[t] / (float)N - mu * mu;
    float s = bf2f(g[t]) * rsqrtf(var + 1e-5f);
    sc[t] = s;
    sh[t] = bf2f(be[t]) - mu * s;
  }
  __syncthreads();
  int f = flagF[0];
  const ushort_t* xp = f ? x0b : (const ushort_t*)x0raw;
  for (size_t i = blockIdx.x * (size_t)blockDim.x + t; i < total8;
       i += (size_t)gridDim.x * blockDim.x) {
    size_t base = i * 8;
    s16x8 hv = *(const s16x8*)(h + base);
    s16x8 xv = *(const s16x8*)(xp + base);
    int c0 = (int)(base & 127);
    float v[8];
#pragma unroll
    for (int j = 0; j < 8; j++) {
      float vv = bf2f((unsigned short)hv[j]) * sc[c0 + j] + sh[c0 + j]
               + bf2f((unsigned short)xv[j]);
      v[j] = relu_nanprop(vv);
    }
    if (f) {
      float4 o1 = {v[0], v[1], v[2], v[3]};
      float4 o2 = {v[4], v[5], v[6], v[7]};
      *(float4*)((float*)out + base) = o1;
      *(float4*)((float*)out + base + 4) = o2;
    } else {
      s16x8 r;
#pragma unroll
      for (int j = 0; j < 8; j++) r[j] = (short)f2bf(v[j]);
      *(s16x8*)((ushort_t*)out + base) = r;
    }
  }
}

extern "C" void kernel_launch(void* const* d_in, const int* in_sizes, int n_in,
                              void* d_out, int out_size, void* d_ws, size_t ws_size,
                              hipStream_t stream) {
  const void* x0  = d_in[0];
  const void* edges = d_in[1];
  const void* Wq1 = d_in[2];
  const void* Wk1 = d_in[3];
  const void* Wv1 = d_in[4];
  const void* Wr1 = d_in[5];
  const void* b1  = d_in[6];
  const void* gw1 = d_in[7];
  const void* bw1 = d_in[8];
  const void* Wq2 = d_in[9];
  const void* Wk2 = d_in[10];
  const void* Wv2 = d_in[11];
  const void* Wr2 = d_in[12];
  const void* b2  = d_in[13];
  const void* gw2 = d_in[14];
  const void* bw2 = d_in[15];

  int N = in_sizes[0] / 128;
  int E = in_sizes[1] / 2;
  int NCHUNK = (N + 255) / 256;
  int MT = (N + 127) / 128;

  uintptr_t base = (uintptr_t)d_ws;
  auto carve = [&](size_t bytes) -> void* {
    uintptr_t p = base;
    base += (bytes + 255) & ~(size_t)255;
    return (void*)p;
  };
  ushort_t* x0b = (ushort_t*)carve((size_t)N * 128 * 2);
  ushort_t* qtb = (ushort_t*)carve((size_t)N * 256 * 2);   // qt1 (128) / qt2 (256)
  ushort_t* aggb = (ushort_t*)carve((size_t)N * 256 * 2);  // agg output (128/256)
  ushort_t* hb = (ushort_t*)carve((size_t)N * 256 * 2);
  ushort_t* x1 = (ushort_t*)carve((size_t)N * 256 * 2);
  ushort_t* Wq1b = (ushort_t*)carve((size_t)128 * 256 * 2);
  ushort_t* Wk1b = (ushort_t*)carve((size_t)128 * 256 * 2);
  ushort_t* wcatQ1 = (ushort_t*)carve((size_t)128 * 128 * 2);  // M1^T
  ushort_t* wcatH1 = (ushort_t*)carve((size_t)256 * 256 * 2);  // [Wr1^T | Wv1^T]
  ushort_t* Wq2b = (ushort_t*)carve((size_t)256 * 256 * 2);
  ushort_t* Wk2b = (ushort_t*)carve((size_t)256 * 256 * 2);
  ushort_t* wcatQ2 = (ushort_t*)carve((size_t)256 * 256 * 2);  // M2^T
  ushort_t* wcatH2 = (ushort_t*)carve((size_t)128 * 512 * 2);  // [Wr2^T | Wv2^T]
  ushort_t* b1b  = (ushort_t*)carve(256 * 2);
  ushort_t* g1b  = (ushort_t*)carve(256 * 2);
  ushort_t* be1b = (ushort_t*)carve(256 * 2);
  ushort_t* b2b  = (ushort_t*)carve(128 * 2);
  ushort_t* g2b  = (ushort_t*)carve(128 * 2);
  ushort_t* be2b = (ushort_t*)carve(128 * 2);
  int* offs = (int*)carve((size_t)(N + 1) * 4);
  int* srcS = (int*)carve((size_t)E * 4);
  int* csum = (int*)carve(256 * 4);
  int* cpre = (int*)carve(256 * 4);
  // zeroed region: deg(N) fill(N) sums(1024 floats)
  int nzero = 2 * N + 1024;
  int* zreg2 = (int*)carve((size_t)nzero * 4);
  int* deg   = zreg2;
  int* fill  = zreg2 + N;
  float* sum1 = (float*)(zreg2 + 2 * N);
  float* sq1  = sum1 + 256;
  float* sum2 = sum1 + 512;
  float* sq2  = sum1 + 640;
  int* eflag = (int*)carve(256);   // [0]=edge wide, [1]=float32 flag (setup writes)
  int* fF = eflag + 1;

  size_t needed = base - (uintptr_t)d_ws;
  if (needed > ws_size) return;

  // 1: zero + dtype detects
  setup_kernel<<<258, 256, 0, stream>>>(zreg2, N, (const int*)edges, 2 * E, eflag,
                                        (const unsigned int*)x0, N * 128, fF);
  // 2: x0 cvt (f32 only) + params + weight prep + hist
  cvt_all_kernel<<<6145, 256, 0, stream>>>(x0, x0b, N * 128,
                                           b1, gw1, bw1, b2, gw2, bw2,
                                           b1b, g1b, be1b, b2b, g2b, be2b,
                                           Wq1, Wk1, Wv1, Wr1, Wq1b, Wk1b, wcatH1,
                                           Wq2, Wk2, Wv2, Wr2, Wq2b, Wk2b, wcatH2,
                                           edges, deg, E, N, eflag, fF);
  // 3-6: scan + scatter
  chunk_sum_kernel<<<NCHUNK, 256, 0, stream>>>(deg, csum, N);
  scan_small_kernel<<<1, 256, 0, stream>>>(csum, cpre, NCHUNK, offs, N);
  scan_final_kernel<<<NCHUNK, 256, 0, stream>>>(deg, cpre, offs, N);
  scatter_kernel<<<1024, 256, 0, stream>>>(edges, eflag, offs, fill, srcS, E, N);

  // both M-GEMMs in one launch (R23)
  mgemm_kernel<<<5, 256, 0, stream>>>(Wk1b, Wq1b, wcatQ1, Wk2b, Wq2b, wcatQ2);

  int gAttn = (N + 3) / 4;        // one wave per node
  // Layer 1: qt1 = x0 @ M1^T;  attn;  h = [x0|agg] @ [Wr1;Wv1] + b1 (+fused BN stats)
  gemm4_kernel<<<dim3(MT, 1), 256, 0, stream>>>(x0b, x0b, 128, wcatQ1,
                                                qtb, qtb, qtb, qtb,
                                                b1b, N, 128, 128, 128, 128, 128,
                                                nullptr, nullptr, fF, x0, 3);
  attn_kernel<<<gAttn, 256, 0, stream>>>(qtb, x0b, offs, srcS, aggb, 128, N, fF, x0, 1);
  gemm4_kernel<<<dim3(MT, 2), 256, 0, stream>>>(x0b, aggb, 128, wcatH1,
                                                hb, hb, hb, hb,
                                                b1b, N, 256, 256, 0, 0, 0,
                                                sum1, sq1, fF, x0, 1);
  norm_relu_kernel<<<4096, 256, 0, stream>>>(hb, sum1, sq1, g1b, be1b, x1, N,
                                             (size_t)N * 32, 255);
  // Layer 2: qt2 = x1 @ M2^T;  attn;  h = [x1|agg] @ [Wr2;Wv2] + b2 (+fused BN stats)
  gemm4_kernel<<<dim3(MT, 2), 256, 0, stream>>>(x1, x1, 256, wcatQ2,
                                                qtb, qtb, qtb, qtb,
                                                b2b, N, 256, 256, 256, 256, 256,
                                                nullptr, nullptr, fF, x0, 0);
  attn_kernel<<<gAttn, 256, 0, stream>>>(qtb, x1, offs, srcS, aggb, 256, N, fF, x0, 0);
  gemm4_kernel<<<dim3(MT, 1), 256, 0, stream>>>(x1, aggb, 256, wcatH2,
                                                hb, hb, hb, hb,
                                                b2b, N, 512, 128, 0, 0, 0,
                                                sum2, sq2, fF, x0, 0);
  final_kernel<<<2048, 256, 0, stream>>>(hb, sum2, sq2, g2b, be2b, x0b, x0, d_out, fF, N,
                                         (size_t)N * 16);
}

// Round 11
// 441.492 us; speedup vs baseline: 1.2649x; 1.0323x over previous
//
#include <hip/hip_runtime.h>
#include <stdint.h>

typedef unsigned short ushort_t;

__device__ __forceinline__ float bf2f(unsigned short u) {
  union { unsigned int i; float f; } c; c.i = ((unsigned int)u) << 16; return c.f;
}
__device__ __forceinline__ unsigned short f2bf(float f) {
  union { float f; unsigned int i; } c; c.f = f;
  unsigned int r = c.i + 0x7FFFu + ((c.i >> 16) & 1u);
  return (unsigned short)(r >> 16);
}
// NaN-propagating relu (tripwire: NaN stays visible)
__device__ __forceinline__ float relu_nanprop(float v) { return (v < 0.f) ? 0.f : v; }

// async global->LDS 16B copy: LDS dest = wave-uniform base + lane*16 (HW-implicit)
__device__ __forceinline__ void async_copy16(const void* g, void* l) {
  __builtin_amdgcn_global_load_lds(
      (const __attribute__((address_space(1))) unsigned int*)(uintptr_t)g,
      (__attribute__((address_space(3))) unsigned int*)(uintptr_t)l,
      16, 0, 0);
}

typedef __attribute__((ext_vector_type(8))) short s16x8;
typedef __attribute__((ext_vector_type(4))) float f32x4;

__device__ __forceinline__ int edge_at(const void* edges, int wide, int idx) {
  if (wide) return (int)((const long long*)edges)[idx];
  return ((const int*)edges)[idx];
}

// ---------------- shared GEMM tile body (R24: factored out; used by 3 kernels) ----
// 128x128 tile, acc 4x4, global_load_lds staging. Split-A (Ksplit). Optional fused
// BN-stats epilogue (R21). C/D layout: col = lane&15, row = (lane>>4)*4+reg [m89].
__device__ __forceinline__ void gemm_tile(
    const ushort_t* __restrict__ Ae, const ushort_t* __restrict__ A2e, int Ksplit,
    const ushort_t* __restrict__ BT,
    ushort_t* __restrict__ o0, ushort_t* __restrict__ o1,
    ushort_t* __restrict__ o2, ushort_t* __restrict__ o3,
    const ushort_t* __restrict__ bias3,
    int M, int K, int NC, int b0, int b1, int b2,
    float* __restrict__ bnsum, float* __restrict__ bnsq,
    int tm, int tn) {
  __shared__ __align__(16) ushort_t As[128 * 32];
  __shared__ __align__(16) ushort_t Bs[128 * 32];
  int tid = threadIdx.x;
  int lane = tid & 63, wave = tid >> 6;
  int wm = (wave >> 1) * 64, wn = (wave & 1) * 64;
  int q = lane >> 4, l = lane & 15;
  f32x4 acc[4][4];
#pragma unroll
  for (int a = 0; a < 4; a++)
#pragma unroll
    for (int b = 0; b < 4; b++) acc[a][b] = (f32x4){0.f, 0.f, 0.f, 0.f};

  int lrow = lane >> 2, c8 = (lane & 3) * 8;
  for (int k0 = 0; k0 < K; k0 += 32) {
    const ushort_t* Ap; int kk, sA;
    if (k0 < Ksplit) { Ap = Ae;  kk = k0;          sA = Ksplit; }
    else             { Ap = A2e; kk = k0 - Ksplit; sA = K - Ksplit; }
#pragma unroll
    for (int t = 0; t < 2; t++) {
      int chunk = t * 4 + wave;           // 0..7, 16 rows each
      int row = chunk * 16 + lrow;
      int ra = tm + row; if (ra > M - 1) ra = M - 1;
      async_copy16(&Ap[(size_t)ra * sA + kk + c8], &As[chunk * 512]);
      async_copy16(&BT[(size_t)(tn + row) * K + k0 + c8], &Bs[chunk * 512]);
    }
    __syncthreads();
    s16x8 af[4], bfr[4];
#pragma unroll
    for (int mf = 0; mf < 4; mf++) af[mf] = *(const s16x8*)&As[(wm + mf * 16 + l) * 32 + q * 8];
#pragma unroll
    for (int nf = 0; nf < 4; nf++) bfr[nf] = *(const s16x8*)&Bs[(wn + nf * 16 + l) * 32 + q * 8];
#pragma unroll
    for (int mf = 0; mf < 4; mf++)
#pragma unroll
      for (int nf = 0; nf < 4; nf++)
        acc[mf][nf] = __builtin_amdgcn_mfma_f32_16x16x32_bf16(af[mf], bfr[nf], acc[mf][nf], 0, 0, 0);
    __syncthreads();
  }
  // Hoisted section select (tile is 128-aligned; sections are 128-multiples).
  ushort_t* op; int sbase, w; bool addb = false;
  if (tn < b0)      { op = o0; sbase = 0;  w = b0; }
  else if (tn < b1) { op = o1; sbase = b0; w = b1 - b0; }
  else if (tn < b2) { op = o2; sbase = b1; w = b2 - b1; }
  else              { op = o3; sbase = b2; w = NC - b2; addb = true; }
  int lc0 = tn + wn - sbase + l;
  float bv[4];
#pragma unroll
  for (int nf = 0; nf < 4; nf++) bv[nf] = addb ? bf2f(bias3[lc0 + nf * 16]) : 0.f;
  float csum[4] = {0.f, 0.f, 0.f, 0.f}, csq[4] = {0.f, 0.f, 0.f, 0.f};
#pragma unroll
  for (int mf = 0; mf < 4; mf++) {
#pragma unroll
    for (int j = 0; j < 4; j++) {
      int r = tm + wm + mf * 16 + q * 4 + j;
      if (r < M) {
#pragma unroll
        for (int nf = 0; nf < 4; nf++) {
          float v = acc[mf][nf][j] + bv[nf];
          op[(size_t)r * w + lc0 + nf * 16] = f2bf(v);
          csum[nf] += v;
          csq[nf]  += v * v;
        }
      }
    }
  }
  if (bnsum) {
    // lanes l, l+16, l+32, l+48 share columns {lc0+nf*16}; reduce then atomicAdd once
#pragma unroll
    for (int nf = 0; nf < 4; nf++) {
      csum[nf] += __shfl_xor(csum[nf], 16); csum[nf] += __shfl_xor(csum[nf], 32);
      csq[nf]  += __shfl_xor(csq[nf], 16);  csq[nf]  += __shfl_xor(csq[nf], 32);
    }
    if (q == 0) {
#pragma unroll
      for (int nf = 0; nf < 4; nf++) {
        atomicAdd(&bnsum[lc0 + nf * 16], csum[nf]);
        atomicAdd(&bnsq[lc0 + nf * 16],  csq[nf]);
      }
    }
  }
}

// ---------------- setup: zero scratch + dtype detects (1 launch) ----------------
__global__ void setup_kernel(int* __restrict__ zreg2, int N,
                             const int* __restrict__ e32, int n32, int* __restrict__ eflag,
                             const unsigned int* __restrict__ x, int nw, int* __restrict__ fF) {
  int b = blockIdx.x, tid = threadIdx.x;
  if (b < 256) {
    int total = 2 * N + 1088;   // deg, fill, sums(1024), done counter
    for (int i = b * 256 + tid; i < total; i += 256 * 256) zreg2[i] = 0;
  } else if (b == 256) {
    __shared__ int any;
    if (tid == 0) any = 0;
    __syncthreads();
    for (int i = tid; i < 4096; i += 256) {
      int idx = 2 * i + 1;
      if (idx < n32 && e32[idx] != 0) any = 1;
    }
    __syncthreads();
    if (tid == 0) eflag[0] = (any == 0) ? 1 : 0;  // 1 => int64
  } else {
    __shared__ int cnt;
    if (tid == 0) cnt = 0;
    __syncthreads();
    int local = 0;
    for (int i = tid; i < 4096 && i < nw; i += 256) {
      unsigned int low = x[i] & 0xFFFFu;
      unsigned int e = (low >> 7) & 0xFFu;
      if (low != 0u && (e < 96u || e > 144u)) local++;
    }
    atomicAdd(&cnt, local);
    __syncthreads();
    if (tid == 0) fF[0] = (cnt > 1024) ? 1 : 0;  // 1 => float32 inputs
  }
}

// ---------------- cvt_all: x0 cvt + params + weight prep + hist (1 launch) ----------
// R20 weight prep: Wq*b/Wk*b straight; wcatH* = [Wr^T | Wv^T] K-concat.
// R22: x0 copy SKIPPED when input already bf16; f32 path vectorized.
__global__ void cvt_all_kernel(const void* __restrict__ x0, ushort_t* __restrict__ x0b, int nx,
                               const void* p0, const void* p1, const void* p2,
                               const void* p3, const void* p4, const void* p5,
                               ushort_t* o0, ushort_t* o1, ushort_t* o2,
                               ushort_t* o3, ushort_t* o4, ushort_t* o5,
                               const void* W10, const void* W11, const void* W12, const void* W13,
                               ushort_t* __restrict__ Wq1b, ushort_t* __restrict__ Wk1b,
                               ushort_t* __restrict__ wcatH1,
                               const void* W20, const void* W21, const void* W22, const void* W23,
                               ushort_t* __restrict__ Wq2b, ushort_t* __restrict__ Wk2b,
                               ushort_t* __restrict__ wcatH2,
                               const void* __restrict__ edges, int* __restrict__ deg,
                               int E, int Nn,
                               const int* __restrict__ eflag, const int* __restrict__ fF) {
  int b = blockIdx.x, tid = threadIdx.x;
  int f = fF[0];
  if (b < 4096) {
    if (f) {  // only convert when input is f32; bf16 inputs are used in place
      int nx8 = nx >> 3;
      for (int i = b * 256 + tid; i < nx8; i += 4096 * 256) {
        const float* src = (const float*)x0 + (size_t)i * 8;
        float4 a = *(const float4*)src;
        float4 c = *(const float4*)(src + 4);
        s16x8 r;
        r[0] = (short)f2bf(a.x); r[1] = (short)f2bf(a.y);
        r[2] = (short)f2bf(a.z); r[3] = (short)f2bf(a.w);
        r[4] = (short)f2bf(c.x); r[5] = (short)f2bf(c.y);
        r[6] = (short)f2bf(c.z); r[7] = (short)f2bf(c.w);
        *(s16x8*)(x0b + (size_t)i * 8) = r;
      }
    }
  } else if (b == 4096) {
    const void* ins[6] = {p0, p1, p2, p3, p4, p5};
    ushort_t* outs[6] = {o0, o1, o2, o3, o4, o5};
    const int segs[7] = {0, 256, 512, 768, 896, 1024, 1152};
    for (int i = tid; i < 1152; i += 256) {
      int s = 0;
      while (i >= segs[s + 1]) s++;
      int li = i - segs[s];
      outs[s][li] = f ? f2bf(((const float*)ins[s])[li]) : ((const ushort_t*)ins[s])[li];
    }
  } else if (b < 4609) {
    // layer-1: Wq1[128][256], Wk1[128][256] straight;
    // Wr1[128][256] -> wcatH1[c][k]  (k<128);  Wv1[128][256] -> wcatH1[c][128+k].
    for (int i = (b - 4097) * 256 + tid; i < 131072; i += 512 * 256) {
      if (i < 32768) {
        Wq1b[i] = f ? f2bf(((const float*)W10)[i]) : ((const ushort_t*)W10)[i];
      } else if (i < 65536) {
        int r = i - 32768;
        Wk1b[r] = f ? f2bf(((const float*)W11)[r]) : ((const ushort_t*)W11)[r];
      } else if (i < 98304) {
        int rem = i - 65536, k = rem >> 8, c = rem & 255;  // Wr1[k][c]
        ushort_t v = f ? f2bf(((const float*)W13)[rem]) : ((const ushort_t*)W13)[rem];
        wcatH1[(size_t)c * 256 + k] = v;
      } else {
        int rem = i - 98304, k = rem >> 8, c = rem & 255;  // Wv1[k][c]
        ushort_t v = f ? f2bf(((const float*)W12)[rem]) : ((const ushort_t*)W12)[rem];
        wcatH1[(size_t)c * 256 + 128 + k] = v;
      }
    }
  } else if (b < 5121) {
    // layer-2: Wq2[256][256], Wk2[256][256] straight;
    // Wr2[256][128] -> wcatH2[c][k] (k<256);  Wv2[256][128] -> wcatH2[c][256+k].
    for (int i = (b - 4609) * 256 + tid; i < 196608; i += 512 * 256) {
      if (i < 65536) {
        Wq2b[i] = f ? f2bf(((const float*)W20)[i]) : ((const ushort_t*)W20)[i];
      } else if (i < 131072) {
        int r = i - 65536;
        Wk2b[r] = f ? f2bf(((const float*)W21)[r]) : ((const ushort_t*)W21)[r];
      } else if (i < 163840) {
        int rem = i - 131072, k = rem >> 7, c = rem & 127;  // Wr2[k][c]
        ushort_t v = f ? f2bf(((const float*)W23)[rem]) : ((const ushort_t*)W23)[rem];
        wcatH2[(size_t)c * 512 + k] = v;
      } else {
        int rem = i - 163840, k = rem >> 7, c = rem & 127;  // Wv2[k][c]
        ushort_t v = f ? f2bf(((const float*)W22)[rem]) : ((const ushort_t*)W22)[rem];
        wcatH2[(size_t)c * 512 + 256 + k] = v;
      }
    }
  } else {  // hist: 1024 blocks
    int wide = eflag[0];
    for (int e = (b - 5121) * 256 + tid; e < E; e += 1024 * 256) {
      int d = edge_at(edges, wide, E + e);
      if (d < 0) d = 0; if (d >= Nn) d = Nn - 1;
      atomicAdd(&deg[d], 1);
    }
  }
}

// ---------------- R24: chunk_sum + scan_small (last-arriver) + both M-GEMMs ---------
// blocks [0,nchunk): per-chunk degree sums -> csum (ATOMIC writes, device-coherent);
//   the LAST arriving chunk block (done counter, zeroed each run) runs the 256-wide
//   scan producing cpre + offs[N]. All cross-block comms via device-scope atomics.
// blocks [nchunk, nchunk+5): M1^T / M2^T weight GEMMs (independent; only need cvt_all).
__global__ __launch_bounds__(256)
void chunk_mgemm_kernel(const int* __restrict__ deg, int* __restrict__ csum,
                        int* __restrict__ cpre, int* __restrict__ offs,
                        int n, int N, int nchunk, int* __restrict__ done,
                        const ushort_t* __restrict__ Wk1b, const ushort_t* __restrict__ Wq1b,
                        ushort_t* __restrict__ wcatQ1,
                        const ushort_t* __restrict__ Wk2b, const ushort_t* __restrict__ Wq2b,
                        ushort_t* __restrict__ wcatQ2) {
  int b = blockIdx.x, t = threadIdx.x;
  if (b < nchunk) {
    int i = b * 256 + t;
    int v = (i < n) ? deg[i] : 0;
    __shared__ int ws[4];
#pragma unroll
    for (int o = 32; o > 0; o >>= 1) v += __shfl_down(v, o);
    if ((t & 63) == 0) ws[t >> 6] = v;
    __syncthreads();
    if (t == 0) atomicExch(&csum[b], ws[0] + ws[1] + ws[2] + ws[3]);
    __shared__ int lastf;
    if (t == 0) lastf = (atomicAdd(done, 1) == nchunk - 1);
    __syncthreads();
    if (lastf) {
      __shared__ int tmp[256];
      int v2 = (t < nchunk) ? atomicAdd(&csum[t], 0) : 0;
      tmp[t] = v2;
      __syncthreads();
      for (int off = 1; off < 256; off <<= 1) {
        int x = (t >= off) ? tmp[t - off] : 0;
        __syncthreads();
        tmp[t] += x;
        __syncthreads();
      }
      if (t < nchunk) cpre[t] = tmp[t] - v2;
      if (t == 255) offs[N] = tmp[255];
    }
  } else {
    int mb = b - nchunk;  // 0..4
    if (mb == 0)
      gemm_tile(Wk1b, Wk1b, 256, Wq1b, wcatQ1, wcatQ1, wcatQ1, wcatQ1,
                wcatQ1 /*bias unused*/, 128, 256, 128, 128, 128, 128,
                nullptr, nullptr, 0, 0);
    else {
      int t2 = mb - 1;
      gemm_tile(Wk2b, Wk2b, 256, Wq2b, wcatQ2, wcatQ2, wcatQ2, wcatQ2,
                wcatQ2 /*bias unused*/, 256, 256, 256, 256, 256, 256,
                nullptr, nullptr, (t2 >> 1) * 128, (t2 & 1) * 128);
    }
  }
}

__global__ void scan_final_kernel(const int* __restrict__ deg, const int* __restrict__ cpre,
                                  int* __restrict__ offs, int n) {
  int b = blockIdx.x, t = threadIdx.x, i = b * 256 + t;
  __shared__ int tmp[256];
  int v = (i < n) ? deg[i] : 0;
  tmp[t] = v;
  __syncthreads();
  for (int off = 1; off < 256; off <<= 1) {
    int x = (t >= off) ? tmp[t - off] : 0;
    __syncthreads();
    tmp[t] += x;
    __syncthreads();
  }
  if (i < n) offs[i] = cpre[b] + tmp[t] - v;
}

// ---------------- R24: scatter + qt1-GEMM in one launch -----------------------
// blocks [0,1024): CSR fill scatter; blocks [1024, 1024+MT): qt1 = x0 @ M1^T.
// Independent after scan_final (qt1 needs only x0 + wcatQ1, ready since chunk_mgemm).
__global__ __launch_bounds__(256)
void scatter_qt1_kernel(const void* __restrict__ edges, const int* __restrict__ flag,
                        const int* __restrict__ offs, int* __restrict__ fill,
                        int* __restrict__ srcS, int E, int Nn,
                        const ushort_t* __restrict__ x0b, const ushort_t* __restrict__ wcatQ1,
                        ushort_t* __restrict__ qtb,
                        const int* __restrict__ fF, const void* __restrict__ x0raw) {
  int b = blockIdx.x;
  if (b < 1024) {
    int wide = flag[0];
    for (int e = b * 256 + threadIdx.x; e < E; e += 1024 * 256) {
      int s = edge_at(edges, wide, e);
      int d = edge_at(edges, wide, E + e);
      if (d < 0) d = 0; if (d >= Nn) d = Nn - 1;
      if (s < 0) s = 0; if (s >= Nn) s = Nn - 1;
      int p = offs[d] + atomicAdd(&fill[d], 1);
      if (p < 0) p = 0; if (p >= E) p = E - 1;
      srcS[p] = s;
    }
  } else {
    const ushort_t* Ae = (fF[0] == 0) ? (const ushort_t*)x0raw : x0b;
    gemm_tile(Ae, Ae, 128, wcatQ1, qtb, qtb, qtb, qtb, wcatQ1 /*bias unused*/,
              Nn, 128, 128, 128, 128, 128, nullptr, nullptr, (b - 1024) * 128, 0);
  }
}

// ---------------- generic multi-section GEMM launch wrapper -------------------
__global__ __launch_bounds__(256)
void gemm4_kernel(const ushort_t* __restrict__ A, const ushort_t* __restrict__ A2,
                  int Ksplit,
                  const ushort_t* __restrict__ BT,
                  ushort_t* __restrict__ o0, ushort_t* __restrict__ o1,
                  ushort_t* __restrict__ o2, ushort_t* __restrict__ o3,
                  const ushort_t* __restrict__ bias3,
                  int M, int K, int NC, int b0, int b1, int b2,
                  float* __restrict__ bnsum, float* __restrict__ bnsq,
                  const int* __restrict__ fF, const void* __restrict__ x0raw, int axsel) {
  const ushort_t* Ae = A;
  const ushort_t* A2e = A2;
  if (axsel && fF[0] == 0) {
    if (axsel & 1) Ae = (const ushort_t*)x0raw;
    if (axsel & 2) A2e = (const ushort_t*)x0raw;
  }
  gemm_tile(Ae, A2e, Ksplit, BT, o0, o1, o2, o3, bias3, M, K, NC, b0, b1, b2,
            bnsum, bnsq, blockIdx.x * 128, blockIdx.y * 128);
}

// ---------------- fused attention + aggregation, one WAVE per dst node ----------------
// R17: qt-factorization. R18: 2-deep pipeline (VGPR 44 — best). [R19/R23: per-wave
// MLP variants flat or negative — pattern is at its fabric concurrency ceiling.]
// R21: nontemporal agg stores. R22: xsel — gather from x0raw when bf16 input.
__global__ __launch_bounds__(256)
void attn_kernel(const ushort_t* __restrict__ qt, const ushort_t* __restrict__ xin,
                 const int* __restrict__ offs, const int* __restrict__ srcS,
                 ushort_t* __restrict__ aggb, int D, int Nn,
                 const int* __restrict__ fF, const void* __restrict__ x0raw, int xsel) {
  int lane = threadIdx.x & 63, wave = threadIdx.x >> 6;
  int n = blockIdx.x * 4 + wave;
  if (n >= Nn) return;
  const ushort_t* x = (xsel && fF[0] == 0) ? (const ushort_t*)x0raw : xin;

  int e0 = offs[n], e1 = offs[n + 1];
  float wsum = 0.f;

  if (D == 128) {  // 8 lanes/edge, 8 edges per wave-iter; 16 dims per lane (R23)
    int g = lane >> 3, sub = lane & 7;
    const ushort_t* qp = qt + (size_t)n * 128 + sub * 16;
    s16x8 q0 = __builtin_nontemporal_load((const s16x8*)qp);
    s16x8 q1 = __builtin_nontemporal_load((const s16x8*)(qp + 8));
    float qf[16];
#pragma unroll
    for (int i = 0; i < 8; i++) {
      qf[i]     = bf2f((unsigned short)q0[i]);
      qf[8 + i] = bf2f((unsigned short)q1[i]);
    }
    float acc[16];
#pragma unroll
    for (int i = 0; i < 16; i++) acc[i] = 0.f;
    int j = e0;
    s16x8 x0c, x1c;
    bool have = (j + 8 <= e1);
    if (have) {
      int s = __builtin_nontemporal_load(srcS + j + g);
      if (s < 0 || s >= Nn) s = 0;
      const ushort_t* xp = x + (size_t)s * 128 + sub * 16;
      x0c = *(const s16x8*)xp; x1c = *(const s16x8*)(xp + 8);
    }
    for (; j + 16 <= e1; j += 8) {
      int s2 = __builtin_nontemporal_load(srcS + j + 8 + g);
      if (s2 < 0 || s2 >= Nn) s2 = 0;
      const ushort_t* xp2 = x + (size_t)s2 * 128 + sub * 16;
      s16x8 x0n = *(const s16x8*)xp2, x1n = *(const s16x8*)(xp2 + 8);
      float pa = 0.f, pb = 0.f;
#pragma unroll
      for (int i = 0; i < 8; i++) {
        pa += qf[i] * bf2f((unsigned short)x0c[i]);
        pb += qf[8 + i] * bf2f((unsigned short)x1c[i]);
      }
      float p = pa + pb;
      p += __shfl_xor(p, 1); p += __shfl_xor(p, 2); p += __shfl_xor(p, 4);
      float w = __expf(p * 0.0625f);
      wsum += w;
#pragma unroll
      for (int i = 0; i < 8; i++) {
        acc[i]     += w * bf2f((unsigned short)x0c[i]);
        acc[8 + i] += w * bf2f((unsigned short)x1c[i]);
      }
      x0c = x0n; x1c = x1n;
    }
    if (have) {
      float pa = 0.f, pb = 0.f;
#pragma unroll
      for (int i = 0; i < 8; i++) {
        pa += qf[i] * bf2f((unsigned short)x0c[i]);
        pb += qf[8 + i] * bf2f((unsigned short)x1c[i]);
      }
      float p = pa + pb;
      p += __shfl_xor(p, 1); p += __shfl_xor(p, 2); p += __shfl_xor(p, 4);
      float w = __expf(p * 0.0625f);
      wsum += w;
#pragma unroll
      for (int i = 0; i < 8; i++) {
        acc[i]     += w * bf2f((unsigned short)x0c[i]);
        acc[8 + i] += w * bf2f((unsigned short)x1c[i]);
      }
      j += 8;
    }
    int rem = e1 - j;  // 0..7
    if (rem > 0) {
      bool valid = g < rem;
      int s = __builtin_nontemporal_load(srcS + (valid ? (j + g) : j));
      if (s < 0 || s >= Nn) s = 0;
      const ushort_t* xp = x + (size_t)s * 128 + sub * 16;
      s16x8 x0v = *(const s16x8*)xp, x1v = *(const s16x8*)(xp + 8);
      float pa = 0.f, pb = 0.f;
#pragma unroll
      for (int i = 0; i < 8; i++) {
        pa += qf[i] * bf2f((unsigned short)x0v[i]);
        pb += qf[8 + i] * bf2f((unsigned short)x1v[i]);
      }
      float p = pa + pb;
      p += __shfl_xor(p, 1); p += __shfl_xor(p, 2); p += __shfl_xor(p, 4);
      float w = 0.f;
      if (valid) w = __expf(p * 0.0625f);
      wsum += w;
#pragma unroll
      for (int i = 0; i < 8; i++) {
        acc[i]     += w * bf2f((unsigned short)x0v[i]);
        acc[8 + i] += w * bf2f((unsigned short)x1v[i]);
      }
    }
    // combine the 8 groups (once per node)
    wsum += __shfl_xor(wsum, 8); wsum += __shfl_xor(wsum, 16); wsum += __shfl_xor(wsum, 32);
#pragma unroll
    for (int i = 0; i < 16; i++) {
      acc[i] += __shfl_xor(acc[i], 8);
      acc[i] += __shfl_xor(acc[i], 16);
      acc[i] += __shfl_xor(acc[i], 32);
    }
    float inv = 1.f / fmaxf(wsum, 1e-16f);
    if (g == 0) {  // lanes 0..7 cover the 128 dims
      s16x8 r0, r1;
#pragma unroll
      for (int i = 0; i < 8; i++) {
        r0[i] = (short)f2bf(acc[i] * inv);
        r1[i] = (short)f2bf(acc[8 + i] * inv);
      }
      size_t idx = (size_t)n * 128 + sub * 16;
      __builtin_nontemporal_store(r0, (s16x8*)(aggb + idx));
      __builtin_nontemporal_store(r1, (s16x8*)(aggb + idx + 8));
    }
  } else {  // D == 256: 16 lanes/edge, 4 edges/iter (R18 config, unchanged)
    int g = lane >> 4, sub = lane & 15;
    s16x8 q0 = __builtin_nontemporal_load((const s16x8*)(qt + (size_t)n * 256 + sub * 16));
    s16x8 q1 = __builtin_nontemporal_load((const s16x8*)(qt + (size_t)n * 256 + sub * 16 + 8));
    float qf[16];
#pragma unroll
    for (int i = 0; i < 8; i++) {
      qf[i]     = bf2f((unsigned short)q0[i]);
      qf[8 + i] = bf2f((unsigned short)q1[i]);
    }
    float acc[16];
#pragma unroll
    for (int i = 0; i < 16; i++) acc[i] = 0.f;
    int j = e0;
    s16x8 x0c, x1c;
    bool have = (j + 4 <= e1);
    if (have) {
      int s = __builtin_nontemporal_load(srcS + j + g);
      if (s < 0 || s >= Nn) s = 0;
      const ushort_t* xp = x + (size_t)s * 256 + sub * 16;
      x0c = *(const s16x8*)xp; x1c = *(const s16x8*)(xp + 8);
    }
    for (; j + 8 <= e1; j += 4) {
      int s2 = __builtin_nontemporal_load(srcS + j + 4 + g);
      if (s2 < 0 || s2 >= Nn) s2 = 0;
      const ushort_t* xp2 = x + (size_t)s2 * 256 + sub * 16;
      s16x8 x0n = *(const s16x8*)xp2, x1n = *(const s16x8*)(xp2 + 8);
      float pa = 0.f, pb = 0.f;
#pragma unroll
      for (int i = 0; i < 8; i++) {
        pa += qf[i] * bf2f((unsigned short)x0c[i]);
        pb += qf[8 + i] * bf2f((unsigned short)x1c[i]);
      }
      float p = pa + pb;
      p += __shfl_xor(p, 1); p += __shfl_xor(p, 2);
      p += __shfl_xor(p, 4); p += __shfl_xor(p, 8);
      float w = __expf(p * 0.0625f);
      wsum += w;
#pragma unroll
      for (int i = 0; i < 8; i++) {
        acc[i]     += w * bf2f((unsigned short)x0c[i]);
        acc[8 + i] += w * bf2f((unsigned short)x1c[i]);
      }
      x0c = x0n; x1c = x1n;
    }
    if (have) {
      float pa = 0.f, pb = 0.f;
#pragma unroll
      for (int i = 0; i < 8; i++) {
        pa += qf[i] * bf2f((unsigned short)x0c[i]);
        pb += qf[8 + i] * bf2f((unsigned short)x1c[i]);
      }
      float p = pa + pb;
      p += __shfl_xor(p, 1); p += __shfl_xor(p, 2);
      p += __shfl_xor(p, 4); p += __shfl_xor(p, 8);
      float w = __expf(p * 0.0625f);
      wsum += w;
#pragma unroll
      for (int i = 0; i < 8; i++) {
        acc[i]     += w * bf2f((unsigned short)x0c[i]);
        acc[8 + i] += w * bf2f((unsigned short)x1c[i]);
      }
      j += 4;
    }
    int rem = e1 - j;
    if (rem > 0) {
      bool valid = g < rem;
      int s = __builtin_nontemporal_load(srcS + (valid ? (j + g) : j));
      if (s < 0 || s >= Nn) s = 0;
      const ushort_t* xp = x + (size_t)s * 256 + sub * 16;
      s16x8 x0v = *(const s16x8*)xp, x1v = *(const s16x8*)(xp + 8);
      float pa = 0.f, pb = 0.f;
#pragma unroll
      for (int i = 0; i < 8; i++) {
        pa += qf[i] * bf2f((unsigned short)x0v[i]);
        pb += qf[8 + i] * bf2f((unsigned short)x1v[i]);
      }
      float p = pa + pb;
      p += __shfl_xor(p, 1); p += __shfl_xor(p, 2);
      p += __shfl_xor(p, 4); p += __shfl_xor(p, 8);
      float w = 0.f;
      if (valid) w = __expf(p * 0.0625f);
      wsum += w;
#pragma unroll
      for (int i = 0; i < 8; i++) {
        acc[i]     += w * bf2f((unsigned short)x0v[i]);
        acc[8 + i] += w * bf2f((unsigned short)x1v[i]);
      }
    }
    wsum += __shfl_xor(wsum, 16); wsum += __shfl_xor(wsum, 32);
#pragma unroll
    for (int i = 0; i < 16; i++) {
      acc[i] += __shfl_xor(acc[i], 16);
      acc[i] += __shfl_xor(acc[i], 32);
    }
    float inv = 1.f / fmaxf(wsum, 1e-16f);
    if (g == 0) {
      s16x8 r0, r1;
#pragma unroll
      for (int i = 0; i < 8; i++) {
        r0[i] = (short)f2bf(acc[i] * inv);
        r1[i] = (short)f2bf(acc[8 + i] * inv);
      }
      size_t idx = (size_t)n * 256 + sub * 16;
      __builtin_nontemporal_store(r0, (s16x8*)(aggb + idx));
      __builtin_nontemporal_store(r1, (s16x8*)(aggb + idx + 8));
    }
  }
}

// normalize+relu; R22: short8-vectorized. total8 = total elements / 8.
__global__ void norm_relu_kernel(const ushort_t* __restrict__ h,
                                 const float* __restrict__ sum, const float* __restrict__ sumsq,
                                 const ushort_t* __restrict__ g, const ushort_t* __restrict__ be,
                                 ushort_t* __restrict__ x1, int N, size_t total8, int cmask) {
  __shared__ float sc[256], sh[256];
  int t = threadIdx.x;
  if (t <= cmask) {
    float mu = sum[t] / (float)N;
    float var = sumsq[t] / (float)N - mu * mu;
    float s = bf2f(g[t]) * rsqrtf(var + 1e-5f);
    sc[t] = s;
    sh[t] = bf2f(be[t]) - mu * s;
  }
  __syncthreads();
  for (size_t i = blockIdx.x * (size_t)blockDim.x + t; i < total8;
       i += (size_t)gridDim.x * blockDim.x) {
    size_t base = i * 8;
    s16x8 hv = *(const s16x8*)(h + base);
    int c0 = (int)(base & (size_t)cmask);
    s16x8 r;
#pragma unroll
    for (int j = 0; j < 8; j++) {
      float vv = bf2f((unsigned short)hv[j]) * sc[c0 + j] + sh[c0 + j];
      r[j] = (short)f2bf(relu_nanprop(vv));
    }
    *(s16x8*)(x1 + base) = r;
  }
}

// final: BN + residual + relu, dual-dtype out; R22: short8-vectorized + x0raw select.
__global__ void final_kernel(const ushort_t* __restrict__ h,
                             const float* __restrict__ sum, const float* __restrict__ sumsq,
                             const ushort_t* __restrict__ g, const ushort_t* __restrict__ be,
                             const ushort_t* __restrict__ x0b, const void* __restrict__ x0raw,
                             void* __restrict__ out,
                             const int* __restrict__ flagF, int N, size_t total8) {
  __shared__ float sc[128], sh[128];
  int t = threadIdx.x;
  if (t < 128) {
    float mu = sum[t] / (float)N;
    float var = sumsq[t] / (float)N - mu * mu;
    float s = bf2f(g[t]) * rsqrtf(var + 1e-5f);
    sc[t] = s;
    sh[t] = bf2f(be[t]) - mu * s;
  }
  __syncthreads();
  int f = flagF[0];
  const ushort_t* xp = f ? x0b : (const ushort_t*)x0raw;
  for (size_t i = blockIdx.x * (size_t)blockDim.x + t; i < total8;
       i += (size_t)gridDim.x * blockDim.x) {
    size_t base = i * 8;
    s16x8 hv = *(const s16x8*)(h + base);
    s16x8 xv = *(const s16x8*)(xp + base);
    int c0 = (int)(base & 127);
    float v[8];
#pragma unroll
    for (int j = 0; j < 8; j++) {
      float vv = bf2f((unsigned short)hv[j]) * sc[c0 + j] + sh[c0 + j]
               + bf2f((unsigned short)xv[j]);
      v[j] = relu_nanprop(vv);
    }
    if (f) {
      float4 o1 = {v[0], v[1], v[2], v[3]};
      float4 o2 = {v[4], v[5], v[6], v[7]};
      *(float4*)((float*)out + base) = o1;
      *(float4*)((float*)out + base + 4) = o2;
    } else {
      s16x8 r;
#pragma unroll
      for (int j = 0; j < 8; j++) r[j] = (short)f2bf(v[j]);
      *(s16x8*)((ushort_t*)out + base) = r;
    }
  }
}

extern "C" void kernel_launch(void* const* d_in, const int* in_sizes, int n_in,
                              void* d_out, int out_size, void* d_ws, size_t ws_size,
                              hipStream_t stream) {
  const void* x0  = d_in[0];
  const void* edges = d_in[1];
  const void* Wq1 = d_in[2];
  const void* Wk1 = d_in[3];
  const void* Wv1 = d_in[4];
  const void* Wr1 = d_in[5];
  const void* b1  = d_in[6];
  const void* gw1 = d_in[7];
  const void* bw1 = d_in[8];
  const void* Wq2 = d_in[9];
  const void* Wk2 = d_in[10];
  const void* Wv2 = d_in[11];
  const void* Wr2 = d_in[12];
  const void* b2  = d_in[13];
  const void* gw2 = d_in[14];
  const void* bw2 = d_in[15];

  int N = in_sizes[0] / 128;
  int E = in_sizes[1] / 2;
  int NCHUNK = (N + 255) / 256;
  int MT = (N + 127) / 128;

  uintptr_t base = (uintptr_t)d_ws;
  auto carve = [&](size_t bytes) -> void* {
    uintptr_t p = base;
    base += (bytes + 255) & ~(size_t)255;
    return (void*)p;
  };
  ushort_t* x0b = (ushort_t*)carve((size_t)N * 128 * 2);
  ushort_t* qtb = (ushort_t*)carve((size_t)N * 256 * 2);   // qt1 (128) / qt2 (256)
  ushort_t* aggb = (ushort_t*)carve((size_t)N * 256 * 2);  // agg output (128/256)
  ushort_t* hb = (ushort_t*)carve((size_t)N * 256 * 2);
  ushort_t* x1 = (ushort_t*)carve((size_t)N * 256 * 2);
  ushort_t* Wq1b = (ushort_t*)carve((size_t)128 * 256 * 2);
  ushort_t* Wk1b = (ushort_t*)carve((size_t)128 * 256 * 2);
  ushort_t* wcatQ1 = (ushort_t*)carve((size_t)128 * 128 * 2);  // M1^T
  ushort_t* wcatH1 = (ushort_t*)carve((size_t)256 * 256 * 2);  // [Wr1^T | Wv1^T]
  ushort_t* Wq2b = (ushort_t*)carve((size_t)256 * 256 * 2);
  ushort_t* Wk2b = (ushort_t*)carve((size_t)256 * 256 * 2);
  ushort_t* wcatQ2 = (ushort_t*)carve((size_t)256 * 256 * 2);  // M2^T
  ushort_t* wcatH2 = (ushort_t*)carve((size_t)128 * 512 * 2);  // [Wr2^T | Wv2^T]
  ushort_t* b1b  = (ushort_t*)carve(256 * 2);
  ushort_t* g1b  = (ushort_t*)carve(256 * 2);
  ushort_t* be1b = (ushort_t*)carve(256 * 2);
  ushort_t* b2b  = (ushort_t*)carve(128 * 2);
  ushort_t* g2b  = (ushort_t*)carve(128 * 2);
  ushort_t* be2b = (ushort_t*)carve(128 * 2);
  int* offs = (int*)carve((size_t)(N + 1) * 4);
  int* srcS = (int*)carve((size_t)E * 4);
  int* csum = (int*)carve(256 * 4);
  int* cpre = (int*)carve(256 * 4);
  // zeroed region: deg(N) fill(N) sums(1024 floats) done(1) -> padded to 2N+1088
  int nzero = 2 * N + 1088;
  int* zreg2 = (int*)carve((size_t)nzero * 4);
  int* deg   = zreg2;
  int* fill  = zreg2 + N;
  float* sum1 = (float*)(zreg2 + 2 * N);
  float* sq1  = sum1 + 256;
  float* sum2 = sum1 + 512;
  float* sq2  = sum1 + 640;
  int* done  = zreg2 + 2 * N + 1024;
  int* eflag = (int*)carve(256);   // [0]=edge wide, [1]=float32 flag (setup writes)
  int* fF = eflag + 1;

  size_t needed = base - (uintptr_t)d_ws;
  if (needed > ws_size) return;

  // 1: zero + dtype detects
  setup_kernel<<<258, 256, 0, stream>>>(zreg2, N, (const int*)edges, 2 * E, eflag,
                                        (const unsigned int*)x0, N * 128, fF);
  // 2: x0 cvt (f32 only) + params + weight prep + hist
  cvt_all_kernel<<<6145, 256, 0, stream>>>(x0, x0b, N * 128,
                                           b1, gw1, bw1, b2, gw2, bw2,
                                           b1b, g1b, be1b, b2b, g2b, be2b,
                                           Wq1, Wk1, Wv1, Wr1, Wq1b, Wk1b, wcatH1,
                                           Wq2, Wk2, Wv2, Wr2, Wq2b, Wk2b, wcatH2,
                                           edges, deg, E, N, eflag, fF);
  // 3: chunk sums + last-arriver scan_small + both M-GEMMs (1 launch)
  chunk_mgemm_kernel<<<NCHUNK + 5, 256, 0, stream>>>(deg, csum, cpre, offs, N, N, NCHUNK,
                                                     done, Wk1b, Wq1b, wcatQ1,
                                                     Wk2b, Wq2b, wcatQ2);
  // 4: per-chunk prefix finalize
  scan_final_kernel<<<NCHUNK, 256, 0, stream>>>(deg, cpre, offs, N);
  // 5: scatter + qt1-GEMM (1 launch, overlapped)
  scatter_qt1_kernel<<<1024 + MT, 256, 0, stream>>>(edges, eflag, offs, fill, srcS, E, N,
                                                    x0b, wcatQ1, qtb, fF, x0);

  int gAttn = (N + 3) / 4;        // one wave per node
  // Layer 1: attn;  h = [x0|agg] @ [Wr1;Wv1] + b1 (+fused BN stats)
  attn_kernel<<<gAttn, 256, 0, stream>>>(qtb, x0b, offs, srcS, aggb, 128, N, fF, x0, 1);
  gemm4_kernel<<<dim3(MT, 2), 256, 0, stream>>>(x0b, aggb, 128, wcatH1,
                                                hb, hb, hb, hb,
                                                b1b, N, 256, 256, 0, 0, 0,
                                                sum1, sq1, fF, x0, 1);
  norm_relu_kernel<<<4096, 256, 0, stream>>>(hb, sum1, sq1, g1b, be1b, x1, N,
                                             (size_t)N * 32, 255);
  // Layer 2: qt2 = x1 @ M2^T;  attn;  h = [x1|agg] @ [Wr2;Wv2] + b2 (+fused BN stats)
  gemm4_kernel<<<dim3(MT, 2), 256, 0, stream>>>(x1, x1, 256, wcatQ2,
                                                qtb, qtb, qtb, qtb,
                                                b2b, N, 256, 256, 256, 256, 256,
                                                nullptr, nullptr, fF, x0, 0);
  attn_kernel<<<gAttn, 256, 0, stream>>>(qtb, x1, offs, srcS, aggb, 256, N, fF, x0, 0);
  gemm4_kernel<<<dim3(MT, 1), 256, 0, stream>>>(x1, aggb, 256, wcatH2,
                                                hb, hb, hb, hb,
                                                b2b, N, 512, 128, 0, 0, 0,
                                                sum2, sq2, fF, x0, 0);
  final_kernel<<<2048, 256, 0, stream>>>(hb, sum2, sq2, g2b, be2b, x0b, x0, d_out, fF, N,
                                         (size_t)N * 16);
}